// Round 1
// baseline (587.827 us; speedup 1.0000x reference)
//
#include <hip/hip_runtime.h>
#include <math.h>
#include <stdio.h>

#define N_NODES 51200
#define N_EDGES 409600
#define B_GRAPH 256
#define NH 13

// ---------------- edge dtype probe: int64 ei has zero high words ----------------
__global__ void probe_flag(const int* __restrict__ ei32, int* __restrict__ flag) {
    if (blockIdx.x == 0 && threadIdx.x == 0) {
        int z = 1;
        for (int k = 1; k < 16; k += 2) z &= (ei32[k] == 0);
        *flag = z;  // 1 -> treat ei as int64
    }
}

__global__ void init_deg(int* __restrict__ degc) {
    int i = blockIdx.x * 256 + threadIdx.x;
    if (i < N_NODES) degc[i] = 1;  // self-loop
}

__global__ void count_deg(const int* __restrict__ ei32, const long long* __restrict__ ei64,
                          const int* __restrict__ flag, int* __restrict__ degc) {
    int e = blockIdx.x * 256 + threadIdx.x;
    if (e >= N_EDGES) return;
    int v = (*flag) ? (int)ei64[N_EDGES + e] : ei32[N_EDGES + e];
    atomicAdd(&degc[v], 1);
}

// ---------------- 3-phase exclusive scan of (deg-1) over N ----------------
__global__ void scan_block_sums(const int* __restrict__ degc, int* __restrict__ bsums) {
    __shared__ int sdata[256];
    int i = blockIdx.x * 256 + threadIdx.x;
    int v = degc[i] - 1;
    sdata[threadIdx.x] = v;
    __syncthreads();
    for (int s = 128; s > 0; s >>= 1) {
        if (threadIdx.x < s) sdata[threadIdx.x] += sdata[threadIdx.x + s];
        __syncthreads();
    }
    if (threadIdx.x == 0) bsums[blockIdx.x] = sdata[0];
}

__global__ void scan_bsums(int* __restrict__ bsums, int nb) {
    __shared__ int s[256];
    int t = threadIdx.x;
    int v = (t < nb) ? bsums[t] : 0;
    s[t] = v;
    __syncthreads();
    for (int off = 1; off < 256; off <<= 1) {
        int u = (t >= off) ? s[t - off] : 0;
        __syncthreads();
        s[t] += u;
        __syncthreads();
    }
    if (t < nb) bsums[t] = s[t] - v;  // exclusive
}

__global__ void scan_finalize(int* __restrict__ degc, int* __restrict__ offs,
                              float* __restrict__ dinv, const int* __restrict__ bsums) {
    __shared__ int s[256];
    int i = blockIdx.x * 256 + threadIdx.x;
    int d = degc[i];
    int v = d - 1;
    s[threadIdx.x] = v;
    __syncthreads();
    for (int off = 1; off < 256; off <<= 1) {
        int u = (threadIdx.x >= off) ? s[threadIdx.x - off] : 0;
        __syncthreads();
        s[threadIdx.x] += u;
        __syncthreads();
    }
    int excl = s[threadIdx.x] - v + bsums[blockIdx.x];
    offs[i] = excl;
    dinv[i] = rsqrtf((float)d);
    degc[i] = excl;  // becomes the fill cursor
    if (i == N_NODES - 1) offs[N_NODES] = N_EDGES;
}

__global__ void fill_csr(const int* __restrict__ ei32, const long long* __restrict__ ei64,
                         const int* __restrict__ flag, int* __restrict__ cursor,
                         int* __restrict__ csr) {
    int e = blockIdx.x * 256 + threadIdx.x;
    if (e >= N_EDGES) return;
    int u, v;
    if (*flag) { u = (int)ei64[e]; v = (int)ei64[N_EDGES + e]; }
    else       { u = ei32[e];      v = ei32[N_EDGES + e]; }
    int pos = atomicAdd(&cursor[v], 1);
    csr[pos] = u;
}

// ---------------- GEMM: Y[N,256] = X[N,64] @ W[64,256] ----------------
__global__ __launch_bounds__(256) void gemm_64_256(const float* __restrict__ X,
                                                   const float* __restrict__ W,
                                                   float* __restrict__ Y) {
    __shared__ float wl[64 * 256];
    __shared__ float xr[16 * 64];
    for (int i = threadIdx.x; i < 64 * 256; i += 256) wl[i] = W[i];
    const int ct = threadIdx.x & 63;   // col-thread, 4 cols each
    const int rg = threadIdx.x >> 6;   // row group, 4 rows each
    const int c0 = ct * 4;
    const int row0 = blockIdx.x * 64;
    for (int rb = 0; rb < 64; rb += 16) {
        __syncthreads();
        {
            const float4* src = (const float4*)(X + (size_t)(row0 + rb) * 64);
            ((float4*)xr)[threadIdx.x] = src[threadIdx.x];  // 16 rows * 64 = 256 float4
        }
        __syncthreads();
        float acc[4][4];
        #pragma unroll
        for (int r = 0; r < 4; ++r)
            #pragma unroll
            for (int cc = 0; cc < 4; ++cc) acc[r][cc] = 0.f;
        #pragma unroll
        for (int k = 0; k < 64; k += 4) {
            float4 wq[4];
            #pragma unroll
            for (int kk = 0; kk < 4; ++kk) wq[kk] = *(const float4*)&wl[(k + kk) * 256 + c0];
            #pragma unroll
            for (int r = 0; r < 4; ++r) {
                float4 xq = *(const float4*)&xr[(rg * 4 + r) * 64 + k];
                float xv[4] = {xq.x, xq.y, xq.z, xq.w};
                #pragma unroll
                for (int kk = 0; kk < 4; ++kk) {
                    acc[r][0] += xv[kk] * wq[kk].x;
                    acc[r][1] += xv[kk] * wq[kk].y;
                    acc[r][2] += xv[kk] * wq[kk].z;
                    acc[r][3] += xv[kk] * wq[kk].w;
                }
            }
        }
        #pragma unroll
        for (int r = 0; r < 4; ++r) {
            int row = row0 + rb + rg * 4 + r;
            *(float4*)&Y[(size_t)row * 256 + c0] =
                make_float4(acc[r][0], acc[r][1], acc[r][2], acc[r][3]);
        }
    }
}

// ---------------- GEMM: Y[N,64] = X[N,256] @ W[256,64] ----------------
__global__ __launch_bounds__(256) void gemm_256_64(const float* __restrict__ X,
                                                   const float* __restrict__ W,
                                                   float* __restrict__ Y) {
    __shared__ float wl[256 * 64];
    __shared__ float xr[16 * 256];
    for (int i = threadIdx.x; i < 256 * 64; i += 256) wl[i] = W[i];
    const int ct = threadIdx.x & 63;  // one col each
    const int rg = threadIdx.x >> 6;  // 4 rows each
    const int row0 = blockIdx.x * 64;
    for (int rb = 0; rb < 64; rb += 16) {
        __syncthreads();
        {
            const float4* src = (const float4*)(X + (size_t)(row0 + rb) * 256);
            float4* d4 = (float4*)xr;
            for (int i = threadIdx.x; i < 1024; i += 256) d4[i] = src[i];
        }
        __syncthreads();
        float acc[4] = {0.f, 0.f, 0.f, 0.f};
        #pragma unroll 8
        for (int k = 0; k < 256; k += 4) {
            float w0 = wl[k * 64 + ct];
            float w1 = wl[(k + 1) * 64 + ct];
            float w2 = wl[(k + 2) * 64 + ct];
            float w3 = wl[(k + 3) * 64 + ct];
            #pragma unroll
            for (int r = 0; r < 4; ++r) {
                float4 xq = *(const float4*)&xr[(rg * 4 + r) * 256 + k];
                acc[r] += xq.x * w0 + xq.y * w1 + xq.z * w2 + xq.w * w3;
            }
        }
        #pragma unroll
        for (int r = 0; r < 4; ++r)
            Y[(size_t)(row0 + rb + rg * 4 + r) * 64 + ct] = acc[r];
    }
}

// ---------------- pull max-aggregation, 256 feats: one wave per node ----------------
__global__ __launch_bounds__(256) void agg_max_f256(const float* __restrict__ xw,
        const float* __restrict__ dinv, const int* __restrict__ offs,
        const int* __restrict__ csr, const float* __restrict__ bias,
        float* __restrict__ out) {
    int gid = blockIdx.x * 256 + threadIdx.x;
    int v = gid >> 6;
    int lane = gid & 63;
    float dv = dinv[v];
    float4 a = ((const float4*)(xw + (size_t)v * 256))[lane];
    float sn = dv * dv;
    float4 acc = make_float4(a.x * sn, a.y * sn, a.z * sn, a.w * sn);
    int e1 = offs[v + 1];
    for (int e = offs[v]; e < e1; ++e) {
        int u = csr[e];
        float nrm = dinv[u] * dv;
        float4 m = ((const float4*)(xw + (size_t)u * 256))[lane];
        acc.x = fmaxf(acc.x, m.x * nrm);
        acc.y = fmaxf(acc.y, m.y * nrm);
        acc.z = fmaxf(acc.z, m.z * nrm);
        acc.w = fmaxf(acc.w, m.w * nrm);
    }
    float4 b4 = ((const float4*)bias)[lane];
    float4 o;
    o.x = fmaxf(acc.x + b4.x, 0.f);
    o.y = fmaxf(acc.y + b4.y, 0.f);
    o.z = fmaxf(acc.z + b4.z, 0.f);
    o.w = fmaxf(acc.w + b4.w, 0.f);
    ((float4*)(out + (size_t)v * 256))[lane] = o;
}

// ---------------- pull max-aggregation, 64 feats: one wave per node ----------------
__global__ __launch_bounds__(256) void agg_max_f64(const float* __restrict__ xw,
        const float* __restrict__ dinv, const int* __restrict__ offs,
        const int* __restrict__ csr, const float* __restrict__ bias,
        float* __restrict__ out) {
    int gid = blockIdx.x * 256 + threadIdx.x;
    int v = gid >> 6;
    int lane = gid & 63;
    float dv = dinv[v];
    float acc = xw[(size_t)v * 64 + lane] * dv * dv;
    int e1 = offs[v + 1];
    for (int e = offs[v]; e < e1; ++e) {
        int u = csr[e];
        float nrm = dinv[u] * dv;
        acc = fmaxf(acc, xw[(size_t)u * 64 + lane] * nrm);
    }
    out[(size_t)v * 64 + lane] = fmaxf(acc + bias[lane], 0.f);
}

// ---------------- fused self-attention: one block per graph ----------------
template <int IN, int H>
__global__ __launch_bounds__(256) void attn_kernel(const float* __restrict__ feat,
        const int* __restrict__ host_idx,
        const float* __restrict__ aW, const float* __restrict__ ab,
        const float* __restrict__ fW, const float* __restrict__ fb,
        const float* __restrict__ gW, const float* __restrict__ gb,
        const float* __restrict__ g_in, float* __restrict__ g_out) {
    __shared__ float vl[NH * IN];
    __shared__ float cat[H + 256];
    __shared__ float red[8];
    const int b = blockIdx.x;
    const int t = threadIdx.x;
    for (int i = t; i < NH * IN; i += 256) {
        int j = i / IN, k = i - j * IN;
        vl[i] = feat[(size_t)host_idx[b * NH + j] * IN + k];
    }
    __syncthreads();
    const bool act = (t < H);
    float accA[NH], accF[NH];
    if (act) {
        #pragma unroll
        for (int j = 0; j < NH; ++j) { accA[j] = ab[t]; accF[j] = fb[t]; }
        for (int k = 0; k < IN; ++k) {
            float wa = aW[k * H + t];
            float wf = fW[k * H + t];
            #pragma unroll
            for (int j = 0; j < NH; ++j) {
                float xv = vl[j * IN + k];
                accA[j] += xv * wa;
                accF[j] += xv * wf;
            }
        }
    }
    constexpr int NW = (H + 63) / 64;
    float outc = 0.f;
    for (int j = 0; j < NH; ++j) {
        float m = act ? accA[j] : -3.402823466e38f;
        #pragma unroll
        for (int off = 32; off; off >>= 1) m = fmaxf(m, __shfl_xor(m, off));
        if ((t & 63) == 0 && t < H) red[t >> 6] = m;
        __syncthreads();
        m = red[0];
        #pragma unroll
        for (int w = 1; w < NW; ++w) m = fmaxf(m, red[w]);
        __syncthreads();
        float p = act ? expf(accA[j] - m) : 0.f;
        float s = p;
        #pragma unroll
        for (int off = 32; off; off >>= 1) s += __shfl_xor(s, off);
        if ((t & 63) == 0 && t < H) red[t >> 6] = s;
        __syncthreads();
        s = red[0];
        #pragma unroll
        for (int w = 1; w < NW; ++w) s += red[w];
        __syncthreads();
        if (act) outc += (p / s) * accF[j];
    }
    if (act) cat[t] = outc;
    cat[H + t] = g_in ? g_in[b * 256 + t] : 0.f;
    __syncthreads();
    float acc = gb[t];
    #pragma unroll 4
    for (int i = 0; i < H + 256; ++i) acc += cat[i] * gW[i * 256 + t];
    g_out[b * 256 + t] = cat[H + t] + acc;
}

// ---------------- head: relu(g@o1W+o1b)@o2W+o2b ----------------
__global__ __launch_bounds__(64) void head_kernel(const float* __restrict__ g,
        const float* __restrict__ o1W, const float* __restrict__ o1b,
        const float* __restrict__ o2W, const float* __restrict__ o2b,
        float* __restrict__ out) {
    int b = blockIdx.x, t = threadIdx.x;
    const float* gr = g + (size_t)b * 256;
    float acc = o1b[t];
    #pragma unroll 8
    for (int k = 0; k < 256; ++k) acc += gr[k] * o1W[k * 64 + t];
    acc = fmaxf(acc, 0.f);
    float s = acc * o2W[t];
    #pragma unroll
    for (int off = 32; off; off >>= 1) s += __shfl_xor(s, off);
    if (t == 0) out[b] = s + o2b[0];
}

extern "C" void kernel_launch(void* const* d_in, const int* in_sizes, int n_in,
                              void* d_out, int out_size, void* d_ws, size_t ws_size,
                              hipStream_t stream) {
    (void)in_sizes; (void)n_in; (void)out_size;
    const float* x    = (const float*)d_in[0];
    const int* ei32   = (const int*)d_in[1];
    const long long* ei64 = (const long long*)d_in[1];
    const int* hidx   = (const int*)d_in[2];
    const float* W1 = (const float*)d_in[3],  *b1 = (const float*)d_in[4];
    const float* W2 = (const float*)d_in[5],  *b2 = (const float*)d_in[6];
    const float* a0W = (const float*)d_in[7],  *a0b = (const float*)d_in[8];
    const float* f0W = (const float*)d_in[9],  *f0b = (const float*)d_in[10];
    const float* g0W = (const float*)d_in[11], *g0b = (const float*)d_in[12];
    const float* a1W = (const float*)d_in[13], *a1b = (const float*)d_in[14];
    const float* f1W = (const float*)d_in[15], *f1b = (const float*)d_in[16];
    const float* g1W = (const float*)d_in[17], *g1b = (const float*)d_in[18];
    const float* a2W = (const float*)d_in[19], *a2b = (const float*)d_in[20];
    const float* f2W = (const float*)d_in[21], *f2b = (const float*)d_in[22];
    const float* g2W = (const float*)d_in[23], *g2b = (const float*)d_in[24];
    const float* o1W = (const float*)d_in[25], *o1b = (const float*)d_in[26];
    const float* o2W = (const float*)d_in[27], *o2b = (const float*)d_in[28];
    float* outp = (float*)d_out;

    char* p = (char*)d_ws;
    auto alloc = [&](size_t bytes) {
        char* r = p;
        p += (bytes + 255) & ~(size_t)255;
        return r;
    };
    float* dinv = (float*)alloc((size_t)N_NODES * 4);
    int* degc   = (int*)alloc((size_t)N_NODES * 4);
    int* offs   = (int*)alloc((size_t)(N_NODES + 1) * 4);
    int* csr    = (int*)alloc((size_t)N_EDGES * 4);
    int* bsums  = (int*)alloc(256 * 4);
    int* flag   = (int*)alloc(256);
    float* g    = (float*)alloc((size_t)B_GRAPH * 256 * 4);
    float* xw1  = (float*)alloc((size_t)N_NODES * 256 * 4);
    float* x1   = (float*)alloc((size_t)N_NODES * 256 * 4);
    // xw1 is dead after agg_max_f256 -> reuse its 52 MB region for xw2 and x2
    float* xw2  = xw1;
    float* x2   = xw1 + (size_t)N_NODES * 64;

    size_t need = (size_t)(p - (char*)d_ws);
    if (need > ws_size) {
        fprintf(stderr, "kernel_launch: ws too small (%zu needed, %zu have)\n", need, ws_size);
        return;
    }

    probe_flag<<<1, 64, 0, stream>>>(ei32, flag);
    init_deg<<<200, 256, 0, stream>>>(degc);
    count_deg<<<1600, 256, 0, stream>>>(ei32, ei64, flag, degc);
    scan_block_sums<<<200, 256, 0, stream>>>(degc, bsums);
    scan_bsums<<<1, 256, 0, stream>>>(bsums, 200);
    scan_finalize<<<200, 256, 0, stream>>>(degc, offs, dinv, bsums);
    fill_csr<<<1600, 256, 0, stream>>>(ei32, ei64, flag, degc, csr);

    gemm_64_256<<<800, 256, 0, stream>>>(x, W1, xw1);
    attn_kernel<64, 256><<<256, 256, 0, stream>>>(x, hidx, a0W, a0b, f0W, f0b, g0W, g0b,
                                                  nullptr, g);
    agg_max_f256<<<12800, 256, 0, stream>>>(xw1, dinv, offs, csr, b1, x1);
    attn_kernel<256, 256><<<256, 256, 0, stream>>>(x1, hidx, a1W, a1b, f1W, f1b, g1W, g1b,
                                                   g, g);
    gemm_256_64<<<800, 256, 0, stream>>>(x1, W2, xw2);
    agg_max_f64<<<12800, 256, 0, stream>>>(xw2, dinv, offs, csr, b2, x2);
    attn_kernel<64, 64><<<256, 256, 0, stream>>>(x2, hidx, a2W, a2b, f2W, f2b, g2W, g2b,
                                                 g, g);
    head_kernel<<<256, 64, 0, stream>>>(g, o1W, o1b, o2W, o2b, outp);
}

// Round 2
// 565.749 us; speedup vs baseline: 1.0390x; 1.0390x over previous
//
#include <hip/hip_runtime.h>
#include <math.h>
#include <stdio.h>

#define N_NODES 51200
#define N_EDGES 409600
#define B_GRAPH 256
#define NH 13

// ---------------- edge dtype probe: int64 ei has zero high words ----------------
__global__ void probe_flag(const int* __restrict__ ei32, int* __restrict__ flag) {
    if (blockIdx.x == 0 && threadIdx.x == 0) {
        int z = 1;
        for (int k = 1; k < 16; k += 2) z &= (ei32[k] == 0);
        *flag = z;  // 1 -> treat ei as int64
    }
}

__global__ void init_deg(int* __restrict__ degc) {
    int i = blockIdx.x * 256 + threadIdx.x;
    if (i < N_NODES) degc[i] = 1;  // self-loop
}

__global__ void count_deg(const int* __restrict__ ei32, const long long* __restrict__ ei64,
                          const int* __restrict__ flag, int* __restrict__ degc) {
    int e = blockIdx.x * 256 + threadIdx.x;
    if (e >= N_EDGES) return;
    int v = (*flag) ? (int)ei64[N_EDGES + e] : ei32[N_EDGES + e];
    atomicAdd(&degc[v], 1);
}

// ---------------- 3-phase exclusive scan of (deg-1) over N ----------------
__global__ void scan_block_sums(const int* __restrict__ degc, int* __restrict__ bsums) {
    __shared__ int sdata[256];
    int i = blockIdx.x * 256 + threadIdx.x;
    int v = degc[i] - 1;
    sdata[threadIdx.x] = v;
    __syncthreads();
    for (int s = 128; s > 0; s >>= 1) {
        if (threadIdx.x < s) sdata[threadIdx.x] += sdata[threadIdx.x + s];
        __syncthreads();
    }
    if (threadIdx.x == 0) bsums[blockIdx.x] = sdata[0];
}

__global__ void scan_bsums(int* __restrict__ bsums, int nb) {
    __shared__ int s[256];
    int t = threadIdx.x;
    int v = (t < nb) ? bsums[t] : 0;
    s[t] = v;
    __syncthreads();
    for (int off = 1; off < 256; off <<= 1) {
        int u = (t >= off) ? s[t - off] : 0;
        __syncthreads();
        s[t] += u;
        __syncthreads();
    }
    if (t < nb) bsums[t] = s[t] - v;  // exclusive
}

__global__ void scan_finalize(int* __restrict__ degc, int* __restrict__ offs,
                              float* __restrict__ dinv, const int* __restrict__ bsums) {
    __shared__ int s[256];
    int i = blockIdx.x * 256 + threadIdx.x;
    int d = degc[i];
    int v = d - 1;
    s[threadIdx.x] = v;
    __syncthreads();
    for (int off = 1; off < 256; off <<= 1) {
        int u = (threadIdx.x >= off) ? s[threadIdx.x - off] : 0;
        __syncthreads();
        s[threadIdx.x] += u;
        __syncthreads();
    }
    int excl = s[threadIdx.x] - v + bsums[blockIdx.x];
    offs[i] = excl;
    dinv[i] = rsqrtf((float)d);
    degc[i] = excl;  // becomes the fill cursor
    if (i == N_NODES - 1) offs[N_NODES] = N_EDGES;
}

__global__ void fill_csr(const int* __restrict__ ei32, const long long* __restrict__ ei64,
                         const int* __restrict__ flag, int* __restrict__ cursor,
                         int* __restrict__ csr) {
    int e = blockIdx.x * 256 + threadIdx.x;
    if (e >= N_EDGES) return;
    int u, v;
    if (*flag) { u = (int)ei64[e]; v = (int)ei64[N_EDGES + e]; }
    else       { u = ei32[e];      v = ei32[N_EDGES + e]; }
    int pos = atomicAdd(&cursor[v], 1);
    csr[pos] = u;
}

// ---------------- GEMM: Y[N,256] = X[N,64] @ W[64,256] ----------------
__global__ __launch_bounds__(256) void gemm_64_256(const float* __restrict__ X,
                                                   const float* __restrict__ W,
                                                   float* __restrict__ Y) {
    __shared__ float wl[64 * 256];
    __shared__ float xr[16 * 64];
    for (int i = threadIdx.x; i < 64 * 256; i += 256) wl[i] = W[i];
    const int ct = threadIdx.x & 63;   // col-thread, 4 cols each
    const int rg = threadIdx.x >> 6;   // row group, 4 rows each
    const int c0 = ct * 4;
    const int row0 = blockIdx.x * 64;
    for (int rb = 0; rb < 64; rb += 16) {
        __syncthreads();
        {
            const float4* src = (const float4*)(X + (size_t)(row0 + rb) * 64);
            ((float4*)xr)[threadIdx.x] = src[threadIdx.x];  // 16 rows * 64 = 256 float4
        }
        __syncthreads();
        float acc[4][4];
        #pragma unroll
        for (int r = 0; r < 4; ++r)
            #pragma unroll
            for (int cc = 0; cc < 4; ++cc) acc[r][cc] = 0.f;
        #pragma unroll
        for (int k = 0; k < 64; k += 4) {
            float4 wq[4];
            #pragma unroll
            for (int kk = 0; kk < 4; ++kk) wq[kk] = *(const float4*)&wl[(k + kk) * 256 + c0];
            #pragma unroll
            for (int r = 0; r < 4; ++r) {
                float4 xq = *(const float4*)&xr[(rg * 4 + r) * 64 + k];
                float xv[4] = {xq.x, xq.y, xq.z, xq.w};
                #pragma unroll
                for (int kk = 0; kk < 4; ++kk) {
                    acc[r][0] += xv[kk] * wq[kk].x;
                    acc[r][1] += xv[kk] * wq[kk].y;
                    acc[r][2] += xv[kk] * wq[kk].z;
                    acc[r][3] += xv[kk] * wq[kk].w;
                }
            }
        }
        #pragma unroll
        for (int r = 0; r < 4; ++r) {
            int row = row0 + rb + rg * 4 + r;
            *(float4*)&Y[(size_t)row * 256 + c0] =
                make_float4(acc[r][0], acc[r][1], acc[r][2], acc[r][3]);
        }
    }
}

// ---------------- GEMM: Y[N,64] = X[N,256] @ W[256,64] ----------------
__global__ __launch_bounds__(256) void gemm_256_64(const float* __restrict__ X,
                                                   const float* __restrict__ W,
                                                   float* __restrict__ Y) {
    __shared__ float wl[256 * 64];
    __shared__ float xr[16 * 256];
    for (int i = threadIdx.x; i < 256 * 64; i += 256) wl[i] = W[i];
    const int ct = threadIdx.x & 63;  // one col each
    const int rg = threadIdx.x >> 6;  // 4 rows each
    const int row0 = blockIdx.x * 64;
    for (int rb = 0; rb < 64; rb += 16) {
        __syncthreads();
        {
            const float4* src = (const float4*)(X + (size_t)(row0 + rb) * 256);
            float4* d4 = (float4*)xr;
            for (int i = threadIdx.x; i < 1024; i += 256) d4[i] = src[i];
        }
        __syncthreads();
        float acc[4] = {0.f, 0.f, 0.f, 0.f};
        #pragma unroll 8
        for (int k = 0; k < 256; k += 4) {
            float w0 = wl[k * 64 + ct];
            float w1 = wl[(k + 1) * 64 + ct];
            float w2 = wl[(k + 2) * 64 + ct];
            float w3 = wl[(k + 3) * 64 + ct];
            #pragma unroll
            for (int r = 0; r < 4; ++r) {
                float4 xq = *(const float4*)&xr[(rg * 4 + r) * 256 + k];
                acc[r] += xq.x * w0 + xq.y * w1 + xq.z * w2 + xq.w * w3;
            }
        }
        #pragma unroll
        for (int r = 0; r < 4; ++r)
            Y[(size_t)(row0 + rb + rg * 4 + r) * 64 + ct] = acc[r];
    }
}

// ---------------- pull max-aggregation, 256 feats: one wave per node ----------------
__global__ __launch_bounds__(256) void agg_max_f256(const float* __restrict__ xw,
        const float* __restrict__ dinv, const int* __restrict__ offs,
        const int* __restrict__ csr, const float* __restrict__ bias,
        float* __restrict__ out) {
    int gid = blockIdx.x * 256 + threadIdx.x;
    int v = gid >> 6;
    int lane = gid & 63;
    float dv = dinv[v];
    float4 a = ((const float4*)(xw + (size_t)v * 256))[lane];
    float sn = dv * dv;
    float4 acc = make_float4(a.x * sn, a.y * sn, a.z * sn, a.w * sn);
    int e1 = offs[v + 1];
    for (int e = offs[v]; e < e1; ++e) {
        int u = csr[e];
        float nrm = dinv[u] * dv;
        float4 m = ((const float4*)(xw + (size_t)u * 256))[lane];
        acc.x = fmaxf(acc.x, m.x * nrm);
        acc.y = fmaxf(acc.y, m.y * nrm);
        acc.z = fmaxf(acc.z, m.z * nrm);
        acc.w = fmaxf(acc.w, m.w * nrm);
    }
    float4 b4 = ((const float4*)bias)[lane];
    float4 o;
    o.x = fmaxf(acc.x + b4.x, 0.f);
    o.y = fmaxf(acc.y + b4.y, 0.f);
    o.z = fmaxf(acc.z + b4.z, 0.f);
    o.w = fmaxf(acc.w + b4.w, 0.f);
    ((float4*)(out + (size_t)v * 256))[lane] = o;
}

// ---------------- pull max-aggregation, 64 feats: one wave per node ----------------
__global__ __launch_bounds__(256) void agg_max_f64(const float* __restrict__ xw,
        const float* __restrict__ dinv, const int* __restrict__ offs,
        const int* __restrict__ csr, const float* __restrict__ bias,
        float* __restrict__ out) {
    int gid = blockIdx.x * 256 + threadIdx.x;
    int v = gid >> 6;
    int lane = gid & 63;
    float dv = dinv[v];
    float acc = xw[(size_t)v * 64 + lane] * dv * dv;
    int e1 = offs[v + 1];
    for (int e = offs[v]; e < e1; ++e) {
        int u = csr[e];
        float nrm = dinv[u] * dv;
        acc = fmaxf(acc, xw[(size_t)u * 64 + lane] * nrm);
    }
    out[(size_t)v * 64 + lane] = fmaxf(acc + bias[lane], 0.f);
}

// ---------------- fused self-attention: one block per graph ----------------
// x rows are block-uniform (host_idx gather) -> read via uniform addresses so
// the compiler emits s_load + SGPR-operand v_fma (scalar pipe feeds VALU).
// Softmax: 4 barriers total, wave-parallel row reductions.
template <int IN, int H>
__global__ __launch_bounds__(256) void attn_kernel(const float* __restrict__ feat,
        const int* __restrict__ host_idx,
        const float* __restrict__ aW, const float* __restrict__ ab,
        const float* __restrict__ fW, const float* __restrict__ fb,
        const float* __restrict__ gW, const float* __restrict__ gb,
        const float* __restrict__ g_in, float* __restrict__ g_out) {
    constexpr int NG = 256 / H;             // column groups per block
    constexpr int JT = (NH + NG - 1) / NG;  // host rows per group
    __shared__ float At[NH][H];
    __shared__ float red_m[NH];
    __shared__ float red_s[NH];
    __shared__ float outp[256];
    __shared__ float cat[H + 256];
    const int b = blockIdx.x;
    const int t = threadIdx.x;
    const int col = t % H;
    const int grp = t / H;
    const int wave = t >> 6;
    const int lane = t & 63;

    const float* xr[JT];
    bool valid[JT];
    #pragma unroll
    for (int jj = 0; jj < JT; ++jj) {
        int j = grp * JT + jj;
        valid[jj] = (j < NH);
        int hi = host_idx[b * NH + (valid[jj] ? j : 0)];
        xr[jj] = feat + (size_t)hi * IN;
    }
    float accA[JT], accF[JT];
    {
        float abv = ab[col], fbv = fb[col];
        #pragma unroll
        for (int jj = 0; jj < JT; ++jj) { accA[jj] = abv; accF[jj] = fbv; }
    }
    const float* wap = aW + col;
    const float* wfp = fW + col;
    #pragma unroll 4
    for (int k = 0; k < IN; ++k) {
        float wa = wap[(size_t)k * H];
        float wf = wfp[(size_t)k * H];
        #pragma unroll
        for (int jj = 0; jj < JT; ++jj) {
            float xv = xr[jj][k];           // uniform -> s_load
            accA[jj] = fmaf(xv, wa, accA[jj]);
            accF[jj] = fmaf(xv, wf, accF[jj]);
        }
    }
    // ---- softmax over feature dim (per row j) ----
    #pragma unroll
    for (int jj = 0; jj < JT; ++jj)
        if (valid[jj]) At[grp * JT + jj][col] = accA[jj];
    __syncthreads();
    for (int j = wave; j < NH; j += 4) {
        float m = -3.402823466e38f;
        #pragma unroll
        for (int q = 0; q < H / 64; ++q) m = fmaxf(m, At[j][q * 64 + lane]);
        #pragma unroll
        for (int off = 32; off; off >>= 1) m = fmaxf(m, __shfl_xor(m, off));
        if (lane == 0) red_m[j] = m;
    }
    __syncthreads();
    float p[JT];
    #pragma unroll
    for (int jj = 0; jj < JT; ++jj) {
        int j = grp * JT + jj;
        if (valid[jj]) {
            p[jj] = expf(accA[jj] - red_m[j]);
            At[j][col] = p[jj];
        }
    }
    __syncthreads();
    for (int j = wave; j < NH; j += 4) {
        float s = 0.f;
        #pragma unroll
        for (int q = 0; q < H / 64; ++q) s += At[j][q * 64 + lane];
        #pragma unroll
        for (int off = 32; off; off >>= 1) s += __shfl_xor(s, off);
        if (lane == 0) red_s[j] = s;
    }
    __syncthreads();
    float outc = 0.f;
    #pragma unroll
    for (int jj = 0; jj < JT; ++jj) {
        int j = grp * JT + jj;
        if (valid[jj]) outc += p[jj] / red_s[j] * accF[jj];
    }
    outp[t] = outc;
    cat[H + t] = g_in ? g_in[b * 256 + t] : 0.f;
    __syncthreads();
    if (t < H) {
        float o = 0.f;
        #pragma unroll
        for (int g2 = 0; g2 < NG; ++g2) o += outp[g2 * H + t];
        cat[t] = o;
    }
    __syncthreads();
    // ---- residual global update: g + cat @ gW + gb ----
    float acc = gb[t];
    const float* gwp = gW + t;
    #pragma unroll 2
    for (int i4 = 0; i4 < (H + 256) / 4; ++i4) {
        float4 cq = ((const float4*)cat)[i4];
        const float* gw4 = gwp + (size_t)i4 * 4 * 256;
        acc = fmaf(cq.x, gw4[0], acc);
        acc = fmaf(cq.y, gw4[256], acc);
        acc = fmaf(cq.z, gw4[512], acc);
        acc = fmaf(cq.w, gw4[768], acc);
    }
    g_out[b * 256 + t] = cat[H + t] + acc;
}

// ---------------- head: relu(g@o1W+o1b)@o2W+o2b ----------------
__global__ __launch_bounds__(64) void head_kernel(const float* __restrict__ g,
        const float* __restrict__ o1W, const float* __restrict__ o1b,
        const float* __restrict__ o2W, const float* __restrict__ o2b,
        float* __restrict__ out) {
    int b = blockIdx.x, t = threadIdx.x;
    const float* gr = g + (size_t)b * 256;
    float acc = o1b[t];
    #pragma unroll 8
    for (int k = 0; k < 256; ++k) acc += gr[k] * o1W[k * 64 + t];
    acc = fmaxf(acc, 0.f);
    float s = acc * o2W[t];
    #pragma unroll
    for (int off = 32; off; off >>= 1) s += __shfl_xor(s, off);
    if (t == 0) out[b] = s + o2b[0];
}

extern "C" void kernel_launch(void* const* d_in, const int* in_sizes, int n_in,
                              void* d_out, int out_size, void* d_ws, size_t ws_size,
                              hipStream_t stream) {
    (void)in_sizes; (void)n_in; (void)out_size;
    const float* x    = (const float*)d_in[0];
    const int* ei32   = (const int*)d_in[1];
    const long long* ei64 = (const long long*)d_in[1];
    const int* hidx   = (const int*)d_in[2];
    const float* W1 = (const float*)d_in[3],  *b1 = (const float*)d_in[4];
    const float* W2 = (const float*)d_in[5],  *b2 = (const float*)d_in[6];
    const float* a0W = (const float*)d_in[7],  *a0b = (const float*)d_in[8];
    const float* f0W = (const float*)d_in[9],  *f0b = (const float*)d_in[10];
    const float* g0W = (const float*)d_in[11], *g0b = (const float*)d_in[12];
    const float* a1W = (const float*)d_in[13], *a1b = (const float*)d_in[14];
    const float* f1W = (const float*)d_in[15], *f1b = (const float*)d_in[16];
    const float* g1W = (const float*)d_in[17], *g1b = (const float*)d_in[18];
    const float* a2W = (const float*)d_in[19], *a2b = (const float*)d_in[20];
    const float* f2W = (const float*)d_in[21], *f2b = (const float*)d_in[22];
    const float* g2W = (const float*)d_in[23], *g2b = (const float*)d_in[24];
    const float* o1W = (const float*)d_in[25], *o1b = (const float*)d_in[26];
    const float* o2W = (const float*)d_in[27], *o2b = (const float*)d_in[28];
    float* outp = (float*)d_out;

    char* p = (char*)d_ws;
    auto alloc = [&](size_t bytes) {
        char* r = p;
        p += (bytes + 255) & ~(size_t)255;
        return r;
    };
    float* dinv = (float*)alloc((size_t)N_NODES * 4);
    int* degc   = (int*)alloc((size_t)N_NODES * 4);
    int* offs   = (int*)alloc((size_t)(N_NODES + 1) * 4);
    int* csr    = (int*)alloc((size_t)N_EDGES * 4);
    int* bsums  = (int*)alloc(256 * 4);
    int* flag   = (int*)alloc(256);
    float* g    = (float*)alloc((size_t)B_GRAPH * 256 * 4);
    float* xw1  = (float*)alloc((size_t)N_NODES * 256 * 4);
    float* x1   = (float*)alloc((size_t)N_NODES * 256 * 4);
    // xw1 is dead after agg_max_f256 -> reuse its 52 MB region for xw2 and x2
    float* xw2  = xw1;
    float* x2   = xw1 + (size_t)N_NODES * 64;

    size_t need = (size_t)(p - (char*)d_ws);
    if (need > ws_size) {
        fprintf(stderr, "kernel_launch: ws too small (%zu needed, %zu have)\n", need, ws_size);
        return;
    }

    probe_flag<<<1, 64, 0, stream>>>(ei32, flag);
    init_deg<<<200, 256, 0, stream>>>(degc);
    count_deg<<<1600, 256, 0, stream>>>(ei32, ei64, flag, degc);
    scan_block_sums<<<200, 256, 0, stream>>>(degc, bsums);
    scan_bsums<<<1, 256, 0, stream>>>(bsums, 200);
    scan_finalize<<<200, 256, 0, stream>>>(degc, offs, dinv, bsums);
    fill_csr<<<1600, 256, 0, stream>>>(ei32, ei64, flag, degc, csr);

    gemm_64_256<<<800, 256, 0, stream>>>(x, W1, xw1);
    attn_kernel<64, 256><<<256, 256, 0, stream>>>(x, hidx, a0W, a0b, f0W, f0b, g0W, g0b,
                                                  nullptr, g);
    agg_max_f256<<<12800, 256, 0, stream>>>(xw1, dinv, offs, csr, b1, x1);
    attn_kernel<256, 256><<<256, 256, 0, stream>>>(x1, hidx, a1W, a1b, f1W, f1b, g1W, g1b,
                                                   g, g);
    gemm_256_64<<<800, 256, 0, stream>>>(x1, W2, xw2);
    agg_max_f64<<<12800, 256, 0, stream>>>(xw2, dinv, offs, csr, b2, x2);
    attn_kernel<64, 64><<<256, 256, 0, stream>>>(x2, hidx, a2W, a2b, f2W, f2b, g2W, g2b,
                                                 g, g);
    head_kernel<<<256, 64, 0, stream>>>(g, o1W, o1b, o2W, o2b, outp);
}

// Round 3
// 521.431 us; speedup vs baseline: 1.1273x; 1.0850x over previous
//
#include <hip/hip_runtime.h>
#include <math.h>
#include <stdio.h>

#define N_NODES 51200
#define N_EDGES 409600
#define B_GRAPH 256
#define NH 13

// ---------------- edge dtype probe: int64 ei has zero high words ----------------
__global__ void probe_flag(const int* __restrict__ ei32, int* __restrict__ flag) {
    if (blockIdx.x == 0 && threadIdx.x == 0) {
        int z = 1;
        for (int k = 1; k < 16; k += 2) z &= (ei32[k] == 0);
        *flag = z;  // 1 -> treat ei as int64
    }
}

__global__ void init_deg(int* __restrict__ degc) {
    int i = blockIdx.x * 256 + threadIdx.x;
    if (i < N_NODES) degc[i] = 1;  // self-loop
}

__global__ void count_deg(const int* __restrict__ ei32, const long long* __restrict__ ei64,
                          const int* __restrict__ flag, int* __restrict__ degc) {
    int e = blockIdx.x * 256 + threadIdx.x;
    if (e >= N_EDGES) return;
    int v = (*flag) ? (int)ei64[N_EDGES + e] : ei32[N_EDGES + e];
    atomicAdd(&degc[v], 1);
}

// ---------------- 3-phase exclusive scan of (deg-1) over N ----------------
__global__ void scan_block_sums(const int* __restrict__ degc, int* __restrict__ bsums) {
    __shared__ int sdata[256];
    int i = blockIdx.x * 256 + threadIdx.x;
    int v = degc[i] - 1;
    sdata[threadIdx.x] = v;
    __syncthreads();
    for (int s = 128; s > 0; s >>= 1) {
        if (threadIdx.x < s) sdata[threadIdx.x] += sdata[threadIdx.x + s];
        __syncthreads();
    }
    if (threadIdx.x == 0) bsums[blockIdx.x] = sdata[0];
}

__global__ void scan_bsums(int* __restrict__ bsums, int nb) {
    __shared__ int s[256];
    int t = threadIdx.x;
    int v = (t < nb) ? bsums[t] : 0;
    s[t] = v;
    __syncthreads();
    for (int off = 1; off < 256; off <<= 1) {
        int u = (t >= off) ? s[t - off] : 0;
        __syncthreads();
        s[t] += u;
        __syncthreads();
    }
    if (t < nb) bsums[t] = s[t] - v;  // exclusive
}

__global__ void scan_finalize(int* __restrict__ degc, int* __restrict__ offs,
                              float* __restrict__ dinv, const int* __restrict__ bsums) {
    __shared__ int s[256];
    int i = blockIdx.x * 256 + threadIdx.x;
    int d = degc[i];
    int v = d - 1;
    s[threadIdx.x] = v;
    __syncthreads();
    for (int off = 1; off < 256; off <<= 1) {
        int u = (threadIdx.x >= off) ? s[threadIdx.x - off] : 0;
        __syncthreads();
        s[threadIdx.x] += u;
        __syncthreads();
    }
    int excl = s[threadIdx.x] - v + bsums[blockIdx.x];
    offs[i] = excl;
    dinv[i] = rsqrtf((float)d);
    degc[i] = excl;  // becomes the fill cursor
    if (i == N_NODES - 1) offs[N_NODES] = N_EDGES;
}

__global__ void fill_csr(const int* __restrict__ ei32, const long long* __restrict__ ei64,
                         const int* __restrict__ flag, int* __restrict__ cursor,
                         int* __restrict__ csr) {
    int e = blockIdx.x * 256 + threadIdx.x;
    if (e >= N_EDGES) return;
    int u, v;
    if (*flag) { u = (int)ei64[e]; v = (int)ei64[N_EDGES + e]; }
    else       { u = ei32[e];      v = ei32[N_EDGES + e]; }
    int pos = atomicAdd(&cursor[v], 1);
    csr[pos] = u;
}

// ---------------- GEMM: Y[N,256] = X[N,64] @ W[64,256] ----------------
__global__ __launch_bounds__(256) void gemm_64_256(const float* __restrict__ X,
                                                   const float* __restrict__ W,
                                                   float* __restrict__ Y) {
    __shared__ float wl[64 * 256];
    __shared__ float xr[16 * 64];
    for (int i = threadIdx.x; i < 64 * 256; i += 256) wl[i] = W[i];
    const int ct = threadIdx.x & 63;   // col-thread, 4 cols each
    const int rg = threadIdx.x >> 6;   // row group, 4 rows each
    const int c0 = ct * 4;
    const int row0 = blockIdx.x * 64;
    for (int rb = 0; rb < 64; rb += 16) {
        __syncthreads();
        {
            const float4* src = (const float4*)(X + (size_t)(row0 + rb) * 64);
            ((float4*)xr)[threadIdx.x] = src[threadIdx.x];  // 16 rows * 64 = 256 float4
        }
        __syncthreads();
        float acc[4][4];
        #pragma unroll
        for (int r = 0; r < 4; ++r)
            #pragma unroll
            for (int cc = 0; cc < 4; ++cc) acc[r][cc] = 0.f;
        #pragma unroll
        for (int k = 0; k < 64; k += 4) {
            float4 wq[4];
            #pragma unroll
            for (int kk = 0; kk < 4; ++kk) wq[kk] = *(const float4*)&wl[(k + kk) * 256 + c0];
            #pragma unroll
            for (int r = 0; r < 4; ++r) {
                float4 xq = *(const float4*)&xr[(rg * 4 + r) * 64 + k];
                float xv[4] = {xq.x, xq.y, xq.z, xq.w};
                #pragma unroll
                for (int kk = 0; kk < 4; ++kk) {
                    acc[r][0] += xv[kk] * wq[kk].x;
                    acc[r][1] += xv[kk] * wq[kk].y;
                    acc[r][2] += xv[kk] * wq[kk].z;
                    acc[r][3] += xv[kk] * wq[kk].w;
                }
            }
        }
        #pragma unroll
        for (int r = 0; r < 4; ++r) {
            int row = row0 + rb + rg * 4 + r;
            *(float4*)&Y[(size_t)row * 256 + c0] =
                make_float4(acc[r][0], acc[r][1], acc[r][2], acc[r][3]);
        }
    }
}

// ---------------- GEMM: Y[N,64] = X[N,256] @ W[256,64] ----------------
__global__ __launch_bounds__(256) void gemm_256_64(const float* __restrict__ X,
                                                   const float* __restrict__ W,
                                                   float* __restrict__ Y) {
    __shared__ float wl[256 * 64];
    __shared__ float xr[16 * 256];
    for (int i = threadIdx.x; i < 256 * 64; i += 256) wl[i] = W[i];
    const int ct = threadIdx.x & 63;  // one col each
    const int rg = threadIdx.x >> 6;  // 4 rows each
    const int row0 = blockIdx.x * 64;
    for (int rb = 0; rb < 64; rb += 16) {
        __syncthreads();
        {
            const float4* src = (const float4*)(X + (size_t)(row0 + rb) * 256);
            float4* d4 = (float4*)xr;
            for (int i = threadIdx.x; i < 1024; i += 256) d4[i] = src[i];
        }
        __syncthreads();
        float acc[4] = {0.f, 0.f, 0.f, 0.f};
        #pragma unroll 8
        for (int k = 0; k < 256; k += 4) {
            float w0 = wl[k * 64 + ct];
            float w1 = wl[(k + 1) * 64 + ct];
            float w2 = wl[(k + 2) * 64 + ct];
            float w3 = wl[(k + 3) * 64 + ct];
            #pragma unroll
            for (int r = 0; r < 4; ++r) {
                float4 xq = *(const float4*)&xr[(rg * 4 + r) * 256 + k];
                acc[r] += xq.x * w0 + xq.y * w1 + xq.z * w2 + xq.w * w3;
            }
        }
        #pragma unroll
        for (int r = 0; r < 4; ++r)
            Y[(size_t)(row0 + rb + rg * 4 + r) * 64 + ct] = acc[r];
    }
}

// ---------------- pull max-aggregation, 256 feats: one wave per node ----------------
__global__ __launch_bounds__(256) void agg_max_f256(const float* __restrict__ xw,
        const float* __restrict__ dinv, const int* __restrict__ offs,
        const int* __restrict__ csr, const float* __restrict__ bias,
        float* __restrict__ out) {
    int gid = blockIdx.x * 256 + threadIdx.x;
    int v = gid >> 6;
    int lane = gid & 63;
    float dv = dinv[v];
    float4 a = ((const float4*)(xw + (size_t)v * 256))[lane];
    float sn = dv * dv;
    float4 acc = make_float4(a.x * sn, a.y * sn, a.z * sn, a.w * sn);
    int e1 = offs[v + 1];
    for (int e = offs[v]; e < e1; ++e) {
        int u = csr[e];
        float nrm = dinv[u] * dv;
        float4 m = ((const float4*)(xw + (size_t)u * 256))[lane];
        acc.x = fmaxf(acc.x, m.x * nrm);
        acc.y = fmaxf(acc.y, m.y * nrm);
        acc.z = fmaxf(acc.z, m.z * nrm);
        acc.w = fmaxf(acc.w, m.w * nrm);
    }
    float4 b4 = ((const float4*)bias)[lane];
    float4 o;
    o.x = fmaxf(acc.x + b4.x, 0.f);
    o.y = fmaxf(acc.y + b4.y, 0.f);
    o.z = fmaxf(acc.z + b4.z, 0.f);
    o.w = fmaxf(acc.w + b4.w, 0.f);
    ((float4*)(out + (size_t)v * 256))[lane] = o;
}

// ---------------- pull max-aggregation, 64 feats: one wave per node ----------------
__global__ __launch_bounds__(256) void agg_max_f64(const float* __restrict__ xw,
        const float* __restrict__ dinv, const int* __restrict__ offs,
        const int* __restrict__ csr, const float* __restrict__ bias,
        float* __restrict__ out) {
    int gid = blockIdx.x * 256 + threadIdx.x;
    int v = gid >> 6;
    int lane = gid & 63;
    float dv = dinv[v];
    float acc = xw[(size_t)v * 64 + lane] * dv * dv;
    int e1 = offs[v + 1];
    for (int e = offs[v]; e < e1; ++e) {
        int u = csr[e];
        float nrm = dinv[u] * dv;
        acc = fmaxf(acc, xw[(size_t)u * 64 + lane] * nrm);
    }
    out[(size_t)v * 64 + lane] = fmaxf(acc + bias[lane], 0.f);
}

// ---------------- fused self-attention: one block per graph ----------------
// Host rows staged in LDS (coalesced once); matmul is k-blocked: 8 weight
// scalars in registers per 4-wide k-block, x via ds_read_b128 BROADCAST
// (all lanes same address = conflict-free). All arrays constant-indexed and
// fully unrolled -> no scratch spills (the round-2 killer).
template <int IN, int H>
__global__ __launch_bounds__(256) void attn_kernel(const float* __restrict__ feat,
        const int* __restrict__ host_idx,
        const float* __restrict__ aW, const float* __restrict__ ab,
        const float* __restrict__ fW, const float* __restrict__ fb,
        const float* __restrict__ gW, const float* __restrict__ gb,
        const float* __restrict__ g_in, float* __restrict__ g_out) {
    constexpr int NG = 256 / H;             // column groups per block
    constexpr int JT = (NH + NG - 1) / NG;  // host rows per group
    __shared__ float xl[NH * IN];
    __shared__ float At[NH][H];
    __shared__ float red_m[NH];
    __shared__ float red_s[NH];
    __shared__ float outp[256];
    __shared__ float cat[H + 256];
    __shared__ int hix[NH];
    const int b = blockIdx.x;
    const int t = threadIdx.x;
    const int col = t % H;
    const int grp = t / H;
    const int wave = t >> 6;
    const int lane = t & 63;

    if (t < NH) hix[t] = host_idx[b * NH + t];
    __syncthreads();
    // stage 13 host rows into LDS, coalesced float4
    constexpr int Q4 = IN / 4;
    for (int idx = t; idx < NH * Q4; idx += 256) {
        int j = idx / Q4, q = idx - j * Q4;
        ((float4*)xl)[idx] = ((const float4*)(feat + (size_t)hix[j] * IN))[q];
    }
    __syncthreads();

    float accA[JT], accF[JT];
    {
        float abv = ab[col], fbv = fb[col];
        #pragma unroll
        for (int jj = 0; jj < JT; ++jj) { accA[jj] = abv; accF[jj] = fbv; }
    }
    const float* wap = aW + col;
    const float* wfp = fW + col;
    #pragma unroll 2
    for (int k0 = 0; k0 < IN; k0 += 4) {
        float wa0 = wap[(size_t)(k0 + 0) * H];
        float wa1 = wap[(size_t)(k0 + 1) * H];
        float wa2 = wap[(size_t)(k0 + 2) * H];
        float wa3 = wap[(size_t)(k0 + 3) * H];
        float wf0 = wfp[(size_t)(k0 + 0) * H];
        float wf1 = wfp[(size_t)(k0 + 1) * H];
        float wf2 = wfp[(size_t)(k0 + 2) * H];
        float wf3 = wfp[(size_t)(k0 + 3) * H];
        #pragma unroll
        for (int jj = 0; jj < JT; ++jj) {
            int j = grp * JT + jj;
            if (j >= NH) j = 0;  // clamp (harmless re-read; constant-folds when NG==1)
            float4 xq = *(const float4*)&xl[j * IN + k0];  // LDS broadcast
            accA[jj] = fmaf(xq.x, wa0, accA[jj]);
            accA[jj] = fmaf(xq.y, wa1, accA[jj]);
            accA[jj] = fmaf(xq.z, wa2, accA[jj]);
            accA[jj] = fmaf(xq.w, wa3, accA[jj]);
            accF[jj] = fmaf(xq.x, wf0, accF[jj]);
            accF[jj] = fmaf(xq.y, wf1, accF[jj]);
            accF[jj] = fmaf(xq.z, wf2, accF[jj]);
            accF[jj] = fmaf(xq.w, wf3, accF[jj]);
        }
    }
    // ---- softmax over feature dim (per row j), 4 barriers ----
    #pragma unroll
    for (int jj = 0; jj < JT; ++jj) {
        int j = grp * JT + jj;
        if (j < NH) At[j][col] = accA[jj];
    }
    __syncthreads();
    for (int j = wave; j < NH; j += 4) {
        float m = -3.402823466e38f;
        #pragma unroll
        for (int q = 0; q < H / 64; ++q) m = fmaxf(m, At[j][q * 64 + lane]);
        #pragma unroll
        for (int off = 32; off; off >>= 1) m = fmaxf(m, __shfl_xor(m, off));
        if (lane == 0) red_m[j] = m;
    }
    __syncthreads();
    float p[JT];
    #pragma unroll
    for (int jj = 0; jj < JT; ++jj) {
        int j = grp * JT + jj;
        if (j < NH) {
            p[jj] = expf(accA[jj] - red_m[j]);
            At[j][col] = p[jj];
        } else p[jj] = 0.f;
    }
    __syncthreads();
    for (int j = wave; j < NH; j += 4) {
        float s = 0.f;
        #pragma unroll
        for (int q = 0; q < H / 64; ++q) s += At[j][q * 64 + lane];
        #pragma unroll
        for (int off = 32; off; off >>= 1) s += __shfl_xor(s, off);
        if (lane == 0) red_s[j] = s;
    }
    __syncthreads();
    float outc = 0.f;
    #pragma unroll
    for (int jj = 0; jj < JT; ++jj) {
        int j = grp * JT + jj;
        if (j < NH) outc += p[jj] / red_s[j] * accF[jj];
    }
    outp[t] = outc;
    cat[H + t] = g_in ? g_in[b * 256 + t] : 0.f;
    __syncthreads();
    if (t < H) {
        float o = 0.f;
        #pragma unroll
        for (int g2 = 0; g2 < NG; ++g2) o += outp[g2 * H + t];
        cat[t] = o;
    }
    __syncthreads();
    // ---- residual global update: g + cat @ gW + gb ----
    float acc = gb[t];
    const float* gwp = gW + t;
    #pragma unroll 2
    for (int i4 = 0; i4 < (H + 256) / 4; ++i4) {
        float4 cq = ((const float4*)cat)[i4];
        const float* gw4 = gwp + (size_t)i4 * 4 * 256;
        acc = fmaf(cq.x, gw4[0], acc);
        acc = fmaf(cq.y, gw4[256], acc);
        acc = fmaf(cq.z, gw4[512], acc);
        acc = fmaf(cq.w, gw4[768], acc);
    }
    g_out[b * 256 + t] = cat[H + t] + acc;
}

// ---------------- head: relu(g@o1W+o1b)@o2W+o2b ----------------
__global__ __launch_bounds__(64) void head_kernel(const float* __restrict__ g,
        const float* __restrict__ o1W, const float* __restrict__ o1b,
        const float* __restrict__ o2W, const float* __restrict__ o2b,
        float* __restrict__ out) {
    int b = blockIdx.x, t = threadIdx.x;
    const float* gr = g + (size_t)b * 256;
    float acc = o1b[t];
    #pragma unroll 8
    for (int k = 0; k < 256; ++k) acc += gr[k] * o1W[k * 64 + t];
    acc = fmaxf(acc, 0.f);
    float s = acc * o2W[t];
    #pragma unroll
    for (int off = 32; off; off >>= 1) s += __shfl_xor(s, off);
    if (t == 0) out[b] = s + o2b[0];
}

extern "C" void kernel_launch(void* const* d_in, const int* in_sizes, int n_in,
                              void* d_out, int out_size, void* d_ws, size_t ws_size,
                              hipStream_t stream) {
    (void)in_sizes; (void)n_in; (void)out_size;
    const float* x    = (const float*)d_in[0];
    const int* ei32   = (const int*)d_in[1];
    const long long* ei64 = (const long long*)d_in[1];
    const int* hidx   = (const int*)d_in[2];
    const float* W1 = (const float*)d_in[3],  *b1 = (const float*)d_in[4];
    const float* W2 = (const float*)d_in[5],  *b2 = (const float*)d_in[6];
    const float* a0W = (const float*)d_in[7],  *a0b = (const float*)d_in[8];
    const float* f0W = (const float*)d_in[9],  *f0b = (const float*)d_in[10];
    const float* g0W = (const float*)d_in[11], *g0b = (const float*)d_in[12];
    const float* a1W = (const float*)d_in[13], *a1b = (const float*)d_in[14];
    const float* f1W = (const float*)d_in[15], *f1b = (const float*)d_in[16];
    const float* g1W = (const float*)d_in[17], *g1b = (const float*)d_in[18];
    const float* a2W = (const float*)d_in[19], *a2b = (const float*)d_in[20];
    const float* f2W = (const float*)d_in[21], *f2b = (const float*)d_in[22];
    const float* g2W = (const float*)d_in[23], *g2b = (const float*)d_in[24];
    const float* o1W = (const float*)d_in[25], *o1b = (const float*)d_in[26];
    const float* o2W = (const float*)d_in[27], *o2b = (const float*)d_in[28];
    float* outp = (float*)d_out;

    char* p = (char*)d_ws;
    auto alloc = [&](size_t bytes) {
        char* r = p;
        p += (bytes + 255) & ~(size_t)255;
        return r;
    };
    float* dinv = (float*)alloc((size_t)N_NODES * 4);
    int* degc   = (int*)alloc((size_t)N_NODES * 4);
    int* offs   = (int*)alloc((size_t)(N_NODES + 1) * 4);
    int* csr    = (int*)alloc((size_t)N_EDGES * 4);
    int* bsums  = (int*)alloc(256 * 4);
    int* flag   = (int*)alloc(256);
    float* g    = (float*)alloc((size_t)B_GRAPH * 256 * 4);
    float* xw1  = (float*)alloc((size_t)N_NODES * 256 * 4);
    float* x1   = (float*)alloc((size_t)N_NODES * 256 * 4);
    // xw1 is dead after agg_max_f256 -> reuse its 52 MB region for xw2 and x2
    float* xw2  = xw1;
    float* x2   = xw1 + (size_t)N_NODES * 64;

    size_t need = (size_t)(p - (char*)d_ws);
    if (need > ws_size) {
        fprintf(stderr, "kernel_launch: ws too small (%zu needed, %zu have)\n", need, ws_size);
        return;
    }

    probe_flag<<<1, 64, 0, stream>>>(ei32, flag);
    init_deg<<<200, 256, 0, stream>>>(degc);
    count_deg<<<1600, 256, 0, stream>>>(ei32, ei64, flag, degc);
    scan_block_sums<<<200, 256, 0, stream>>>(degc, bsums);
    scan_bsums<<<1, 256, 0, stream>>>(bsums, 200);
    scan_finalize<<<200, 256, 0, stream>>>(degc, offs, dinv, bsums);
    fill_csr<<<1600, 256, 0, stream>>>(ei32, ei64, flag, degc, csr);

    gemm_64_256<<<800, 256, 0, stream>>>(x, W1, xw1);
    attn_kernel<64, 256><<<256, 256, 0, stream>>>(x, hidx, a0W, a0b, f0W, f0b, g0W, g0b,
                                                  nullptr, g);
    agg_max_f256<<<12800, 256, 0, stream>>>(xw1, dinv, offs, csr, b1, x1);
    attn_kernel<256, 256><<<256, 256, 0, stream>>>(x1, hidx, a1W, a1b, f1W, f1b, g1W, g1b,
                                                   g, g);
    gemm_256_64<<<800, 256, 0, stream>>>(x1, W2, xw2);
    agg_max_f64<<<12800, 256, 0, stream>>>(xw2, dinv, offs, csr, b2, x2);
    attn_kernel<64, 64><<<256, 256, 0, stream>>>(x2, hidx, a2W, a2b, f2W, f2b, g2W, g2b,
                                                 g, g);
    head_kernel<<<256, 64, 0, stream>>>(g, o1W, o1b, o2W, o2b, outp);
}

// Round 4
// 443.032 us; speedup vs baseline: 1.3268x; 1.1770x over previous
//
#include <hip/hip_runtime.h>
#include <math.h>
#include <stdio.h>

#define N_NODES 51200
#define N_EDGES 409600
#define B_GRAPH 256
#define NH 13

// ---------------- edge dtype probe: int64 ei has zero high words ----------------
__global__ void probe_flag(const int* __restrict__ ei32, int* __restrict__ flag) {
    if (blockIdx.x == 0 && threadIdx.x == 0) {
        int z = 1;
        for (int k = 1; k < 16; k += 2) z &= (ei32[k] == 0);
        *flag = z;  // 1 -> treat ei as int64
    }
}

__global__ void init_deg(int* __restrict__ degc) {
    int i = blockIdx.x * 256 + threadIdx.x;
    if (i < N_NODES) degc[i] = 1;  // self-loop
}

__global__ void count_deg(const int* __restrict__ ei32, const long long* __restrict__ ei64,
                          const int* __restrict__ flag, int* __restrict__ degc) {
    int e = blockIdx.x * 256 + threadIdx.x;
    if (e >= N_EDGES) return;
    int v = (*flag) ? (int)ei64[N_EDGES + e] : ei32[N_EDGES + e];
    atomicAdd(&degc[v], 1);
}

// ---------------- 3-phase exclusive scan of (deg-1) over N ----------------
__global__ void scan_block_sums(const int* __restrict__ degc, int* __restrict__ bsums) {
    __shared__ int sdata[256];
    int i = blockIdx.x * 256 + threadIdx.x;
    int v = degc[i] - 1;
    sdata[threadIdx.x] = v;
    __syncthreads();
    for (int s = 128; s > 0; s >>= 1) {
        if (threadIdx.x < s) sdata[threadIdx.x] += sdata[threadIdx.x + s];
        __syncthreads();
    }
    if (threadIdx.x == 0) bsums[blockIdx.x] = sdata[0];
}

__global__ void scan_bsums(int* __restrict__ bsums, int nb) {
    __shared__ int s[256];
    int t = threadIdx.x;
    int v = (t < nb) ? bsums[t] : 0;
    s[t] = v;
    __syncthreads();
    for (int off = 1; off < 256; off <<= 1) {
        int u = (t >= off) ? s[t - off] : 0;
        __syncthreads();
        s[t] += u;
        __syncthreads();
    }
    if (t < nb) bsums[t] = s[t] - v;  // exclusive
}

__global__ void scan_finalize(int* __restrict__ degc, int* __restrict__ offs,
                              float* __restrict__ dinv, const int* __restrict__ bsums) {
    __shared__ int s[256];
    int i = blockIdx.x * 256 + threadIdx.x;
    int d = degc[i];
    int v = d - 1;
    s[threadIdx.x] = v;
    __syncthreads();
    for (int off = 1; off < 256; off <<= 1) {
        int u = (threadIdx.x >= off) ? s[threadIdx.x - off] : 0;
        __syncthreads();
        s[threadIdx.x] += u;
        __syncthreads();
    }
    int excl = s[threadIdx.x] - v + bsums[blockIdx.x];
    offs[i] = excl;
    dinv[i] = rsqrtf((float)d);
    degc[i] = excl;  // becomes the fill cursor
    if (i == N_NODES - 1) offs[N_NODES] = N_EDGES;
}

__global__ void fill_csr(const int* __restrict__ ei32, const long long* __restrict__ ei64,
                         const int* __restrict__ flag, int* __restrict__ cursor,
                         int* __restrict__ csr) {
    int e = blockIdx.x * 256 + threadIdx.x;
    if (e >= N_EDGES) return;
    int u, v;
    if (*flag) { u = (int)ei64[e]; v = (int)ei64[N_EDGES + e]; }
    else       { u = ei32[e];      v = ei32[N_EDGES + e]; }
    int pos = atomicAdd(&cursor[v], 1);
    csr[pos] = u;
}

// ---------------- unified tiled GEMM: Y[N, NTOT] = X[N, K] @ W[K, NTOT] ----------------
// Block tile 64x64, thread tile 4x4, BK=32. LDS ~17 KB -> 4-6 blocks/CU
// (round-3 killer was 80 KB LDS -> 2 blocks/CU -> latency-bound at 1 wave/SIMD).
// xs stride 36 floats (144 B): 16B-aligned rows for b128, bank-group spread.
template <int K, int NTOT>
__global__ __launch_bounds__(256) void gemm_tile(const float* __restrict__ X,
                                                 const float* __restrict__ W,
                                                 float* __restrict__ Y) {
    constexpr int BK = 32;
    constexpr int XS = BK + 4;  // 36
    __shared__ float xs[64 * XS];
    __shared__ float ws[BK * 64];
    constexpr int nColBlk = NTOT / 64;
    const int rb = blockIdx.x / nColBlk;
    const int cb = blockIdx.x - rb * nColBlk;
    const int row0 = rb * 64;
    const int c0 = cb * 64;
    const int t = threadIdx.x;
    const int ct = t & 15;
    const int rt = t >> 4;
    float acc[4][4] = {{0.f}};
    for (int kc = 0; kc < K; kc += BK) {
        __syncthreads();
        // stage x: 64 rows x BK = 512 float4, 2 per thread (coalesced 128B runs)
        #pragma unroll
        for (int i = 0; i < 2; ++i) {
            int idx = t + i * 256;
            int q = idx & 7, r = idx >> 3;
            float4 v = *(const float4*)(X + (size_t)(row0 + r) * K + kc + q * 4);
            *(float4*)&xs[r * XS + q * 4] = v;
        }
        // stage w: BK x 64 = 512 float4, 2 per thread (coalesced 256B runs)
        #pragma unroll
        for (int i = 0; i < 2; ++i) {
            int idx = t + i * 256;
            int q = idx & 15, k = idx >> 4;
            float4 v = *(const float4*)(W + (size_t)(kc + k) * NTOT + c0 + q * 4);
            *(float4*)&ws[k * 64 + q * 4] = v;
        }
        __syncthreads();
        #pragma unroll
        for (int kb = 0; kb < BK; kb += 4) {
            float4 wv[4];
            #pragma unroll
            for (int kk = 0; kk < 4; ++kk)
                wv[kk] = *(const float4*)&ws[(kb + kk) * 64 + ct * 4];
            #pragma unroll
            for (int r = 0; r < 4; ++r) {
                float4 xv = *(const float4*)&xs[(rt * 4 + r) * XS + kb];
                acc[r][0] = fmaf(xv.x, wv[0].x, acc[r][0]);
                acc[r][1] = fmaf(xv.x, wv[0].y, acc[r][1]);
                acc[r][2] = fmaf(xv.x, wv[0].z, acc[r][2]);
                acc[r][3] = fmaf(xv.x, wv[0].w, acc[r][3]);
                acc[r][0] = fmaf(xv.y, wv[1].x, acc[r][0]);
                acc[r][1] = fmaf(xv.y, wv[1].y, acc[r][1]);
                acc[r][2] = fmaf(xv.y, wv[1].z, acc[r][2]);
                acc[r][3] = fmaf(xv.y, wv[1].w, acc[r][3]);
                acc[r][0] = fmaf(xv.z, wv[2].x, acc[r][0]);
                acc[r][1] = fmaf(xv.z, wv[2].y, acc[r][1]);
                acc[r][2] = fmaf(xv.z, wv[2].z, acc[r][2]);
                acc[r][3] = fmaf(xv.z, wv[2].w, acc[r][3]);
                acc[r][0] = fmaf(xv.w, wv[3].x, acc[r][0]);
                acc[r][1] = fmaf(xv.w, wv[3].y, acc[r][1]);
                acc[r][2] = fmaf(xv.w, wv[3].z, acc[r][2]);
                acc[r][3] = fmaf(xv.w, wv[3].w, acc[r][3]);
            }
        }
    }
    #pragma unroll
    for (int r = 0; r < 4; ++r) {
        int row = row0 + rt * 4 + r;
        *(float4*)&Y[(size_t)row * NTOT + c0 + ct * 4] =
            make_float4(acc[r][0], acc[r][1], acc[r][2], acc[r][3]);
    }
}

// ---------------- pull max-aggregation, 256 feats: one wave per node ----------------
__global__ __launch_bounds__(256) void agg_max_f256(const float* __restrict__ xw,
        const float* __restrict__ dinv, const int* __restrict__ offs,
        const int* __restrict__ csr, const float* __restrict__ bias,
        float* __restrict__ out) {
    int gid = blockIdx.x * 256 + threadIdx.x;
    int v = gid >> 6;
    int lane = gid & 63;
    float dv = dinv[v];
    float4 a = ((const float4*)(xw + (size_t)v * 256))[lane];
    float sn = dv * dv;
    float4 acc = make_float4(a.x * sn, a.y * sn, a.z * sn, a.w * sn);
    int e1 = offs[v + 1];
    for (int e = offs[v]; e < e1; ++e) {
        int u = csr[e];
        float nrm = dinv[u] * dv;
        float4 m = ((const float4*)(xw + (size_t)u * 256))[lane];
        acc.x = fmaxf(acc.x, m.x * nrm);
        acc.y = fmaxf(acc.y, m.y * nrm);
        acc.z = fmaxf(acc.z, m.z * nrm);
        acc.w = fmaxf(acc.w, m.w * nrm);
    }
    float4 b4 = ((const float4*)bias)[lane];
    float4 o;
    o.x = fmaxf(acc.x + b4.x, 0.f);
    o.y = fmaxf(acc.y + b4.y, 0.f);
    o.z = fmaxf(acc.z + b4.z, 0.f);
    o.w = fmaxf(acc.w + b4.w, 0.f);
    ((float4*)(out + (size_t)v * 256))[lane] = o;
}

// ---------------- pull max-aggregation, 64 feats: one wave per node ----------------
__global__ __launch_bounds__(256) void agg_max_f64(const float* __restrict__ xw,
        const float* __restrict__ dinv, const int* __restrict__ offs,
        const int* __restrict__ csr, const float* __restrict__ bias,
        float* __restrict__ out) {
    int gid = blockIdx.x * 256 + threadIdx.x;
    int v = gid >> 6;
    int lane = gid & 63;
    float dv = dinv[v];
    float acc = xw[(size_t)v * 64 + lane] * dv * dv;
    int e1 = offs[v + 1];
    for (int e = offs[v]; e < e1; ++e) {
        int u = csr[e];
        float nrm = dinv[u] * dv;
        acc = fmaxf(acc, xw[(size_t)u * 64 + lane] * nrm);
    }
    out[(size_t)v * 64 + lane] = fmaxf(acc + bias[lane], 0.f);
}

// ---------------- fused self-attention: one block per graph ----------------
template <int IN, int H>
__global__ __launch_bounds__(256) void attn_kernel(const float* __restrict__ feat,
        const int* __restrict__ host_idx,
        const float* __restrict__ aW, const float* __restrict__ ab,
        const float* __restrict__ fW, const float* __restrict__ fb,
        const float* __restrict__ gW, const float* __restrict__ gb,
        const float* __restrict__ g_in, float* __restrict__ g_out) {
    constexpr int NG = 256 / H;             // column groups per block
    constexpr int JT = (NH + NG - 1) / NG;  // host rows per group
    __shared__ float xl[NH * IN];
    __shared__ float At[NH][H];
    __shared__ float red_m[NH];
    __shared__ float red_s[NH];
    __shared__ float outp[256];
    __shared__ float cat[H + 256];
    __shared__ int hix[NH];
    const int b = blockIdx.x;
    const int t = threadIdx.x;
    const int col = t % H;
    const int grp = t / H;
    const int wave = t >> 6;
    const int lane = t & 63;

    if (t < NH) hix[t] = host_idx[b * NH + t];
    __syncthreads();
    constexpr int Q4 = IN / 4;
    for (int idx = t; idx < NH * Q4; idx += 256) {
        int j = idx / Q4, q = idx - j * Q4;
        ((float4*)xl)[idx] = ((const float4*)(feat + (size_t)hix[j] * IN))[q];
    }
    __syncthreads();

    float accA[JT], accF[JT];
    {
        float abv = ab[col], fbv = fb[col];
        #pragma unroll
        for (int jj = 0; jj < JT; ++jj) { accA[jj] = abv; accF[jj] = fbv; }
    }
    const float* wap = aW + col;
    const float* wfp = fW + col;
    #pragma unroll 2
    for (int k0 = 0; k0 < IN; k0 += 4) {
        float wa0 = wap[(size_t)(k0 + 0) * H];
        float wa1 = wap[(size_t)(k0 + 1) * H];
        float wa2 = wap[(size_t)(k0 + 2) * H];
        float wa3 = wap[(size_t)(k0 + 3) * H];
        float wf0 = wfp[(size_t)(k0 + 0) * H];
        float wf1 = wfp[(size_t)(k0 + 1) * H];
        float wf2 = wfp[(size_t)(k0 + 2) * H];
        float wf3 = wfp[(size_t)(k0 + 3) * H];
        #pragma unroll
        for (int jj = 0; jj < JT; ++jj) {
            int j = grp * JT + jj;
            if (j >= NH) j = 0;
            float4 xq = *(const float4*)&xl[j * IN + k0];  // LDS broadcast
            accA[jj] = fmaf(xq.x, wa0, accA[jj]);
            accA[jj] = fmaf(xq.y, wa1, accA[jj]);
            accA[jj] = fmaf(xq.z, wa2, accA[jj]);
            accA[jj] = fmaf(xq.w, wa3, accA[jj]);
            accF[jj] = fmaf(xq.x, wf0, accF[jj]);
            accF[jj] = fmaf(xq.y, wf1, accF[jj]);
            accF[jj] = fmaf(xq.z, wf2, accF[jj]);
            accF[jj] = fmaf(xq.w, wf3, accF[jj]);
        }
    }
    #pragma unroll
    for (int jj = 0; jj < JT; ++jj) {
        int j = grp * JT + jj;
        if (j < NH) At[j][col] = accA[jj];
    }
    __syncthreads();
    for (int j = wave; j < NH; j += 4) {
        float m = -3.402823466e38f;
        #pragma unroll
        for (int q = 0; q < H / 64; ++q) m = fmaxf(m, At[j][q * 64 + lane]);
        #pragma unroll
        for (int off = 32; off; off >>= 1) m = fmaxf(m, __shfl_xor(m, off));
        if (lane == 0) red_m[j] = m;
    }
    __syncthreads();
    float p[JT];
    #pragma unroll
    for (int jj = 0; jj < JT; ++jj) {
        int j = grp * JT + jj;
        if (j < NH) {
            p[jj] = expf(accA[jj] - red_m[j]);
            At[j][col] = p[jj];
        } else p[jj] = 0.f;
    }
    __syncthreads();
    for (int j = wave; j < NH; j += 4) {
        float s = 0.f;
        #pragma unroll
        for (int q = 0; q < H / 64; ++q) s += At[j][q * 64 + lane];
        #pragma unroll
        for (int off = 32; off; off >>= 1) s += __shfl_xor(s, off);
        if (lane == 0) red_s[j] = s;
    }
    __syncthreads();
    float outc = 0.f;
    #pragma unroll
    for (int jj = 0; jj < JT; ++jj) {
        int j = grp * JT + jj;
        if (j < NH) outc += p[jj] / red_s[j] * accF[jj];
    }
    outp[t] = outc;
    cat[H + t] = g_in ? g_in[b * 256 + t] : 0.f;
    __syncthreads();
    if (t < H) {
        float o = 0.f;
        #pragma unroll
        for (int g2 = 0; g2 < NG; ++g2) o += outp[g2 * H + t];
        cat[t] = o;
    }
    __syncthreads();
    float acc = gb[t];
    const float* gwp = gW + t;
    #pragma unroll 2
    for (int i4 = 0; i4 < (H + 256) / 4; ++i4) {
        float4 cq = ((const float4*)cat)[i4];
        const float* gw4 = gwp + (size_t)i4 * 4 * 256;
        acc = fmaf(cq.x, gw4[0], acc);
        acc = fmaf(cq.y, gw4[256], acc);
        acc = fmaf(cq.z, gw4[512], acc);
        acc = fmaf(cq.w, gw4[768], acc);
    }
    g_out[b * 256 + t] = cat[H + t] + acc;
}

// ---------------- head: relu(g@o1W+o1b)@o2W+o2b ----------------
__global__ __launch_bounds__(64) void head_kernel(const float* __restrict__ g,
        const float* __restrict__ o1W, const float* __restrict__ o1b,
        const float* __restrict__ o2W, const float* __restrict__ o2b,
        float* __restrict__ out) {
    int b = blockIdx.x, t = threadIdx.x;
    const float* gr = g + (size_t)b * 256;
    float acc = o1b[t];
    #pragma unroll 8
    for (int k = 0; k < 256; ++k) acc += gr[k] * o1W[k * 64 + t];
    acc = fmaxf(acc, 0.f);
    float s = acc * o2W[t];
    #pragma unroll
    for (int off = 32; off; off >>= 1) s += __shfl_xor(s, off);
    if (t == 0) out[b] = s + o2b[0];
}

extern "C" void kernel_launch(void* const* d_in, const int* in_sizes, int n_in,
                              void* d_out, int out_size, void* d_ws, size_t ws_size,
                              hipStream_t stream) {
    (void)in_sizes; (void)n_in; (void)out_size;
    const float* x    = (const float*)d_in[0];
    const int* ei32   = (const int*)d_in[1];
    const long long* ei64 = (const long long*)d_in[1];
    const int* hidx   = (const int*)d_in[2];
    const float* W1 = (const float*)d_in[3],  *b1 = (const float*)d_in[4];
    const float* W2 = (const float*)d_in[5],  *b2 = (const float*)d_in[6];
    const float* a0W = (const float*)d_in[7],  *a0b = (const float*)d_in[8];
    const float* f0W = (const float*)d_in[9],  *f0b = (const float*)d_in[10];
    const float* g0W = (const float*)d_in[11], *g0b = (const float*)d_in[12];
    const float* a1W = (const float*)d_in[13], *a1b = (const float*)d_in[14];
    const float* f1W = (const float*)d_in[15], *f1b = (const float*)d_in[16];
    const float* g1W = (const float*)d_in[17], *g1b = (const float*)d_in[18];
    const float* a2W = (const float*)d_in[19], *a2b = (const float*)d_in[20];
    const float* f2W = (const float*)d_in[21], *f2b = (const float*)d_in[22];
    const float* g2W = (const float*)d_in[23], *g2b = (const float*)d_in[24];
    const float* o1W = (const float*)d_in[25], *o1b = (const float*)d_in[26];
    const float* o2W = (const float*)d_in[27], *o2b = (const float*)d_in[28];
    float* outp = (float*)d_out;

    char* p = (char*)d_ws;
    auto alloc = [&](size_t bytes) {
        char* r = p;
        p += (bytes + 255) & ~(size_t)255;
        return r;
    };
    float* dinv = (float*)alloc((size_t)N_NODES * 4);
    int* degc   = (int*)alloc((size_t)N_NODES * 4);
    int* offs   = (int*)alloc((size_t)(N_NODES + 1) * 4);
    int* csr    = (int*)alloc((size_t)N_EDGES * 4);
    int* bsums  = (int*)alloc(256 * 4);
    int* flag   = (int*)alloc(256);
    float* g    = (float*)alloc((size_t)B_GRAPH * 256 * 4);
    float* xw1  = (float*)alloc((size_t)N_NODES * 256 * 4);
    float* x1   = (float*)alloc((size_t)N_NODES * 256 * 4);
    // xw1 is dead after agg_max_f256 -> reuse its 52 MB region for xw2 and x2
    float* xw2  = xw1;
    float* x2   = xw1 + (size_t)N_NODES * 64;

    size_t need = (size_t)(p - (char*)d_ws);
    if (need > ws_size) {
        fprintf(stderr, "kernel_launch: ws too small (%zu needed, %zu have)\n", need, ws_size);
        return;
    }

    probe_flag<<<1, 64, 0, stream>>>(ei32, flag);
    init_deg<<<200, 256, 0, stream>>>(degc);
    count_deg<<<1600, 256, 0, stream>>>(ei32, ei64, flag, degc);
    scan_block_sums<<<200, 256, 0, stream>>>(degc, bsums);
    scan_bsums<<<1, 256, 0, stream>>>(bsums, 200);
    scan_finalize<<<200, 256, 0, stream>>>(degc, offs, dinv, bsums);
    fill_csr<<<1600, 256, 0, stream>>>(ei32, ei64, flag, degc, csr);

    gemm_tile<64, 256><<<800 * 4, 256, 0, stream>>>(x, W1, xw1);
    attn_kernel<64, 256><<<256, 256, 0, stream>>>(x, hidx, a0W, a0b, f0W, f0b, g0W, g0b,
                                                  nullptr, g);
    agg_max_f256<<<12800, 256, 0, stream>>>(xw1, dinv, offs, csr, b1, x1);
    attn_kernel<256, 256><<<256, 256, 0, stream>>>(x1, hidx, a1W, a1b, f1W, f1b, g1W, g1b,
                                                   g, g);
    gemm_tile<256, 64><<<800, 256, 0, stream>>>(x1, W2, xw2);
    agg_max_f64<<<12800, 256, 0, stream>>>(xw2, dinv, offs, csr, b2, x2);
    attn_kernel<64, 64><<<256, 256, 0, stream>>>(x2, hidx, a2W, a2b, f2W, f2b, g2W, g2b,
                                                 g, g);
    head_kernel<<<256, 64, 0, stream>>>(g, o1W, o1b, o2W, o2b, outp);
}

// Round 5
// 439.507 us; speedup vs baseline: 1.3375x; 1.0080x over previous
//
#include <hip/hip_runtime.h>
#include <math.h>
#include <stdio.h>

#define N_NODES 51200
#define N_EDGES 409600
#define B_GRAPH 256
#define NH 13

// ---------------- edge dtype probe: int64 ei has zero high words ----------------
__global__ void probe_flag(const int* __restrict__ ei32, int* __restrict__ flag) {
    if (blockIdx.x == 0 && threadIdx.x == 0) {
        int z = 1;
        for (int k = 1; k < 16; k += 2) z &= (ei32[k] == 0);
        *flag = z;  // 1 -> treat ei as int64
    }
}

__global__ void init_deg(int* __restrict__ degc) {
    int i = blockIdx.x * 256 + threadIdx.x;
    if (i < N_NODES) degc[i] = 1;  // self-loop
}

__global__ void count_deg(const int* __restrict__ ei32, const long long* __restrict__ ei64,
                          const int* __restrict__ flag, int* __restrict__ degc) {
    int e = blockIdx.x * 256 + threadIdx.x;
    if (e >= N_EDGES) return;
    int v = (*flag) ? (int)ei64[N_EDGES + e] : ei32[N_EDGES + e];
    atomicAdd(&degc[v], 1);
}

// ---------------- 3-phase exclusive scan of (deg-1) over N ----------------
__global__ void scan_block_sums(const int* __restrict__ degc, int* __restrict__ bsums) {
    __shared__ int sdata[256];
    int i = blockIdx.x * 256 + threadIdx.x;
    int v = degc[i] - 1;
    sdata[threadIdx.x] = v;
    __syncthreads();
    for (int s = 128; s > 0; s >>= 1) {
        if (threadIdx.x < s) sdata[threadIdx.x] += sdata[threadIdx.x + s];
        __syncthreads();
    }
    if (threadIdx.x == 0) bsums[blockIdx.x] = sdata[0];
}

__global__ void scan_bsums(int* __restrict__ bsums, int nb) {
    __shared__ int s[256];
    int t = threadIdx.x;
    int v = (t < nb) ? bsums[t] : 0;
    s[t] = v;
    __syncthreads();
    for (int off = 1; off < 256; off <<= 1) {
        int u = (t >= off) ? s[t - off] : 0;
        __syncthreads();
        s[t] += u;
        __syncthreads();
    }
    if (t < nb) bsums[t] = s[t] - v;  // exclusive
}

__global__ void scan_finalize(int* __restrict__ degc, int* __restrict__ offs,
                              float* __restrict__ dinv, const int* __restrict__ bsums) {
    __shared__ int s[256];
    int i = blockIdx.x * 256 + threadIdx.x;
    int d = degc[i];
    int v = d - 1;
    s[threadIdx.x] = v;
    __syncthreads();
    for (int off = 1; off < 256; off <<= 1) {
        int u = (threadIdx.x >= off) ? s[threadIdx.x - off] : 0;
        __syncthreads();
        s[threadIdx.x] += u;
        __syncthreads();
    }
    int excl = s[threadIdx.x] - v + bsums[blockIdx.x];
    offs[i] = excl;
    dinv[i] = rsqrtf((float)d);
    degc[i] = excl;  // becomes the fill cursor
    if (i == N_NODES - 1) offs[N_NODES] = N_EDGES;
}

// fill CSR and per-edge norm = dinv[u]*dinv[v] (removes one chase level in agg)
__global__ void fill_csr(const int* __restrict__ ei32, const long long* __restrict__ ei64,
                         const int* __restrict__ flag, const float* __restrict__ dinv,
                         int* __restrict__ cursor, int* __restrict__ csr,
                         float* __restrict__ nrmv) {
    int e = blockIdx.x * 256 + threadIdx.x;
    if (e >= N_EDGES) return;
    int u, v;
    if (*flag) { u = (int)ei64[e]; v = (int)ei64[N_EDGES + e]; }
    else       { u = ei32[e];      v = ei32[N_EDGES + e]; }
    int pos = atomicAdd(&cursor[v], 1);
    csr[pos] = u;
    nrmv[pos] = dinv[u] * dinv[v];
}

// ---------------- unified tiled GEMM: Y[N, NTOT] = X[N, K] @ W[K, NTOT] ----------------
template <int K, int NTOT>
__global__ __launch_bounds__(256) void gemm_tile(const float* __restrict__ X,
                                                 const float* __restrict__ W,
                                                 float* __restrict__ Y) {
    constexpr int BK = 32;
    constexpr int XS = BK + 4;  // 36
    __shared__ float xs[64 * XS];
    __shared__ float ws[BK * 64];
    constexpr int nColBlk = NTOT / 64;
    const int rb = blockIdx.x / nColBlk;
    const int cb = blockIdx.x - rb * nColBlk;
    const int row0 = rb * 64;
    const int c0 = cb * 64;
    const int t = threadIdx.x;
    const int ct = t & 15;
    const int rt = t >> 4;
    float acc[4][4] = {{0.f}};
    for (int kc = 0; kc < K; kc += BK) {
        __syncthreads();
        #pragma unroll
        for (int i = 0; i < 2; ++i) {
            int idx = t + i * 256;
            int q = idx & 7, r = idx >> 3;
            float4 v = *(const float4*)(X + (size_t)(row0 + r) * K + kc + q * 4);
            *(float4*)&xs[r * XS + q * 4] = v;
        }
        #pragma unroll
        for (int i = 0; i < 2; ++i) {
            int idx = t + i * 256;
            int q = idx & 15, k = idx >> 4;
            float4 v = *(const float4*)(W + (size_t)(kc + k) * NTOT + c0 + q * 4);
            *(float4*)&ws[k * 64 + q * 4] = v;
        }
        __syncthreads();
        #pragma unroll
        for (int kb = 0; kb < BK; kb += 4) {
            float4 wv[4];
            #pragma unroll
            for (int kk = 0; kk < 4; ++kk)
                wv[kk] = *(const float4*)&ws[(kb + kk) * 64 + ct * 4];
            #pragma unroll
            for (int r = 0; r < 4; ++r) {
                float4 xv = *(const float4*)&xs[(rt * 4 + r) * XS + kb];
                acc[r][0] = fmaf(xv.x, wv[0].x, acc[r][0]);
                acc[r][1] = fmaf(xv.x, wv[0].y, acc[r][1]);
                acc[r][2] = fmaf(xv.x, wv[0].z, acc[r][2]);
                acc[r][3] = fmaf(xv.x, wv[0].w, acc[r][3]);
                acc[r][0] = fmaf(xv.y, wv[1].x, acc[r][0]);
                acc[r][1] = fmaf(xv.y, wv[1].y, acc[r][1]);
                acc[r][2] = fmaf(xv.y, wv[1].z, acc[r][2]);
                acc[r][3] = fmaf(xv.y, wv[1].w, acc[r][3]);
                acc[r][0] = fmaf(xv.z, wv[2].x, acc[r][0]);
                acc[r][1] = fmaf(xv.z, wv[2].y, acc[r][1]);
                acc[r][2] = fmaf(xv.z, wv[2].z, acc[r][2]);
                acc[r][3] = fmaf(xv.z, wv[2].w, acc[r][3]);
                acc[r][0] = fmaf(xv.w, wv[3].x, acc[r][0]);
                acc[r][1] = fmaf(xv.w, wv[3].y, acc[r][1]);
                acc[r][2] = fmaf(xv.w, wv[3].z, acc[r][2]);
                acc[r][3] = fmaf(xv.w, wv[3].w, acc[r][3]);
            }
        }
    }
    #pragma unroll
    for (int r = 0; r < 4; ++r) {
        int row = row0 + rt * 4 + r;
        *(float4*)&Y[(size_t)row * NTOT + c0 + ct * 4] =
            make_float4(acc[r][0], acc[r][1], acc[r][2], acc[r][3]);
    }
}

// ---- attention phase A: AF[3328, 2H] = x[host_idx] @ [aW | fW] + [ab | fb] ----
// Same tile structure as gemm_tile, rows gathered via host_idx; each 64-wide
// col-block lies entirely in A or F (H % 64 == 0) so W/bias pointer is
// block-uniform.
template <int K, int H>
__global__ __launch_bounds__(256) void gemm_af(const float* __restrict__ X,
        const int* __restrict__ host_idx,
        const float* __restrict__ aW, const float* __restrict__ ab,
        const float* __restrict__ fW, const float* __restrict__ fb,
        float* __restrict__ AF) {
    constexpr int NTOT = 2 * H;
    constexpr int BK = 32;
    constexpr int XS = BK + 4;
    __shared__ float xs[64 * XS];
    __shared__ float ws[BK * 64];
    __shared__ int rows[64];
    constexpr int nColBlk = NTOT / 64;
    const int rb = blockIdx.x / nColBlk;
    const int cb = blockIdx.x - rb * nColBlk;
    const int row0 = rb * 64;
    const int c0 = cb * 64;
    const float* W    = (c0 < H) ? (aW + c0) : (fW + (c0 - H));
    const float* bias = (c0 < H) ? (ab + c0) : (fb + (c0 - H));
    const int t = threadIdx.x;
    const int ct = t & 15;
    const int rt = t >> 4;
    if (t < 64) rows[t] = host_idx[row0 + t];
    float acc[4][4] = {{0.f}};
    for (int kc = 0; kc < K; kc += BK) {
        __syncthreads();
        #pragma unroll
        for (int i = 0; i < 2; ++i) {
            int idx = t + i * 256;
            int q = idx & 7, r = idx >> 3;
            float4 v = *(const float4*)(X + (size_t)rows[r] * K + kc + q * 4);
            *(float4*)&xs[r * XS + q * 4] = v;
        }
        #pragma unroll
        for (int i = 0; i < 2; ++i) {
            int idx = t + i * 256;
            int q = idx & 15, k = idx >> 4;
            float4 v = *(const float4*)(W + (size_t)(kc + k) * H + q * 4);
            *(float4*)&ws[k * 64 + q * 4] = v;
        }
        __syncthreads();
        #pragma unroll
        for (int kb = 0; kb < BK; kb += 4) {
            float4 wv[4];
            #pragma unroll
            for (int kk = 0; kk < 4; ++kk)
                wv[kk] = *(const float4*)&ws[(kb + kk) * 64 + ct * 4];
            #pragma unroll
            for (int r = 0; r < 4; ++r) {
                float4 xv = *(const float4*)&xs[(rt * 4 + r) * XS + kb];
                acc[r][0] = fmaf(xv.x, wv[0].x, acc[r][0]);
                acc[r][1] = fmaf(xv.x, wv[0].y, acc[r][1]);
                acc[r][2] = fmaf(xv.x, wv[0].z, acc[r][2]);
                acc[r][3] = fmaf(xv.x, wv[0].w, acc[r][3]);
                acc[r][0] = fmaf(xv.y, wv[1].x, acc[r][0]);
                acc[r][1] = fmaf(xv.y, wv[1].y, acc[r][1]);
                acc[r][2] = fmaf(xv.y, wv[1].z, acc[r][2]);
                acc[r][3] = fmaf(xv.y, wv[1].w, acc[r][3]);
                acc[r][0] = fmaf(xv.z, wv[2].x, acc[r][0]);
                acc[r][1] = fmaf(xv.z, wv[2].y, acc[r][1]);
                acc[r][2] = fmaf(xv.z, wv[2].z, acc[r][2]);
                acc[r][3] = fmaf(xv.z, wv[2].w, acc[r][3]);
                acc[r][0] = fmaf(xv.w, wv[3].x, acc[r][0]);
                acc[r][1] = fmaf(xv.w, wv[3].y, acc[r][1]);
                acc[r][2] = fmaf(xv.w, wv[3].z, acc[r][2]);
                acc[r][3] = fmaf(xv.w, wv[3].w, acc[r][3]);
            }
        }
    }
    #pragma unroll
    for (int r = 0; r < 4; ++r) {
        int row = row0 + rt * 4 + r;
        float4 o = make_float4(acc[r][0] + bias[ct * 4 + 0],
                               acc[r][1] + bias[ct * 4 + 1],
                               acc[r][2] + bias[ct * 4 + 2],
                               acc[r][3] + bias[ct * 4 + 3]);
        *(float4*)&AF[(size_t)row * NTOT + c0 + ct * 4] = o;
    }
}

// ---- attention phase B: softmax + weighted sum + residual global update ----
template <int H>
__global__ __launch_bounds__(256) void attn_reduce(const float* __restrict__ AF,
        const float* __restrict__ gW, const float* __restrict__ gb,
        const float* __restrict__ g_in, float* __restrict__ g_out) {
    constexpr int NG = 256 / H;
    constexpr int JT = (NH + NG - 1) / NG;
    constexpr int NTOT = 2 * H;
    __shared__ float At[NH][H];
    __shared__ float red_m[NH];
    __shared__ float red_s[NH];
    __shared__ float outp[256];
    __shared__ float cat[H + 256];
    const int b = blockIdx.x;
    const int t = threadIdx.x;
    const int col = t % H;
    const int grp = t / H;
    const int wave = t >> 6;
    const int lane = t & 63;

    float accA[JT], accF[JT];
    #pragma unroll
    for (int jj = 0; jj < JT; ++jj) {
        int j = grp * JT + jj;
        if (j < NH) {
            const float* r = AF + (size_t)(b * NH + j) * NTOT;
            accA[jj] = r[col];
            accF[jj] = r[H + col];
            At[j][col] = accA[jj];
        } else { accA[jj] = 0.f; accF[jj] = 0.f; }
    }
    __syncthreads();
    for (int j = wave; j < NH; j += 4) {
        float m = -3.402823466e38f;
        #pragma unroll
        for (int q = 0; q < H / 64; ++q) m = fmaxf(m, At[j][q * 64 + lane]);
        #pragma unroll
        for (int off = 32; off; off >>= 1) m = fmaxf(m, __shfl_xor(m, off));
        if (lane == 0) red_m[j] = m;
    }
    __syncthreads();
    #pragma unroll
    for (int jj = 0; jj < JT; ++jj) {
        int j = grp * JT + jj;
        if (j < NH) At[j][col] = expf(accA[jj] - red_m[j]);
    }
    __syncthreads();
    for (int j = wave; j < NH; j += 4) {
        float s = 0.f;
        #pragma unroll
        for (int q = 0; q < H / 64; ++q) s += At[j][q * 64 + lane];
        #pragma unroll
        for (int off = 32; off; off >>= 1) s += __shfl_xor(s, off);
        if (lane == 0) red_s[j] = s;
    }
    __syncthreads();
    float outc = 0.f;
    #pragma unroll
    for (int jj = 0; jj < JT; ++jj) {
        int j = grp * JT + jj;
        if (j < NH) outc += At[j][col] / red_s[j] * accF[jj];
    }
    outp[t] = outc;
    cat[H + t] = g_in ? g_in[b * 256 + t] : 0.f;
    __syncthreads();
    if (t < H) {
        float o = 0.f;
        #pragma unroll
        for (int g2 = 0; g2 < NG; ++g2) o += outp[g2 * H + t];
        cat[t] = o;
    }
    __syncthreads();
    float acc = gb[t];
    const float* gwp = gW + t;
    #pragma unroll 2
    for (int i4 = 0; i4 < (H + 256) / 4; ++i4) {
        float4 cq = ((const float4*)cat)[i4];
        const float* gw4 = gwp + (size_t)i4 * 4 * 256;
        acc = fmaf(cq.x, gw4[0], acc);
        acc = fmaf(cq.y, gw4[256], acc);
        acc = fmaf(cq.z, gw4[512], acc);
        acc = fmaf(cq.w, gw4[768], acc);
    }
    g_out[b * 256 + t] = cat[H + t] + acc;
}

// ---------------- pull max-aggregation, 256 feats: one wave per node ----------------
// Linear csr+nrm loads (norm precomputed) + manual 4-wide unroll -> 4 row
// gathers in flight per wave (round-4 version was a 2-level chase, 1 in flight).
__global__ __launch_bounds__(256) void agg_max_f256(const float* __restrict__ xw,
        const float* __restrict__ dinv, const int* __restrict__ offs,
        const int* __restrict__ csr, const float* __restrict__ nrmv,
        const float* __restrict__ bias, float* __restrict__ out) {
    int gid = blockIdx.x * 256 + threadIdx.x;
    int v = gid >> 6;
    int lane = gid & 63;
    float dv = dinv[v];
    float4 a = ((const float4*)(xw + (size_t)v * 256))[lane];
    float sn = dv * dv;
    float4 acc = make_float4(a.x * sn, a.y * sn, a.z * sn, a.w * sn);
    int e = offs[v];
    int e1 = offs[v + 1];
    for (; e + 4 <= e1; e += 4) {
        int u0 = csr[e + 0], u1 = csr[e + 1], u2 = csr[e + 2], u3 = csr[e + 3];
        float n0 = nrmv[e + 0], n1 = nrmv[e + 1], n2 = nrmv[e + 2], n3 = nrmv[e + 3];
        float4 m0 = ((const float4*)(xw + (size_t)u0 * 256))[lane];
        float4 m1 = ((const float4*)(xw + (size_t)u1 * 256))[lane];
        float4 m2 = ((const float4*)(xw + (size_t)u2 * 256))[lane];
        float4 m3 = ((const float4*)(xw + (size_t)u3 * 256))[lane];
        acc.x = fmaxf(fmaxf(fmaxf(acc.x, m0.x * n0), fmaxf(m1.x * n1, m2.x * n2)), m3.x * n3);
        acc.y = fmaxf(fmaxf(fmaxf(acc.y, m0.y * n0), fmaxf(m1.y * n1, m2.y * n2)), m3.y * n3);
        acc.z = fmaxf(fmaxf(fmaxf(acc.z, m0.z * n0), fmaxf(m1.z * n1, m2.z * n2)), m3.z * n3);
        acc.w = fmaxf(fmaxf(fmaxf(acc.w, m0.w * n0), fmaxf(m1.w * n1, m2.w * n2)), m3.w * n3);
    }
    for (; e < e1; ++e) {
        int u = csr[e];
        float n = nrmv[e];
        float4 m = ((const float4*)(xw + (size_t)u * 256))[lane];
        acc.x = fmaxf(acc.x, m.x * n);
        acc.y = fmaxf(acc.y, m.y * n);
        acc.z = fmaxf(acc.z, m.z * n);
        acc.w = fmaxf(acc.w, m.w * n);
    }
    float4 b4 = ((const float4*)bias)[lane];
    float4 o;
    o.x = fmaxf(acc.x + b4.x, 0.f);
    o.y = fmaxf(acc.y + b4.y, 0.f);
    o.z = fmaxf(acc.z + b4.z, 0.f);
    o.w = fmaxf(acc.w + b4.w, 0.f);
    ((float4*)(out + (size_t)v * 256))[lane] = o;
}

// ---------------- pull max-aggregation, 64 feats: one wave per node ----------------
__global__ __launch_bounds__(256) void agg_max_f64(const float* __restrict__ xw,
        const float* __restrict__ dinv, const int* __restrict__ offs,
        const int* __restrict__ csr, const float* __restrict__ nrmv,
        const float* __restrict__ bias, float* __restrict__ out) {
    int gid = blockIdx.x * 256 + threadIdx.x;
    int v = gid >> 6;
    int lane = gid & 63;
    float dv = dinv[v];
    float acc = xw[(size_t)v * 64 + lane] * dv * dv;
    int e = offs[v];
    int e1 = offs[v + 1];
    for (; e + 4 <= e1; e += 4) {
        int u0 = csr[e + 0], u1 = csr[e + 1], u2 = csr[e + 2], u3 = csr[e + 3];
        float n0 = nrmv[e + 0], n1 = nrmv[e + 1], n2 = nrmv[e + 2], n3 = nrmv[e + 3];
        float m0 = xw[(size_t)u0 * 64 + lane];
        float m1 = xw[(size_t)u1 * 64 + lane];
        float m2 = xw[(size_t)u2 * 64 + lane];
        float m3 = xw[(size_t)u3 * 64 + lane];
        acc = fmaxf(fmaxf(fmaxf(acc, m0 * n0), fmaxf(m1 * n1, m2 * n2)), m3 * n3);
    }
    for (; e < e1; ++e) {
        int u = csr[e];
        acc = fmaxf(acc, xw[(size_t)u * 64 + lane] * nrmv[e]);
    }
    out[(size_t)v * 64 + lane] = fmaxf(acc + bias[lane], 0.f);
}

// ---------------- head: relu(g@o1W+o1b)@o2W+o2b ----------------
__global__ __launch_bounds__(64) void head_kernel(const float* __restrict__ g,
        const float* __restrict__ o1W, const float* __restrict__ o1b,
        const float* __restrict__ o2W, const float* __restrict__ o2b,
        float* __restrict__ out) {
    int b = blockIdx.x, t = threadIdx.x;
    const float* gr = g + (size_t)b * 256;
    float acc = o1b[t];
    #pragma unroll 8
    for (int k = 0; k < 256; ++k) acc += gr[k] * o1W[k * 64 + t];
    acc = fmaxf(acc, 0.f);
    float s = acc * o2W[t];
    #pragma unroll
    for (int off = 32; off; off >>= 1) s += __shfl_xor(s, off);
    if (t == 0) out[b] = s + o2b[0];
}

extern "C" void kernel_launch(void* const* d_in, const int* in_sizes, int n_in,
                              void* d_out, int out_size, void* d_ws, size_t ws_size,
                              hipStream_t stream) {
    (void)in_sizes; (void)n_in; (void)out_size;
    const float* x    = (const float*)d_in[0];
    const int* ei32   = (const int*)d_in[1];
    const long long* ei64 = (const long long*)d_in[1];
    const int* hidx   = (const int*)d_in[2];
    const float* W1 = (const float*)d_in[3],  *b1 = (const float*)d_in[4];
    const float* W2 = (const float*)d_in[5],  *b2 = (const float*)d_in[6];
    const float* a0W = (const float*)d_in[7],  *a0b = (const float*)d_in[8];
    const float* f0W = (const float*)d_in[9],  *f0b = (const float*)d_in[10];
    const float* g0W = (const float*)d_in[11], *g0b = (const float*)d_in[12];
    const float* a1W = (const float*)d_in[13], *a1b = (const float*)d_in[14];
    const float* f1W = (const float*)d_in[15], *f1b = (const float*)d_in[16];
    const float* g1W = (const float*)d_in[17], *g1b = (const float*)d_in[18];
    const float* a2W = (const float*)d_in[19], *a2b = (const float*)d_in[20];
    const float* f2W = (const float*)d_in[21], *f2b = (const float*)d_in[22];
    const float* g2W = (const float*)d_in[23], *g2b = (const float*)d_in[24];
    const float* o1W = (const float*)d_in[25], *o1b = (const float*)d_in[26];
    const float* o2W = (const float*)d_in[27], *o2b = (const float*)d_in[28];
    float* outp = (float*)d_out;

    char* p = (char*)d_ws;
    auto alloc = [&](size_t bytes) {
        char* r = p;
        p += (bytes + 255) & ~(size_t)255;
        return r;
    };
    float* dinv = (float*)alloc((size_t)N_NODES * 4);
    int* degc   = (int*)alloc((size_t)N_NODES * 4);
    int* offs   = (int*)alloc((size_t)(N_NODES + 1) * 4);
    int* csr    = (int*)alloc((size_t)N_EDGES * 4);
    float* nrmv = (float*)alloc((size_t)N_EDGES * 4);
    int* bsums  = (int*)alloc(256 * 4);
    int* flag   = (int*)alloc(256);
    float* g    = (float*)alloc((size_t)B_GRAPH * 256 * 4);
    float* AF   = (float*)alloc((size_t)B_GRAPH * NH * 512 * 4);  // 3328 x 512 max
    float* xw1  = (float*)alloc((size_t)N_NODES * 256 * 4);
    float* x1   = (float*)alloc((size_t)N_NODES * 256 * 4);
    // xw1 is dead after agg_max_f256 -> reuse its 52 MB region for xw2 and x2
    float* xw2  = xw1;
    float* x2   = xw1 + (size_t)N_NODES * 64;

    size_t need = (size_t)(p - (char*)d_ws);
    if (need > ws_size) {
        fprintf(stderr, "kernel_launch: ws too small (%zu needed, %zu have)\n", need, ws_size);
        return;
    }

    probe_flag<<<1, 64, 0, stream>>>(ei32, flag);
    init_deg<<<200, 256, 0, stream>>>(degc);
    count_deg<<<1600, 256, 0, stream>>>(ei32, ei64, flag, degc);
    scan_block_sums<<<200, 256, 0, stream>>>(degc, bsums);
    scan_bsums<<<1, 256, 0, stream>>>(bsums, 200);
    scan_finalize<<<200, 256, 0, stream>>>(degc, offs, dinv, bsums);
    fill_csr<<<1600, 256, 0, stream>>>(ei32, ei64, flag, dinv, degc, csr, nrmv);

    gemm_tile<64, 256><<<800 * 4, 256, 0, stream>>>(x, W1, xw1);
    gemm_af<64, 256><<<52 * 8, 256, 0, stream>>>(x, hidx, a0W, a0b, f0W, f0b, AF);
    attn_reduce<256><<<256, 256, 0, stream>>>(AF, g0W, g0b, nullptr, g);
    agg_max_f256<<<12800, 256, 0, stream>>>(xw1, dinv, offs, csr, nrmv, b1, x1);
    gemm_af<256, 256><<<52 * 8, 256, 0, stream>>>(x1, hidx, a1W, a1b, f1W, f1b, AF);
    attn_reduce<256><<<256, 256, 0, stream>>>(AF, g1W, g1b, g, g);
    gemm_tile<256, 64><<<800, 256, 0, stream>>>(x1, W2, xw2);
    agg_max_f64<<<12800, 256, 0, stream>>>(xw2, dinv, offs, csr, nrmv, b2, x2);
    gemm_af<64, 64><<<52 * 2, 256, 0, stream>>>(x2, hidx, a2W, a2b, f2W, f2b, AF);
    attn_reduce<64><<<256, 256, 0, stream>>>(AF, g2W, g2b, g, g);
    head_kernel<<<256, 64, 0, stream>>>(g, o1W, o1b, o2W, o2b, outp);
}

// Round 6
// 405.269 us; speedup vs baseline: 1.4505x; 1.0845x over previous
//
#include <hip/hip_runtime.h>
#include <math.h>
#include <stdio.h>

#define N_NODES 51200
#define N_EDGES 409600
#define B_GRAPH 256
#define NH 13

typedef float v4f __attribute__((ext_vector_type(4)));
__device__ __forceinline__ void nt_store_f4(float* p, float4 v) {
    v4f w; w.x = v.x; w.y = v.y; w.z = v.z; w.w = v.w;
    __builtin_nontemporal_store(w, (v4f*)p);
}

// ei dtype probe, inlined at use sites: int64 ei has zero high words.
// Uniform pointer + constant offsets -> scalar loads, negligible.
__device__ __forceinline__ bool ei_is_64(const int* __restrict__ ei32) {
    int z = 1;
    #pragma unroll
    for (int k = 1; k < 16; k += 2) z &= (ei32[k] == 0);
    return z != 0;
}

// degc pre-zeroed by hipMemsetAsync; self-loop handled as deg = count+1.
__global__ void count_deg(const int* __restrict__ ei32, const long long* __restrict__ ei64,
                          int* __restrict__ degc) {
    int e = blockIdx.x * 256 + threadIdx.x;
    if (e >= N_EDGES) return;
    int v = ei_is_64(ei32) ? (int)ei64[N_EDGES + e] : ei32[N_EDGES + e];
    atomicAdd(&degc[v], 1);
}

__global__ void scan_block_sums(const int* __restrict__ degc, int* __restrict__ bsums) {
    __shared__ int sdata[256];
    int i = blockIdx.x * 256 + threadIdx.x;
    sdata[threadIdx.x] = degc[i];
    __syncthreads();
    for (int s = 128; s > 0; s >>= 1) {
        if (threadIdx.x < s) sdata[threadIdx.x] += sdata[threadIdx.x + s];
        __syncthreads();
    }
    if (threadIdx.x == 0) bsums[blockIdx.x] = sdata[0];
}

// finalize with INLINE scan of the 200 block sums (kills the scan_bsums dispatch)
__global__ void scan_finalize(int* __restrict__ degc, int* __restrict__ offs,
                              float* __restrict__ dinv, const int* __restrict__ bsums) {
    __shared__ int bs[256];
    __shared__ int s[256];
    const int t = threadIdx.x;
    bs[t] = (t < 200) ? bsums[t] : 0;
    __syncthreads();
    for (int off = 1; off < 256; off <<= 1) {
        int u = (t >= off) ? bs[t - off] : 0;
        __syncthreads();
        bs[t] += u;
        __syncthreads();
    }
    int i = blockIdx.x * 256 + t;
    int cnt = degc[i];  // in-degree without self-loop
    s[t] = cnt;
    __syncthreads();
    for (int off = 1; off < 256; off <<= 1) {
        int u = (t >= off) ? s[t - off] : 0;
        __syncthreads();
        s[t] += u;
        __syncthreads();
    }
    int base = (blockIdx.x == 0) ? 0 : bs[blockIdx.x - 1];
    int excl = base + s[t] - cnt;
    offs[i] = excl;
    dinv[i] = rsqrtf((float)(cnt + 1));
    degc[i] = excl;  // becomes the fill cursor
    if (i == N_NODES - 1) offs[N_NODES] = N_EDGES;
}

__global__ void fill_csr(const int* __restrict__ ei32, const long long* __restrict__ ei64,
                         const float* __restrict__ dinv,
                         int* __restrict__ cursor, int* __restrict__ csr,
                         float* __restrict__ nrmv) {
    int e = blockIdx.x * 256 + threadIdx.x;
    if (e >= N_EDGES) return;
    int u, v;
    if (ei_is_64(ei32)) { u = (int)ei64[e]; v = (int)ei64[N_EDGES + e]; }
    else                { u = ei32[e];      v = ei32[N_EDGES + e]; }
    int pos = atomicAdd(&cursor[v], 1);
    csr[pos] = u;
    nrmv[pos] = dinv[u] * dinv[v];
}

// ---------------- unified tiled GEMM: Y[N, NTOT] = X[N, K] @ W[K, NTOT] ----------------
template <int K, int NTOT>
__global__ __launch_bounds__(256) void gemm_tile(const float* __restrict__ X,
                                                 const float* __restrict__ W,
                                                 float* __restrict__ Y) {
    constexpr int BK = 32;
    constexpr int XS = BK + 4;  // 36
    __shared__ float xs[64 * XS];
    __shared__ float ws[BK * 64];
    constexpr int nColBlk = NTOT / 64;
    const int rb = blockIdx.x / nColBlk;
    const int cb = blockIdx.x - rb * nColBlk;
    const int row0 = rb * 64;
    const int c0 = cb * 64;
    const int t = threadIdx.x;
    const int ct = t & 15;
    const int rt = t >> 4;
    float acc[4][4] = {{0.f}};
    for (int kc = 0; kc < K; kc += BK) {
        __syncthreads();
        #pragma unroll
        for (int i = 0; i < 2; ++i) {
            int idx = t + i * 256;
            int q = idx & 7, r = idx >> 3;
            float4 v = *(const float4*)(X + (size_t)(row0 + r) * K + kc + q * 4);
            *(float4*)&xs[r * XS + q * 4] = v;
        }
        #pragma unroll
        for (int i = 0; i < 2; ++i) {
            int idx = t + i * 256;
            int q = idx & 15, k = idx >> 4;
            float4 v = *(const float4*)(W + (size_t)(kc + k) * NTOT + c0 + q * 4);
            *(float4*)&ws[k * 64 + q * 4] = v;
        }
        __syncthreads();
        #pragma unroll
        for (int kb = 0; kb < BK; kb += 4) {
            float4 wv[4];
            #pragma unroll
            for (int kk = 0; kk < 4; ++kk)
                wv[kk] = *(const float4*)&ws[(kb + kk) * 64 + ct * 4];
            #pragma unroll
            for (int r = 0; r < 4; ++r) {
                float4 xv = *(const float4*)&xs[(rt * 4 + r) * XS + kb];
                acc[r][0] = fmaf(xv.x, wv[0].x, acc[r][0]);
                acc[r][1] = fmaf(xv.x, wv[0].y, acc[r][1]);
                acc[r][2] = fmaf(xv.x, wv[0].z, acc[r][2]);
                acc[r][3] = fmaf(xv.x, wv[0].w, acc[r][3]);
                acc[r][0] = fmaf(xv.y, wv[1].x, acc[r][0]);
                acc[r][1] = fmaf(xv.y, wv[1].y, acc[r][1]);
                acc[r][2] = fmaf(xv.y, wv[1].z, acc[r][2]);
                acc[r][3] = fmaf(xv.y, wv[1].w, acc[r][3]);
                acc[r][0] = fmaf(xv.z, wv[2].x, acc[r][0]);
                acc[r][1] = fmaf(xv.z, wv[2].y, acc[r][1]);
                acc[r][2] = fmaf(xv.z, wv[2].z, acc[r][2]);
                acc[r][3] = fmaf(xv.z, wv[2].w, acc[r][3]);
                acc[r][0] = fmaf(xv.w, wv[3].x, acc[r][0]);
                acc[r][1] = fmaf(xv.w, wv[3].y, acc[r][1]);
                acc[r][2] = fmaf(xv.w, wv[3].z, acc[r][2]);
                acc[r][3] = fmaf(xv.w, wv[3].w, acc[r][3]);
            }
        }
    }
    #pragma unroll
    for (int r = 0; r < 4; ++r) {
        int row = row0 + rt * 4 + r;
        *(float4*)&Y[(size_t)row * NTOT + c0 + ct * 4] =
            make_float4(acc[r][0], acc[r][1], acc[r][2], acc[r][3]);
    }
}

// ---- attention phase A: AF[3328, 2H] = x[host_idx] @ [aW | fW] + [ab | fb] ----
template <int K, int H>
__global__ __launch_bounds__(256) void gemm_af(const float* __restrict__ X,
        const int* __restrict__ host_idx,
        const float* __restrict__ aW, const float* __restrict__ ab,
        const float* __restrict__ fW, const float* __restrict__ fb,
        float* __restrict__ AF) {
    constexpr int NTOT = 2 * H;
    constexpr int BK = 32;
    constexpr int XS = BK + 4;
    __shared__ float xs[64 * XS];
    __shared__ float ws[BK * 64];
    __shared__ int rows[64];
    constexpr int nColBlk = NTOT / 64;
    const int rb = blockIdx.x / nColBlk;
    const int cb = blockIdx.x - rb * nColBlk;
    const int row0 = rb * 64;
    const int c0 = cb * 64;
    const float* W    = (c0 < H) ? (aW + c0) : (fW + (c0 - H));
    const float* bias = (c0 < H) ? (ab + c0) : (fb + (c0 - H));
    const int t = threadIdx.x;
    const int ct = t & 15;
    const int rt = t >> 4;
    if (t < 64) rows[t] = host_idx[row0 + t];
    float acc[4][4] = {{0.f}};
    for (int kc = 0; kc < K; kc += BK) {
        __syncthreads();
        #pragma unroll
        for (int i = 0; i < 2; ++i) {
            int idx = t + i * 256;
            int q = idx & 7, r = idx >> 3;
            float4 v = *(const float4*)(X + (size_t)rows[r] * K + kc + q * 4);
            *(float4*)&xs[r * XS + q * 4] = v;
        }
        #pragma unroll
        for (int i = 0; i < 2; ++i) {
            int idx = t + i * 256;
            int q = idx & 15, k = idx >> 4;
            float4 v = *(const float4*)(W + (size_t)(kc + k) * H + q * 4);
            *(float4*)&ws[k * 64 + q * 4] = v;
        }
        __syncthreads();
        #pragma unroll
        for (int kb = 0; kb < BK; kb += 4) {
            float4 wv[4];
            #pragma unroll
            for (int kk = 0; kk < 4; ++kk)
                wv[kk] = *(const float4*)&ws[(kb + kk) * 64 + ct * 4];
            #pragma unroll
            for (int r = 0; r < 4; ++r) {
                float4 xv = *(const float4*)&xs[(rt * 4 + r) * XS + kb];
                acc[r][0] = fmaf(xv.x, wv[0].x, acc[r][0]);
                acc[r][1] = fmaf(xv.x, wv[0].y, acc[r][1]);
                acc[r][2] = fmaf(xv.x, wv[0].z, acc[r][2]);
                acc[r][3] = fmaf(xv.x, wv[0].w, acc[r][3]);
                acc[r][0] = fmaf(xv.y, wv[1].x, acc[r][0]);
                acc[r][1] = fmaf(xv.y, wv[1].y, acc[r][1]);
                acc[r][2] = fmaf(xv.y, wv[1].z, acc[r][2]);
                acc[r][3] = fmaf(xv.y, wv[1].w, acc[r][3]);
                acc[r][0] = fmaf(xv.z, wv[2].x, acc[r][0]);
                acc[r][1] = fmaf(xv.z, wv[2].y, acc[r][1]);
                acc[r][2] = fmaf(xv.z, wv[2].z, acc[r][2]);
                acc[r][3] = fmaf(xv.z, wv[2].w, acc[r][3]);
                acc[r][0] = fmaf(xv.w, wv[3].x, acc[r][0]);
                acc[r][1] = fmaf(xv.w, wv[3].y, acc[r][1]);
                acc[r][2] = fmaf(xv.w, wv[3].z, acc[r][2]);
                acc[r][3] = fmaf(xv.w, wv[3].w, acc[r][3]);
            }
        }
    }
    #pragma unroll
    for (int r = 0; r < 4; ++r) {
        int row = row0 + rt * 4 + r;
        float4 o = make_float4(acc[r][0] + bias[ct * 4 + 0],
                               acc[r][1] + bias[ct * 4 + 1],
                               acc[r][2] + bias[ct * 4 + 2],
                               acc[r][3] + bias[ct * 4 + 3]);
        *(float4*)&AF[(size_t)row * NTOT + c0 + ct * 4] = o;
    }
}

// ---- attention phase B (H=256 layers): softmax + weighted sum + residual update ----
template <int H>
__global__ __launch_bounds__(256) void attn_reduce(const float* __restrict__ AF,
        const float* __restrict__ gW, const float* __restrict__ gb,
        const float* __restrict__ g_in, float* __restrict__ g_out) {
    constexpr int NG = 256 / H;
    constexpr int JT = (NH + NG - 1) / NG;
    constexpr int NTOT = 2 * H;
    __shared__ float At[NH][H];
    __shared__ float red_m[NH];
    __shared__ float red_s[NH];
    __shared__ float outp[256];
    __shared__ float cat[H + 256];
    const int b = blockIdx.x;
    const int t = threadIdx.x;
    const int col = t % H;
    const int grp = t / H;
    const int wave = t >> 6;
    const int lane = t & 63;

    float accA[JT], accF[JT];
    #pragma unroll
    for (int jj = 0; jj < JT; ++jj) {
        int j = grp * JT + jj;
        if (j < NH) {
            const float* r = AF + (size_t)(b * NH + j) * NTOT;
            accA[jj] = r[col];
            accF[jj] = r[H + col];
            At[j][col] = accA[jj];
        } else { accA[jj] = 0.f; accF[jj] = 0.f; }
    }
    __syncthreads();
    for (int j = wave; j < NH; j += 4) {
        float m = -3.402823466e38f;
        #pragma unroll
        for (int q = 0; q < H / 64; ++q) m = fmaxf(m, At[j][q * 64 + lane]);
        #pragma unroll
        for (int off = 32; off; off >>= 1) m = fmaxf(m, __shfl_xor(m, off));
        if (lane == 0) red_m[j] = m;
    }
    __syncthreads();
    #pragma unroll
    for (int jj = 0; jj < JT; ++jj) {
        int j = grp * JT + jj;
        if (j < NH) At[j][col] = expf(accA[jj] - red_m[j]);
    }
    __syncthreads();
    for (int j = wave; j < NH; j += 4) {
        float s = 0.f;
        #pragma unroll
        for (int q = 0; q < H / 64; ++q) s += At[j][q * 64 + lane];
        #pragma unroll
        for (int off = 32; off; off >>= 1) s += __shfl_xor(s, off);
        if (lane == 0) red_s[j] = s;
    }
    __syncthreads();
    float outc = 0.f;
    #pragma unroll
    for (int jj = 0; jj < JT; ++jj) {
        int j = grp * JT + jj;
        if (j < NH) outc += At[j][col] / red_s[j] * accF[jj];
    }
    outp[t] = outc;
    cat[H + t] = g_in ? g_in[b * 256 + t] : 0.f;
    __syncthreads();
    if (t < H) {
        float o = 0.f;
        #pragma unroll
        for (int g2 = 0; g2 < NG; ++g2) o += outp[g2 * H + t];
        cat[t] = o;
    }
    __syncthreads();
    float acc = gb[t];
    const float* gwp = gW + t;
    #pragma unroll 4
    for (int i4 = 0; i4 < (H + 256) / 4; ++i4) {
        float4 cq = ((const float4*)cat)[i4];
        const float* gw4 = gwp + (size_t)i4 * 4 * 256;
        acc = fmaf(cq.x, gw4[0], acc);
        acc = fmaf(cq.y, gw4[256], acc);
        acc = fmaf(cq.z, gw4[512], acc);
        acc = fmaf(cq.w, gw4[768], acc);
    }
    g_out[b * 256 + t] = cat[H + t] + acc;
}

// ---- fused layer-2 attention + head (IN=64, H=64): one block per graph ----
__global__ __launch_bounds__(256) void attn_head64(const float* __restrict__ feat,
        const int* __restrict__ host_idx,
        const float* __restrict__ aW, const float* __restrict__ ab,
        const float* __restrict__ fW, const float* __restrict__ fb,
        const float* __restrict__ gW, const float* __restrict__ gb,
        const float* __restrict__ g_in,
        const float* __restrict__ o1W, const float* __restrict__ o1b,
        const float* __restrict__ o2W, const float* __restrict__ o2b,
        float* __restrict__ out) {
    __shared__ float xl[NH * 64];
    __shared__ float At[NH][64];
    __shared__ float red_m[NH];
    __shared__ float red_s[NH];
    __shared__ float outp[256];
    __shared__ float cat[64 + 256];
    __shared__ float grow[256];
    __shared__ float part[4][64];
    __shared__ int hix[NH];
    const int b = blockIdx.x;
    const int t = threadIdx.x;
    const int col = t & 63;
    const int grp = t >> 6;
    const int lane = t & 63;

    if (t < NH) hix[t] = host_idx[b * NH + t];
    __syncthreads();
    if (t < NH * 16) {
        int j = t >> 4, q = t & 15;
        ((float4*)xl)[t] = ((const float4*)(feat + (size_t)hix[j] * 64))[q];
    }
    __syncthreads();
    // A/F matmul: 13 rows x 64 cols, K=64
    float accA[4], accF[4];
    {
        float abv = ab[col], fbv = fb[col];
        #pragma unroll
        for (int jj = 0; jj < 4; ++jj) { accA[jj] = abv; accF[jj] = fbv; }
    }
    #pragma unroll 4
    for (int k = 0; k < 64; ++k) {
        float wa = aW[k * 64 + col];
        float wf = fW[k * 64 + col];
        #pragma unroll
        for (int jj = 0; jj < 4; ++jj) {
            int j = grp * 4 + jj;
            if (j >= NH) j = 0;
            float xv = xl[j * 64 + k];  // LDS broadcast
            accA[jj] = fmaf(xv, wa, accA[jj]);
            accF[jj] = fmaf(xv, wf, accF[jj]);
        }
    }
    #pragma unroll
    for (int jj = 0; jj < 4; ++jj) {
        int j = grp * 4 + jj;
        if (j < NH) At[j][col] = accA[jj];
    }
    __syncthreads();
    for (int j = grp; j < NH; j += 4) {
        float m = At[j][lane];
        #pragma unroll
        for (int off = 32; off; off >>= 1) m = fmaxf(m, __shfl_xor(m, off));
        if (lane == 0) red_m[j] = m;
    }
    __syncthreads();
    #pragma unroll
    for (int jj = 0; jj < 4; ++jj) {
        int j = grp * 4 + jj;
        if (j < NH) At[j][col] = expf(accA[jj] - red_m[j]);
    }
    __syncthreads();
    for (int j = grp; j < NH; j += 4) {
        float s = At[j][lane];
        #pragma unroll
        for (int off = 32; off; off >>= 1) s += __shfl_xor(s, off);
        if (lane == 0) red_s[j] = s;
    }
    __syncthreads();
    float outc = 0.f;
    #pragma unroll
    for (int jj = 0; jj < 4; ++jj) {
        int j = grp * 4 + jj;
        if (j < NH) outc += At[j][col] / red_s[j] * accF[jj];
    }
    outp[t] = outc;
    cat[64 + t] = g_in[b * 256 + t];
    __syncthreads();
    if (t < 64) cat[t] = outp[t] + outp[64 + t] + outp[128 + t] + outp[192 + t];
    __syncthreads();
    // residual global update: grow = g + cat @ gW + gb
    float acc = gb[t];
    const float* gwp = gW + t;
    #pragma unroll 4
    for (int i4 = 0; i4 < (64 + 256) / 4; ++i4) {
        float4 cq = ((const float4*)cat)[i4];
        const float* gw4 = gwp + (size_t)i4 * 4 * 256;
        acc = fmaf(cq.x, gw4[0], acc);
        acc = fmaf(cq.y, gw4[256], acc);
        acc = fmaf(cq.z, gw4[512], acc);
        acc = fmaf(cq.w, gw4[768], acc);
    }
    grow[t] = cat[64 + t] + acc;
    __syncthreads();
    // head: h = relu(grow @ o1W + o1b); out[b] = h @ o2W + o2b
    {
        float hp = 0.f;
        #pragma unroll 8
        for (int k = 0; k < 64; ++k) {
            int kk = grp * 64 + k;
            hp = fmaf(grow[kk], o1W[(size_t)kk * 64 + col], hp);
        }
        part[grp][col] = hp;
    }
    __syncthreads();
    if (t < 64) {
        float h = part[0][t] + part[1][t] + part[2][t] + part[3][t] + o1b[t];
        h = fmaxf(h, 0.f);
        float sres = h * o2W[t];
        #pragma unroll
        for (int off = 32; off; off >>= 1) sres += __shfl_xor(sres, off);
        if (t == 0) out[b] = sres + o2b[0];
    }
}

// ---------------- pull max-aggregation, 256 feats: one wave per node ----------------
// Predicated 8-wide gather batches (clamped idx, wave-uniform guards): 8 row
// gathers always in flight, no serial remainder. NT store keeps L2 for gathers.
__global__ __launch_bounds__(256) void agg_max_f256(const float* __restrict__ xw,
        const float* __restrict__ dinv, const int* __restrict__ offs,
        const int* __restrict__ csr, const float* __restrict__ nrmv,
        const float* __restrict__ bias, float* __restrict__ out) {
    int gid = blockIdx.x * 256 + threadIdx.x;
    int v = gid >> 6;
    int lane = gid & 63;
    float dv = dinv[v];
    const float4* xw4 = (const float4*)xw;
    float4 a = xw4[(size_t)v * 64 + lane];
    float sn = dv * dv;
    float4 acc = make_float4(a.x * sn, a.y * sn, a.z * sn, a.w * sn);
    int e0 = offs[v];
    int e1 = offs[v + 1];
    for (int e = e0; e < e1; e += 8) {
        int idx[8];
        #pragma unroll
        for (int i = 0; i < 8; ++i) idx[i] = (e + i < e1) ? (e + i) : (e1 - 1);
        int u[8]; float n[8];
        #pragma unroll
        for (int i = 0; i < 8; ++i) { u[i] = csr[idx[i]]; n[i] = nrmv[idx[i]]; }
        float4 m[8];
        #pragma unroll
        for (int i = 0; i < 8; ++i) m[i] = xw4[(size_t)u[i] * 64 + lane];
        #pragma unroll
        for (int i = 0; i < 8; ++i) {
            if (e + i < e1) {  // wave-uniform guard
                acc.x = fmaxf(acc.x, m[i].x * n[i]);
                acc.y = fmaxf(acc.y, m[i].y * n[i]);
                acc.z = fmaxf(acc.z, m[i].z * n[i]);
                acc.w = fmaxf(acc.w, m[i].w * n[i]);
            }
        }
    }
    float4 b4 = ((const float4*)bias)[lane];
    float4 o;
    o.x = fmaxf(acc.x + b4.x, 0.f);
    o.y = fmaxf(acc.y + b4.y, 0.f);
    o.z = fmaxf(acc.z + b4.z, 0.f);
    o.w = fmaxf(acc.w + b4.w, 0.f);
    nt_store_f4(out + (size_t)v * 256 + lane * 4, o);
}

// ---------------- pull max-aggregation, 64 feats: one wave per node ----------------
__global__ __launch_bounds__(256) void agg_max_f64(const float* __restrict__ xw,
        const float* __restrict__ dinv, const int* __restrict__ offs,
        const int* __restrict__ csr, const float* __restrict__ nrmv,
        const float* __restrict__ bias, float* __restrict__ out) {
    int gid = blockIdx.x * 256 + threadIdx.x;
    int v = gid >> 6;
    int lane = gid & 63;
    float dv = dinv[v];
    float acc = xw[(size_t)v * 64 + lane] * dv * dv;
    int e0 = offs[v];
    int e1 = offs[v + 1];
    for (int e = e0; e < e1; e += 8) {
        int idx[8];
        #pragma unroll
        for (int i = 0; i < 8; ++i) idx[i] = (e + i < e1) ? (e + i) : (e1 - 1);
        int u[8]; float n[8];
        #pragma unroll
        for (int i = 0; i < 8; ++i) { u[i] = csr[idx[i]]; n[i] = nrmv[idx[i]]; }
        float m[8];
        #pragma unroll
        for (int i = 0; i < 8; ++i) m[i] = xw[(size_t)u[i] * 64 + lane];
        #pragma unroll
        for (int i = 0; i < 8; ++i)
            if (e + i < e1) acc = fmaxf(acc, m[i] * n[i]);
    }
    float o = fmaxf(acc + bias[lane], 0.f);
    __builtin_nontemporal_store(o, out + (size_t)v * 64 + lane);
}

extern "C" void kernel_launch(void* const* d_in, const int* in_sizes, int n_in,
                              void* d_out, int out_size, void* d_ws, size_t ws_size,
                              hipStream_t stream) {
    (void)in_sizes; (void)n_in; (void)out_size;
    const float* x    = (const float*)d_in[0];
    const int* ei32   = (const int*)d_in[1];
    const long long* ei64 = (const long long*)d_in[1];
    const int* hidx   = (const int*)d_in[2];
    const float* W1 = (const float*)d_in[3],  *b1 = (const float*)d_in[4];
    const float* W2 = (const float*)d_in[5],  *b2 = (const float*)d_in[6];
    const float* a0W = (const float*)d_in[7],  *a0b = (const float*)d_in[8];
    const float* f0W = (const float*)d_in[9],  *f0b = (const float*)d_in[10];
    const float* g0W = (const float*)d_in[11], *g0b = (const float*)d_in[12];
    const float* a1W = (const float*)d_in[13], *a1b = (const float*)d_in[14];
    const float* f1W = (const float*)d_in[15], *f1b = (const float*)d_in[16];
    const float* g1W = (const float*)d_in[17], *g1b = (const float*)d_in[18];
    const float* a2W = (const float*)d_in[19], *a2b = (const float*)d_in[20];
    const float* f2W = (const float*)d_in[21], *f2b = (const float*)d_in[22];
    const float* g2W = (const float*)d_in[23], *g2b = (const float*)d_in[24];
    const float* o1W = (const float*)d_in[25], *o1b = (const float*)d_in[26];
    const float* o2W = (const float*)d_in[27], *o2b = (const float*)d_in[28];
    float* outp = (float*)d_out;

    char* p = (char*)d_ws;
    auto alloc = [&](size_t bytes) {
        char* r = p;
        p += (bytes + 255) & ~(size_t)255;
        return r;
    };
    float* dinv = (float*)alloc((size_t)N_NODES * 4);
    int* degc   = (int*)alloc((size_t)N_NODES * 4);
    int* offs   = (int*)alloc((size_t)(N_NODES + 1) * 4);
    int* csr    = (int*)alloc((size_t)N_EDGES * 4);
    float* nrmv = (float*)alloc((size_t)N_EDGES * 4);
    int* bsums  = (int*)alloc(256 * 4);
    float* g    = (float*)alloc((size_t)B_GRAPH * 256 * 4);
    float* AF   = (float*)alloc((size_t)B_GRAPH * NH * 512 * 4);  // 3328 x 512
    float* xw1  = (float*)alloc((size_t)N_NODES * 256 * 4);
    float* x1   = (float*)alloc((size_t)N_NODES * 256 * 4);
    // xw1 is dead after agg_max_f256 -> reuse its 52 MB region for xw2 and x2
    float* xw2  = xw1;
    float* x2   = xw1 + (size_t)N_NODES * 64;

    size_t need = (size_t)(p - (char*)d_ws);
    if (need > ws_size) {
        fprintf(stderr, "kernel_launch: ws too small (%zu needed, %zu have)\n", need, ws_size);
        return;
    }

    hipMemsetAsync(degc, 0, (size_t)N_NODES * 4, stream);
    count_deg<<<1600, 256, 0, stream>>>(ei32, ei64, degc);
    scan_block_sums<<<200, 256, 0, stream>>>(degc, bsums);
    scan_finalize<<<200, 256, 0, stream>>>(degc, offs, dinv, bsums);
    fill_csr<<<1600, 256, 0, stream>>>(ei32, ei64, dinv, degc, csr, nrmv);

    gemm_tile<64, 256><<<800 * 4, 256, 0, stream>>>(x, W1, xw1);
    gemm_af<64, 256><<<52 * 8, 256, 0, stream>>>(x, hidx, a0W, a0b, f0W, f0b, AF);
    attn_reduce<256><<<256, 256, 0, stream>>>(AF, g0W, g0b, nullptr, g);
    agg_max_f256<<<12800, 256, 0, stream>>>(xw1, dinv, offs, csr, nrmv, b1, x1);
    gemm_af<256, 256><<<52 * 8, 256, 0, stream>>>(x1, hidx, a1W, a1b, f1W, f1b, AF);
    attn_reduce<256><<<256, 256, 0, stream>>>(AF, g1W, g1b, g, g);
    gemm_tile<256, 64><<<800, 256, 0, stream>>>(x1, W2, xw2);
    agg_max_f64<<<12800, 256, 0, stream>>>(xw2, dinv, offs, csr, nrmv, b2, x2);
    attn_head64<<<256, 256, 0, stream>>>(x2, hidx, a2W, a2b, f2W, f2b, g2W, g2b, g,
                                         o1W, o1b, o2W, o2b, outp);
}

// Round 7
// 373.985 us; speedup vs baseline: 1.5718x; 1.0837x over previous
//
#include <hip/hip_runtime.h>
#include <math.h>
#include <stdio.h>

#define N_NODES 51200
#define N_EDGES 409600
#define B_GRAPH 256
#define NH 13

typedef float v4f __attribute__((ext_vector_type(4)));
__device__ __forceinline__ void nt_store_f4(float* p, float4 v) {
    v4f w; w.x = v.x; w.y = v.y; w.z = v.z; w.w = v.w;
    __builtin_nontemporal_store(w, (v4f*)p);
}

// ei dtype probe, inlined: int64 ei has zero high words (uniform scalar loads).
__device__ __forceinline__ bool ei_is_64(const int* __restrict__ ei32) {
    int z = 1;
    #pragma unroll
    for (int k = 1; k < 16; k += 2) z &= (ei32[k] == 0);
    return z != 0;
}

// degc pre-zeroed by hipMemsetAsync; self-loop handled as deg = count+1.
__global__ void count_deg(const int* __restrict__ ei32, const long long* __restrict__ ei64,
                          int* __restrict__ degc) {
    int e = blockIdx.x * 256 + threadIdx.x;
    if (e >= N_EDGES) return;
    int v = ei_is_64(ei32) ? (int)ei64[N_EDGES + e] : ei32[N_EDGES + e];
    atomicAdd(&degc[v], 1);
}

__global__ void scan_block_sums(const int* __restrict__ degc, int* __restrict__ bsums) {
    __shared__ int sdata[256];
    int i = blockIdx.x * 256 + threadIdx.x;
    sdata[threadIdx.x] = degc[i];
    __syncthreads();
    for (int s = 128; s > 0; s >>= 1) {
        if (threadIdx.x < s) sdata[threadIdx.x] += sdata[threadIdx.x + s];
        __syncthreads();
    }
    if (threadIdx.x == 0) bsums[blockIdx.x] = sdata[0];
}

// finalize with inline scan of the 200 block sums
__global__ void scan_finalize(int* __restrict__ degc, int* __restrict__ offs,
                              float* __restrict__ dinv, const int* __restrict__ bsums) {
    __shared__ int bs[256];
    __shared__ int s[256];
    const int t = threadIdx.x;
    bs[t] = (t < 200) ? bsums[t] : 0;
    __syncthreads();
    for (int off = 1; off < 256; off <<= 1) {
        int u = (t >= off) ? bs[t - off] : 0;
        __syncthreads();
        bs[t] += u;
        __syncthreads();
    }
    int i = blockIdx.x * 256 + t;
    int cnt = degc[i];
    s[t] = cnt;
    __syncthreads();
    for (int off = 1; off < 256; off <<= 1) {
        int u = (t >= off) ? s[t - off] : 0;
        __syncthreads();
        s[t] += u;
        __syncthreads();
    }
    int base = (blockIdx.x == 0) ? 0 : bs[blockIdx.x - 1];
    int excl = base + s[t] - cnt;
    offs[i] = excl;
    dinv[i] = rsqrtf((float)(cnt + 1));
    degc[i] = excl;  // fill cursor
    if (i == N_NODES - 1) offs[N_NODES] = N_EDGES;
}

// ---- shared GEMM tile body: 64x64 out, BK=32, thread tile 4x4 ----
// W and Y are pre-offset to the 64-col slice; WS/YS are their row strides.
template <int K, int WS, int YS, bool GATHER, bool SCALE, bool BIAS>
__device__ __forceinline__ void gemm_body(const float* __restrict__ X,
        const float* __restrict__ W, const float* __restrict__ bias,
        const float* __restrict__ dinv, float* __restrict__ Y,
        int row0, const int* __restrict__ rows,
        float* __restrict__ xs, float* __restrict__ ws) {
    constexpr int BK = 32;
    constexpr int XS = BK + 4;  // 36
    const int t = threadIdx.x;
    const int ct = t & 15;
    const int rt = t >> 4;
    float acc[4][4] = {{0.f}};
    for (int kc = 0; kc < K; kc += BK) {
        __syncthreads();
        #pragma unroll
        for (int i = 0; i < 2; ++i) {
            int idx = t + i * 256;
            int q = idx & 7, r = idx >> 3;
            int xr = GATHER ? rows[r] : (row0 + r);
            float4 v = *(const float4*)(X + (size_t)xr * K + kc + q * 4);
            *(float4*)&xs[r * XS + q * 4] = v;
        }
        #pragma unroll
        for (int i = 0; i < 2; ++i) {
            int idx = t + i * 256;
            int q = idx & 15, k = idx >> 4;
            float4 v = *(const float4*)(W + (size_t)(kc + k) * WS + q * 4);
            *(float4*)&ws[k * 64 + q * 4] = v;
        }
        __syncthreads();
        #pragma unroll
        for (int kb = 0; kb < BK; kb += 4) {
            float4 wv[4];
            #pragma unroll
            for (int kk = 0; kk < 4; ++kk)
                wv[kk] = *(const float4*)&ws[(kb + kk) * 64 + ct * 4];
            #pragma unroll
            for (int r = 0; r < 4; ++r) {
                float4 xv = *(const float4*)&xs[(rt * 4 + r) * XS + kb];
                acc[r][0] = fmaf(xv.x, wv[0].x, acc[r][0]);
                acc[r][1] = fmaf(xv.x, wv[0].y, acc[r][1]);
                acc[r][2] = fmaf(xv.x, wv[0].z, acc[r][2]);
                acc[r][3] = fmaf(xv.x, wv[0].w, acc[r][3]);
                acc[r][0] = fmaf(xv.y, wv[1].x, acc[r][0]);
                acc[r][1] = fmaf(xv.y, wv[1].y, acc[r][1]);
                acc[r][2] = fmaf(xv.y, wv[1].z, acc[r][2]);
                acc[r][3] = fmaf(xv.y, wv[1].w, acc[r][3]);
                acc[r][0] = fmaf(xv.z, wv[2].x, acc[r][0]);
                acc[r][1] = fmaf(xv.z, wv[2].y, acc[r][1]);
                acc[r][2] = fmaf(xv.z, wv[2].z, acc[r][2]);
                acc[r][3] = fmaf(xv.z, wv[2].w, acc[r][3]);
                acc[r][0] = fmaf(xv.w, wv[3].x, acc[r][0]);
                acc[r][1] = fmaf(xv.w, wv[3].y, acc[r][1]);
                acc[r][2] = fmaf(xv.w, wv[3].z, acc[r][2]);
                acc[r][3] = fmaf(xv.w, wv[3].w, acc[r][3]);
            }
        }
    }
    #pragma unroll
    for (int r = 0; r < 4; ++r) {
        int row = row0 + rt * 4 + r;
        float4 o = make_float4(acc[r][0], acc[r][1], acc[r][2], acc[r][3]);
        if (BIAS) {
            o.x += bias[ct * 4 + 0];
            o.y += bias[ct * 4 + 1];
            o.z += bias[ct * 4 + 2];
            o.w += bias[ct * 4 + 3];
        }
        if (SCALE) {
            float sc = dinv[row];
            o.x *= sc; o.y *= sc; o.z *= sc; o.w *= sc;
        }
        *(float4*)&Y[(size_t)row * YS + ct * 4] = o;
    }
}

// ---- fused launch: [0,NG) gemm X@W -> Y (dinv-prescaled), [NG,NG+NF) fill_csr,
//      [NG+NF, ...) gemm_af (A|F with bias) ----
template <int K, int NTOT, int NG_BLK, int NF_BLK>
__global__ __launch_bounds__(256) void fused_gemm(const float* __restrict__ X,
        const float* __restrict__ W, float* __restrict__ Y,
        const float* __restrict__ dinv,
        const int* __restrict__ ei32, const long long* __restrict__ ei64,
        int* __restrict__ cursor, int* __restrict__ csr,
        const float* __restrict__ XA, const int* __restrict__ host_idx,
        const float* __restrict__ aW, const float* __restrict__ ab,
        const float* __restrict__ fW, const float* __restrict__ fb,
        float* __restrict__ AF) {
    __shared__ float xs[64 * 36];
    __shared__ float ws[32 * 64];
    __shared__ int rows[64];
    const int bid = blockIdx.x;
    const int t = threadIdx.x;
    if (bid < NG_BLK) {
        constexpr int nColBlk = NTOT / 64;
        const int rb = bid / nColBlk;
        const int cb = bid - rb * nColBlk;
        gemm_body<K, NTOT, NTOT, false, true, false>(
            X, W + cb * 64, nullptr, dinv, Y + cb * 64, rb * 64, nullptr, xs, ws);
    } else if (bid < NG_BLK + NF_BLK) {
        int e = (bid - NG_BLK) * 256 + t;
        if (e < N_EDGES) {
            int u, v;
            if (ei_is_64(ei32)) { u = (int)ei64[e]; v = (int)ei64[N_EDGES + e]; }
            else                { u = ei32[e];      v = ei32[N_EDGES + e]; }
            int pos = atomicAdd(&cursor[v], 1);
            csr[pos] = u;
        }
    } else {
        const int abid = bid - NG_BLK - NF_BLK;
        const int rb = abid >> 3;        // 8 col-blocks (2*256/64)
        const int cb = abid & 7;
        const int c0 = cb * 64;
        const float* Wp = (c0 < 256) ? (aW + c0) : (fW + (c0 - 256));
        const float* bp = (c0 < 256) ? (ab + c0) : (fb + (c0 - 256));
        if (t < 64) rows[t] = host_idx[rb * 64 + t];
        gemm_body<K, 256, 512, true, false, true>(
            XA, Wp, bp, nullptr, AF + c0, rb * 64, rows, xs, ws);
    }
}

// ---- attn reduce body (H=256): softmax over feats + weighted sum + g update ----
__device__ __forceinline__ void attn_red256(const float* __restrict__ AF,
        const float* __restrict__ gW, const float* __restrict__ gb,
        const float* __restrict__ g_in, float* __restrict__ g_out, int b,
        float (*At)[256], float* red_m, float* red_s, float* cat) {
    const int t = threadIdx.x;
    const int wave = t >> 6, lane = t & 63;
    float accA[NH], accF[NH];
    #pragma unroll
    for (int j = 0; j < NH; ++j) {
        const float* r = AF + (size_t)(b * NH + j) * 512;
        accA[j] = r[t];
        accF[j] = r[256 + t];
        At[j][t] = accA[j];
    }
    __syncthreads();
    for (int j = wave; j < NH; j += 4) {
        float m = -3.402823466e38f;
        #pragma unroll
        for (int q = 0; q < 4; ++q) m = fmaxf(m, At[j][q * 64 + lane]);
        #pragma unroll
        for (int off = 32; off; off >>= 1) m = fmaxf(m, __shfl_xor(m, off));
        if (lane == 0) red_m[j] = m;
    }
    __syncthreads();
    #pragma unroll
    for (int j = 0; j < NH; ++j) At[j][t] = expf(accA[j] - red_m[j]);
    __syncthreads();
    for (int j = wave; j < NH; j += 4) {
        float s = 0.f;
        #pragma unroll
        for (int q = 0; q < 4; ++q) s += At[j][q * 64 + lane];
        #pragma unroll
        for (int off = 32; off; off >>= 1) s += __shfl_xor(s, off);
        if (lane == 0) red_s[j] = s;
    }
    __syncthreads();
    float outc = 0.f;
    #pragma unroll
    for (int j = 0; j < NH; ++j) outc += At[j][t] / red_s[j] * accF[j];
    cat[t] = outc;
    float gv = g_in ? g_in[b * 256 + t] : 0.f;
    cat[256 + t] = gv;
    __syncthreads();
    float acc = gb[t];
    const float* gwp = gW + t;
    #pragma unroll 4
    for (int i4 = 0; i4 < 128; ++i4) {
        float4 cq = ((const float4*)cat)[i4];
        const float* gw4 = gwp + (size_t)i4 * 4 * 256;
        acc = fmaf(cq.x, gw4[0], acc);
        acc = fmaf(cq.y, gw4[256], acc);
        acc = fmaf(cq.z, gw4[512], acc);
        acc = fmaf(cq.w, gw4[768], acc);
    }
    g_out[b * 256 + t] = gv + acc;
}

// ---- fused: [0,12800) agg_max 256-feat (rows pre-scaled; out=relu(dinv_v*max+b)),
//      [12800,13056) attn reduce ----
__global__ __launch_bounds__(256) void fused_agg256(const float* __restrict__ xw,
        const float* __restrict__ dinv, const int* __restrict__ offs,
        const int* __restrict__ csr, const float* __restrict__ bias,
        float* __restrict__ out,
        const float* __restrict__ AF, const float* __restrict__ gW,
        const float* __restrict__ gb, const float* __restrict__ g_in,
        float* __restrict__ g_out) {
    __shared__ float At[NH][256];
    __shared__ float red_m[NH];
    __shared__ float red_s[NH];
    __shared__ float cat[512];
    const int bid = blockIdx.x;
    if (bid < 12800) {
        int gid = bid * 256 + threadIdx.x;
        int v = gid >> 6;
        int lane = gid & 63;
        const float4* xw4 = (const float4*)xw;
        float4 acc = xw4[(size_t)v * 64 + lane];  // self-loop (pre-scaled row)
        int e0 = offs[v];
        int e1 = offs[v + 1];
        for (int e = e0; e < e1; e += 8) {
            int idx[8];
            #pragma unroll
            for (int i = 0; i < 8; ++i) idx[i] = (e + i < e1) ? (e + i) : (e1 - 1);
            int u[8];
            #pragma unroll
            for (int i = 0; i < 8; ++i) u[i] = csr[idx[i]];
            float4 m[8];
            #pragma unroll
            for (int i = 0; i < 8; ++i) m[i] = xw4[(size_t)u[i] * 64 + lane];
            #pragma unroll
            for (int i = 0; i < 8; ++i) {
                if (e + i < e1) {  // wave-uniform guard
                    acc.x = fmaxf(acc.x, m[i].x);
                    acc.y = fmaxf(acc.y, m[i].y);
                    acc.z = fmaxf(acc.z, m[i].z);
                    acc.w = fmaxf(acc.w, m[i].w);
                }
            }
        }
        float dv = dinv[v];
        float4 b4 = ((const float4*)bias)[lane];
        float4 o;
        o.x = fmaxf(fmaf(acc.x, dv, b4.x), 0.f);
        o.y = fmaxf(fmaf(acc.y, dv, b4.y), 0.f);
        o.z = fmaxf(fmaf(acc.z, dv, b4.z), 0.f);
        o.w = fmaxf(fmaf(acc.w, dv, b4.w), 0.f);
        nt_store_f4(out + (size_t)v * 256 + lane * 4, o);
    } else {
        attn_red256(AF, gW, gb, g_in, g_out, bid - 12800, At, red_m, red_s, cat);
    }
}

// ---- fused: [0,12800) agg_max 64-feat, [12800,13056) attn reduce ----
__global__ __launch_bounds__(256) void fused_agg64(const float* __restrict__ xw,
        const float* __restrict__ dinv, const int* __restrict__ offs,
        const int* __restrict__ csr, const float* __restrict__ bias,
        float* __restrict__ out,
        const float* __restrict__ AF, const float* __restrict__ gW,
        const float* __restrict__ gb, const float* __restrict__ g_in,
        float* __restrict__ g_out) {
    __shared__ float At[NH][256];
    __shared__ float red_m[NH];
    __shared__ float red_s[NH];
    __shared__ float cat[512];
    const int bid = blockIdx.x;
    if (bid < 12800) {
        int gid = bid * 256 + threadIdx.x;
        int v = gid >> 6;
        int lane = gid & 63;
        float acc = xw[(size_t)v * 64 + lane];
        int e0 = offs[v];
        int e1 = offs[v + 1];
        for (int e = e0; e < e1; e += 8) {
            int idx[8];
            #pragma unroll
            for (int i = 0; i < 8; ++i) idx[i] = (e + i < e1) ? (e + i) : (e1 - 1);
            int u[8];
            #pragma unroll
            for (int i = 0; i < 8; ++i) u[i] = csr[idx[i]];
            float m[8];
            #pragma unroll
            for (int i = 0; i < 8; ++i) m[i] = xw[(size_t)u[i] * 64 + lane];
            #pragma unroll
            for (int i = 0; i < 8; ++i)
                if (e + i < e1) acc = fmaxf(acc, m[i]);
        }
        float o = fmaxf(fmaf(acc, dinv[v], bias[lane]), 0.f);
        __builtin_nontemporal_store(o, out + (size_t)v * 64 + lane);
    } else {
        attn_red256(AF, gW, gb, g_in, g_out, bid - 12800, At, red_m, red_s, cat);
    }
}

// ---- fused layer-2 attention + head (IN=64, H=64): one block per graph ----
__global__ __launch_bounds__(256) void attn_head64(const float* __restrict__ feat,
        const int* __restrict__ host_idx,
        const float* __restrict__ aW, const float* __restrict__ ab,
        const float* __restrict__ fW, const float* __restrict__ fb,
        const float* __restrict__ gW, const float* __restrict__ gb,
        const float* __restrict__ g_in,
        const float* __restrict__ o1W, const float* __restrict__ o1b,
        const float* __restrict__ o2W, const float* __restrict__ o2b,
        float* __restrict__ out) {
    __shared__ float xl[NH * 64];
    __shared__ float At[NH][64];
    __shared__ float red_m[NH];
    __shared__ float red_s[NH];
    __shared__ float outp[256];
    __shared__ float cat[64 + 256];
    __shared__ float grow[256];
    __shared__ float part[4][64];
    __shared__ int hix[NH];
    const int b = blockIdx.x;
    const int t = threadIdx.x;
    const int col = t & 63;
    const int grp = t >> 6;
    const int lane = t & 63;

    if (t < NH) hix[t] = host_idx[b * NH + t];
    __syncthreads();
    if (t < NH * 16) {
        int j = t >> 4, q = t & 15;
        ((float4*)xl)[t] = ((const float4*)(feat + (size_t)hix[j] * 64))[q];
    }
    __syncthreads();
    float accA[4], accF[4];
    {
        float abv = ab[col], fbv = fb[col];
        #pragma unroll
        for (int jj = 0; jj < 4; ++jj) { accA[jj] = abv; accF[jj] = fbv; }
    }
    #pragma unroll 4
    for (int k = 0; k < 64; ++k) {
        float wa = aW[k * 64 + col];
        float wf = fW[k * 64 + col];
        #pragma unroll
        for (int jj = 0; jj < 4; ++jj) {
            int j = grp * 4 + jj;
            if (j >= NH) j = 0;
            float xv = xl[j * 64 + k];
            accA[jj] = fmaf(xv, wa, accA[jj]);
            accF[jj] = fmaf(xv, wf, accF[jj]);
        }
    }
    #pragma unroll
    for (int jj = 0; jj < 4; ++jj) {
        int j = grp * 4 + jj;
        if (j < NH) At[j][col] = accA[jj];
    }
    __syncthreads();
    for (int j = grp; j < NH; j += 4) {
        float m = At[j][lane];
        #pragma unroll
        for (int off = 32; off; off >>= 1) m = fmaxf(m, __shfl_xor(m, off));
        if (lane == 0) red_m[j] = m;
    }
    __syncthreads();
    #pragma unroll
    for (int jj = 0; jj < 4; ++jj) {
        int j = grp * 4 + jj;
        if (j < NH) At[j][col] = expf(accA[jj] - red_m[j]);
    }
    __syncthreads();
    for (int j = grp; j < NH; j += 4) {
        float s = At[j][lane];
        #pragma unroll
        for (int off = 32; off; off >>= 1) s += __shfl_xor(s, off);
        if (lane == 0) red_s[j] = s;
    }
    __syncthreads();
    float outc = 0.f;
    #pragma unroll
    for (int jj = 0; jj < 4; ++jj) {
        int j = grp * 4 + jj;
        if (j < NH) outc += At[j][col] / red_s[j] * accF[jj];
    }
    outp[t] = outc;
    cat[64 + t] = g_in[b * 256 + t];
    __syncthreads();
    if (t < 64) cat[t] = outp[t] + outp[64 + t] + outp[128 + t] + outp[192 + t];
    __syncthreads();
    float acc = gb[t];
    const float* gwp = gW + t;
    #pragma unroll 4
    for (int i4 = 0; i4 < (64 + 256) / 4; ++i4) {
        float4 cq = ((const float4*)cat)[i4];
        const float* gw4 = gwp + (size_t)i4 * 4 * 256;
        acc = fmaf(cq.x, gw4[0], acc);
        acc = fmaf(cq.y, gw4[256], acc);
        acc = fmaf(cq.z, gw4[512], acc);
        acc = fmaf(cq.w, gw4[768], acc);
    }
    grow[t] = cat[64 + t] + acc;
    __syncthreads();
    {
        float hp = 0.f;
        #pragma unroll 8
        for (int k = 0; k < 64; ++k) {
            int kk = grp * 64 + k;
            hp = fmaf(grow[kk], o1W[(size_t)kk * 64 + col], hp);
        }
        part[grp][col] = hp;
    }
    __syncthreads();
    if (t < 64) {
        float h = part[0][t] + part[1][t] + part[2][t] + part[3][t] + o1b[t];
        h = fmaxf(h, 0.f);
        float sres = h * o2W[t];
        #pragma unroll
        for (int off = 32; off; off >>= 1) sres += __shfl_xor(sres, off);
        if (t == 0) out[b] = sres + o2b[0];
    }
}

extern "C" void kernel_launch(void* const* d_in, const int* in_sizes, int n_in,
                              void* d_out, int out_size, void* d_ws, size_t ws_size,
                              hipStream_t stream) {
    (void)in_sizes; (void)n_in; (void)out_size;
    const float* x    = (const float*)d_in[0];
    const int* ei32   = (const int*)d_in[1];
    const long long* ei64 = (const long long*)d_in[1];
    const int* hidx   = (const int*)d_in[2];
    const float* W1 = (const float*)d_in[3],  *b1 = (const float*)d_in[4];
    const float* W2 = (const float*)d_in[5],  *b2 = (const float*)d_in[6];
    const float* a0W = (const float*)d_in[7],  *a0b = (const float*)d_in[8];
    const float* f0W = (const float*)d_in[9],  *f0b = (const float*)d_in[10];
    const float* g0W = (const float*)d_in[11], *g0b = (const float*)d_in[12];
    const float* a1W = (const float*)d_in[13], *a1b = (const float*)d_in[14];
    const float* f1W = (const float*)d_in[15], *f1b = (const float*)d_in[16];
    const float* g1W = (const float*)d_in[17], *g1b = (const float*)d_in[18];
    const float* a2W = (const float*)d_in[19], *a2b = (const float*)d_in[20];
    const float* f2W = (const float*)d_in[21], *f2b = (const float*)d_in[22];
    const float* g2W = (const float*)d_in[23], *g2b = (const float*)d_in[24];
    const float* o1W = (const float*)d_in[25], *o1b = (const float*)d_in[26];
    const float* o2W = (const float*)d_in[27], *o2b = (const float*)d_in[28];
    float* outp = (float*)d_out;

    char* p = (char*)d_ws;
    auto alloc = [&](size_t bytes) {
        char* r = p;
        p += (bytes + 255) & ~(size_t)255;
        return r;
    };
    float* dinv = (float*)alloc((size_t)N_NODES * 4);
    int* degc   = (int*)alloc((size_t)N_NODES * 4);
    int* offs   = (int*)alloc((size_t)(N_NODES + 1) * 4);
    int* csr    = (int*)alloc((size_t)N_EDGES * 4);
    int* bsums  = (int*)alloc(256 * 4);
    float* g    = (float*)alloc((size_t)B_GRAPH * 256 * 4);
    float* AF   = (float*)alloc((size_t)B_GRAPH * NH * 512 * 4);
    float* xw1  = (float*)alloc((size_t)N_NODES * 256 * 4);
    float* x1   = (float*)alloc((size_t)N_NODES * 256 * 4);
    // xw1 dead after fused_agg256 -> reuse region for xw2 and x2
    float* xw2  = xw1;
    float* x2   = xw1 + (size_t)N_NODES * 64;

    size_t need = (size_t)(p - (char*)d_ws);
    if (need > ws_size) {
        fprintf(stderr, "kernel_launch: ws too small (%zu needed, %zu have)\n", need, ws_size);
        return;
    }

    hipMemsetAsync(degc, 0, (size_t)N_NODES * 4, stream);
    count_deg<<<1600, 256, 0, stream>>>(ei32, ei64, degc);
    scan_block_sums<<<200, 256, 0, stream>>>(degc, bsums);
    scan_finalize<<<200, 256, 0, stream>>>(degc, offs, dinv, bsums);

    // gemm1 (x@W1, dinv-prescaled) | fill_csr | af0
    fused_gemm<64, 256, 3200, 1600><<<3200 + 1600 + 416, 256, 0, stream>>>(
        x, W1, xw1, dinv, ei32, ei64, degc, csr,
        x, hidx, a0W, a0b, f0W, f0b, AF);
    // agg (layer1) | attn reduce 0
    fused_agg256<<<12800 + 256, 256, 0, stream>>>(xw1, dinv, offs, csr, b1, x1,
                                                  AF, g0W, g0b, nullptr, g);
    // gemm2 (x1@W2, dinv-prescaled) | af1
    fused_gemm<256, 64, 800, 0><<<800 + 416, 256, 0, stream>>>(
        x1, W2, xw2, dinv, ei32, ei64, degc, csr,
        x1, hidx, a1W, a1b, f1W, f1b, AF);
    // agg (layer2) | attn reduce 1
    fused_agg64<<<12800 + 256, 256, 0, stream>>>(xw2, dinv, offs, csr, b2, x2,
                                                 AF, g1W, g1b, g, g);
    attn_head64<<<256, 256, 0, stream>>>(x2, hidx, a2W, a2b, f2W, f2b, g2W, g2b, g,
                                         o1W, o1b, o2W, o2b, outp);
}

// Round 8
// 337.092 us; speedup vs baseline: 1.7438x; 1.1094x over previous
//
#include <hip/hip_runtime.h>
#include <math.h>
#include <stdio.h>

#define N_NODES 51200
#define N_EDGES 409600
#define B_GRAPH 256
#define NH 13

typedef float v4f __attribute__((ext_vector_type(4)));
__device__ __forceinline__ void nt_store_f4(float* p, float4 v) {
    v4f w; w.x = v.x; w.y = v.y; w.z = v.z; w.w = v.w;
    __builtin_nontemporal_store(w, (v4f*)p);
}

// ei dtype probe, inlined: int64 ei has zero high words (uniform scalar loads).
__device__ __forceinline__ bool ei_is_64(const int* __restrict__ ei32) {
    int z = 1;
    #pragma unroll
    for (int k = 1; k < 16; k += 2) z &= (ei32[k] == 0);
    return z != 0;
}

// degc pre-zeroed by hipMemsetAsync; self-loop handled as deg = count+1.
__global__ void count_deg(const int* __restrict__ ei32, const long long* __restrict__ ei64,
                          int* __restrict__ degc) {
    int e = blockIdx.x * 256 + threadIdx.x;
    if (e >= N_EDGES) return;
    int v = ei_is_64(ei32) ? (int)ei64[N_EDGES + e] : ei32[N_EDGES + e];
    atomicAdd(&degc[v], 1);
}

__global__ void scan_block_sums(const int* __restrict__ degc, int* __restrict__ bsums) {
    __shared__ int sdata[256];
    int i = blockIdx.x * 256 + threadIdx.x;
    sdata[threadIdx.x] = degc[i];
    __syncthreads();
    for (int s = 128; s > 0; s >>= 1) {
        if (threadIdx.x < s) sdata[threadIdx.x] += sdata[threadIdx.x + s];
        __syncthreads();
    }
    if (threadIdx.x == 0) bsums[blockIdx.x] = sdata[0];
}

// finalize with inline scan of the 200 block sums
__global__ void scan_finalize(int* __restrict__ degc, int* __restrict__ offs,
                              float* __restrict__ dinv, const int* __restrict__ bsums) {
    __shared__ int bs[256];
    __shared__ int s[256];
    const int t = threadIdx.x;
    bs[t] = (t < 200) ? bsums[t] : 0;
    __syncthreads();
    for (int off = 1; off < 256; off <<= 1) {
        int u = (t >= off) ? bs[t - off] : 0;
        __syncthreads();
        bs[t] += u;
        __syncthreads();
    }
    int i = blockIdx.x * 256 + t;
    int cnt = degc[i];
    s[t] = cnt;
    __syncthreads();
    for (int off = 1; off < 256; off <<= 1) {
        int u = (t >= off) ? s[t - off] : 0;
        __syncthreads();
        s[t] += u;
        __syncthreads();
    }
    int base = (blockIdx.x == 0) ? 0 : bs[blockIdx.x - 1];
    int excl = base + s[t] - cnt;
    offs[i] = excl;
    dinv[i] = rsqrtf((float)(cnt + 1));
    degc[i] = excl;  // fill cursor
    if (i == N_NODES - 1) offs[N_NODES] = N_EDGES;
}

// ---- shared GEMM tile body: 64x64 out, BK=32, thread tile 4x4 ----
template <int K, int WS, int YS, bool GATHER, bool SCALE, bool BIAS>
__device__ __forceinline__ void gemm_body(const float* __restrict__ X,
        const float* __restrict__ W, const float* __restrict__ bias,
        const float* __restrict__ dinv, float* __restrict__ Y,
        int row0, const int* __restrict__ rows,
        float* __restrict__ xs, float* __restrict__ ws) {
    constexpr int BK = 32;
    constexpr int XS = BK + 4;  // 36
    const int t = threadIdx.x;
    const int ct = t & 15;
    const int rt = t >> 4;
    float acc[4][4] = {{0.f}};
    for (int kc = 0; kc < K; kc += BK) {
        __syncthreads();
        #pragma unroll
        for (int i = 0; i < 2; ++i) {
            int idx = t + i * 256;
            int q = idx & 7, r = idx >> 3;
            int xr = GATHER ? rows[r] : (row0 + r);
            float4 v = *(const float4*)(X + (size_t)xr * K + kc + q * 4);
            *(float4*)&xs[r * XS + q * 4] = v;
        }
        #pragma unroll
        for (int i = 0; i < 2; ++i) {
            int idx = t + i * 256;
            int q = idx & 15, k = idx >> 4;
            float4 v = *(const float4*)(W + (size_t)(kc + k) * WS + q * 4);
            *(float4*)&ws[k * 64 + q * 4] = v;
        }
        __syncthreads();
        #pragma unroll
        for (int kb = 0; kb < BK; kb += 4) {
            float4 wv[4];
            #pragma unroll
            for (int kk = 0; kk < 4; ++kk)
                wv[kk] = *(const float4*)&ws[(kb + kk) * 64 + ct * 4];
            #pragma unroll
            for (int r = 0; r < 4; ++r) {
                float4 xv = *(const float4*)&xs[(rt * 4 + r) * XS + kb];
                acc[r][0] = fmaf(xv.x, wv[0].x, acc[r][0]);
                acc[r][1] = fmaf(xv.x, wv[0].y, acc[r][1]);
                acc[r][2] = fmaf(xv.x, wv[0].z, acc[r][2]);
                acc[r][3] = fmaf(xv.x, wv[0].w, acc[r][3]);
                acc[r][0] = fmaf(xv.y, wv[1].x, acc[r][0]);
                acc[r][1] = fmaf(xv.y, wv[1].y, acc[r][1]);
                acc[r][2] = fmaf(xv.y, wv[1].z, acc[r][2]);
                acc[r][3] = fmaf(xv.y, wv[1].w, acc[r][3]);
                acc[r][0] = fmaf(xv.z, wv[2].x, acc[r][0]);
                acc[r][1] = fmaf(xv.z, wv[2].y, acc[r][1]);
                acc[r][2] = fmaf(xv.z, wv[2].z, acc[r][2]);
                acc[r][3] = fmaf(xv.z, wv[2].w, acc[r][3]);
                acc[r][0] = fmaf(xv.w, wv[3].x, acc[r][0]);
                acc[r][1] = fmaf(xv.w, wv[3].y, acc[r][1]);
                acc[r][2] = fmaf(xv.w, wv[3].z, acc[r][2]);
                acc[r][3] = fmaf(xv.w, wv[3].w, acc[r][3]);
            }
        }
    }
    #pragma unroll
    for (int r = 0; r < 4; ++r) {
        int row = row0 + rt * 4 + r;
        float4 o = make_float4(acc[r][0], acc[r][1], acc[r][2], acc[r][3]);
        if (BIAS) {
            o.x += bias[ct * 4 + 0];
            o.y += bias[ct * 4 + 1];
            o.z += bias[ct * 4 + 2];
            o.w += bias[ct * 4 + 3];
        }
        if (SCALE) {
            float sc = dinv[row];
            o.x *= sc; o.y *= sc; o.z *= sc; o.w *= sc;
        }
        *(float4*)&Y[(size_t)row * YS + ct * 4] = o;
    }
}

// ---- fused launch: [0,NA) gemm_af (A|F, H=256), [NA,NA+NF) fill_csr,
//      [NA+NF,...) gemm X@W -> Y (dinv-prescaled). Small segments FIRST so
//      their latency hides under the big gemm (round-7 lesson: tail exposure).
template <int K, int NTOT, int NA_BLK, int NF_BLK>
__global__ __launch_bounds__(256) void fused_gemm(const float* __restrict__ X,
        const float* __restrict__ W, float* __restrict__ Y,
        const float* __restrict__ dinv,
        const int* __restrict__ ei32, const long long* __restrict__ ei64,
        int* __restrict__ cursor, int* __restrict__ csr,
        const float* __restrict__ XA, const int* __restrict__ host_idx,
        const float* __restrict__ aW, const float* __restrict__ ab,
        const float* __restrict__ fW, const float* __restrict__ fb,
        float* __restrict__ AF) {
    __shared__ float xs[64 * 36];
    __shared__ float ws[32 * 64];
    __shared__ int rows[64];
    const int bid = blockIdx.x;
    const int t = threadIdx.x;
    if (bid < NA_BLK) {
        const int rb = bid >> 3;        // 8 col-blocks (2*256/64)
        const int cb = bid & 7;
        const int c0 = cb * 64;
        const float* Wp = (c0 < 256) ? (aW + c0) : (fW + (c0 - 256));
        const float* bp = (c0 < 256) ? (ab + c0) : (fb + (c0 - 256));
        if (t < 64) rows[t] = host_idx[rb * 64 + t];
        gemm_body<K, 256, 512, true, false, true>(
            XA, Wp, bp, nullptr, AF + c0, rb * 64, rows, xs, ws);
    } else if (bid < NA_BLK + NF_BLK) {
        int e = (bid - NA_BLK) * 256 + t;
        if (e < N_EDGES) {
            int u, v;
            if (ei_is_64(ei32)) { u = (int)ei64[e]; v = (int)ei64[N_EDGES + e]; }
            else                { u = ei32[e];      v = ei32[N_EDGES + e]; }
            int pos = atomicAdd(&cursor[v], 1);
            csr[pos] = u;
        }
    } else {
        const int gbid = bid - NA_BLK - NF_BLK;
        constexpr int nColBlk = NTOT / 64;
        const int rb = gbid / nColBlk;
        const int cb = gbid - rb * nColBlk;
        gemm_body<K, NTOT, NTOT, false, true, false>(
            X, W + cb * 64, nullptr, dinv, Y + cb * 64, rb * 64, nullptr, xs, ws);
    }
}

// ---- attn reduce body (H=256): softmax over feats + weighted sum + g update ----
__device__ __forceinline__ void attn_red256(const float* __restrict__ AF,
        const float* __restrict__ gW, const float* __restrict__ gb,
        const float* __restrict__ g_in, float* __restrict__ g_out, int b,
        float (*At)[256], float* red_m, float* red_s, float* cat) {
    const int t = threadIdx.x;
    const int wave = t >> 6, lane = t & 63;
    float accA[NH], accF[NH];
    #pragma unroll
    for (int j = 0; j < NH; ++j) {
        const float* r = AF + (size_t)(b * NH + j) * 512;
        accA[j] = r[t];
        accF[j] = r[256 + t];
        At[j][t] = accA[j];
    }
    __syncthreads();
    for (int j = wave; j < NH; j += 4) {
        float m = -3.402823466e38f;
        #pragma unroll
        for (int q = 0; q < 4; ++q) m = fmaxf(m, At[j][q * 64 + lane]);
        #pragma unroll
        for (int off = 32; off; off >>= 1) m = fmaxf(m, __shfl_xor(m, off));
        if (lane == 0) red_m[j] = m;
    }
    __syncthreads();
    #pragma unroll
    for (int j = 0; j < NH; ++j) At[j][t] = expf(accA[j] - red_m[j]);
    __syncthreads();
    for (int j = wave; j < NH; j += 4) {
        float s = 0.f;
        #pragma unroll
        for (int q = 0; q < 4; ++q) s += At[j][q * 64 + lane];
        #pragma unroll
        for (int off = 32; off; off >>= 1) s += __shfl_xor(s, off);
        if (lane == 0) red_s[j] = s;
    }
    __syncthreads();
    float outc = 0.f;
    #pragma unroll
    for (int j = 0; j < NH; ++j) outc += At[j][t] / red_s[j] * accF[j];
    cat[t] = outc;
    float gv = g_in ? g_in[b * 256 + t] : 0.f;
    cat[256 + t] = gv;
    __syncthreads();
    float acc = gb[t];
    const float* gwp = gW + t;
    #pragma unroll 4
    for (int i4 = 0; i4 < 128; ++i4) {
        float4 cq = ((const float4*)cat)[i4];
        const float* gw4 = gwp + (size_t)i4 * 4 * 256;
        acc = fmaf(cq.x, gw4[0], acc);
        acc = fmaf(cq.y, gw4[256], acc);
        acc = fmaf(cq.z, gw4[512], acc);
        acc = fmaf(cq.w, gw4[768], acc);
    }
    g_out[b * 256 + t] = gv + acc;
}

// ---- fused: [0,256) attn reduce 0 (FIRST: hides under the agg wall),
//      [256,13056) agg_max 256-feat (rows pre-scaled; out=relu(dinv_v*max+b)) ----
__global__ __launch_bounds__(256) void fused_agg256(const float* __restrict__ xw,
        const float* __restrict__ dinv, const int* __restrict__ offs,
        const int* __restrict__ csr, const float* __restrict__ bias,
        float* __restrict__ out,
        const float* __restrict__ AF, const float* __restrict__ gW,
        const float* __restrict__ gb, const float* __restrict__ g_in,
        float* __restrict__ g_out) {
    __shared__ float At[NH][256];
    __shared__ float red_m[NH];
    __shared__ float red_s[NH];
    __shared__ float cat[512];
    const int bid = blockIdx.x;
    if (bid < 256) {
        attn_red256(AF, gW, gb, g_in, g_out, bid, At, red_m, red_s, cat);
        return;
    }
    int gid = (bid - 256) * 256 + threadIdx.x;
    int v = gid >> 6;
    int lane = gid & 63;
    const float4* xw4 = (const float4*)xw;
    float4 acc = xw4[(size_t)v * 64 + lane];  // self-loop (pre-scaled row)
    int e0 = offs[v];
    int e1 = offs[v + 1];
    int em = e0 + ((e1 - e0) & ~7);
    for (int e = e0; e < em; e += 8) {
        int u[8];
        #pragma unroll
        for (int i = 0; i < 8; ++i) u[i] = csr[e + i];
        float4 m[8];
        #pragma unroll
        for (int i = 0; i < 8; ++i) m[i] = xw4[(size_t)u[i] * 64 + lane];
        #pragma unroll
        for (int i = 0; i < 8; ++i) {
            acc.x = fmaxf(acc.x, m[i].x);
            acc.y = fmaxf(acc.y, m[i].y);
            acc.z = fmaxf(acc.z, m[i].z);
            acc.w = fmaxf(acc.w, m[i].w);
        }
    }
    if (em < e1) {
        int u[8];
        #pragma unroll
        for (int i = 0; i < 8; ++i) u[i] = csr[(em + i < e1) ? (em + i) : (e1 - 1)];
        float4 m[8];
        #pragma unroll
        for (int i = 0; i < 8; ++i) m[i] = xw4[(size_t)u[i] * 64 + lane];
        #pragma unroll
        for (int i = 0; i < 8; ++i) {
            if (em + i < e1) {
                acc.x = fmaxf(acc.x, m[i].x);
                acc.y = fmaxf(acc.y, m[i].y);
                acc.z = fmaxf(acc.z, m[i].z);
                acc.w = fmaxf(acc.w, m[i].w);
            }
        }
    }
    float dv = dinv[v];
    float4 b4 = ((const float4*)bias)[lane];
    float4 o;
    o.x = fmaxf(fmaf(acc.x, dv, b4.x), 0.f);
    o.y = fmaxf(fmaf(acc.y, dv, b4.y), 0.f);
    o.z = fmaxf(fmaf(acc.z, dv, b4.z), 0.f);
    o.w = fmaxf(fmaf(acc.w, dv, b4.w), 0.f);
    nt_store_f4(out + (size_t)v * 256 + lane * 4, o);
}

// ---- per-graph mega-kernel: layer-1 attn reduce + host-only layer-2 GCN agg
//      + layer-2 attention + g2 update + head. One block per graph.
//      KEY: x2 is consumed ONLY at host rows -> the full 51200-node agg64
//      pass (~105 MB gathers) is unnecessary; compute 13 host rows in-block.
__global__ __launch_bounds__(256) void attn_graph_head(
        const float* __restrict__ AF,   // layer-1 A|F (3328 x 512)
        const float* __restrict__ g1W, const float* __restrict__ g1b,
        const float* __restrict__ g_in, // g after reduce0
        const float* __restrict__ xw2,  // prescaled x1@W2 (51200 x 64)
        const float* __restrict__ dinv, const int* __restrict__ offs,
        const int* __restrict__ csr, const float* __restrict__ b2,
        const int* __restrict__ host_idx,
        const float* __restrict__ a2W, const float* __restrict__ a2b,
        const float* __restrict__ f2W, const float* __restrict__ f2b,
        const float* __restrict__ g2W, const float* __restrict__ g2b,
        const float* __restrict__ o1W, const float* __restrict__ o1b,
        const float* __restrict__ o2W, const float* __restrict__ o2b,
        float* __restrict__ out) {
    __shared__ float At[NH][256];
    __shared__ float red_m[NH];
    __shared__ float red_s[NH];
    __shared__ float cat[512];
    __shared__ float g1s[256];
    __shared__ float x2l[NH * 64];
    __shared__ float outp[256];
    __shared__ float part[4][64];
    __shared__ float grow[256];
    const int b = blockIdx.x;
    const int t = threadIdx.x;
    const int wave = t >> 6, lane = t & 63;

    // ---- phase 1: layer-1 attn reduce (H=256), result to g1s (LDS) ----
    {
        float accA[NH], accF[NH];
        #pragma unroll
        for (int j = 0; j < NH; ++j) {
            const float* r = AF + (size_t)(b * NH + j) * 512;
            accA[j] = r[t];
            accF[j] = r[256 + t];
            At[j][t] = accA[j];
        }
        __syncthreads();
        for (int j = wave; j < NH; j += 4) {
            float m = -3.402823466e38f;
            #pragma unroll
            for (int q = 0; q < 4; ++q) m = fmaxf(m, At[j][q * 64 + lane]);
            #pragma unroll
            for (int off = 32; off; off >>= 1) m = fmaxf(m, __shfl_xor(m, off));
            if (lane == 0) red_m[j] = m;
        }
        __syncthreads();
        #pragma unroll
        for (int j = 0; j < NH; ++j) At[j][t] = expf(accA[j] - red_m[j]);
        __syncthreads();
        for (int j = wave; j < NH; j += 4) {
            float s = 0.f;
            #pragma unroll
            for (int q = 0; q < 4; ++q) s += At[j][q * 64 + lane];
            #pragma unroll
            for (int off = 32; off; off >>= 1) s += __shfl_xor(s, off);
            if (lane == 0) red_s[j] = s;
        }
        __syncthreads();
        float outc = 0.f;
        #pragma unroll
        for (int j = 0; j < NH; ++j) outc += At[j][t] / red_s[j] * accF[j];
        cat[t] = outc;
        float gv = g_in[b * 256 + t];
        cat[256 + t] = gv;
        __syncthreads();
        float acc = g1b[t];
        const float* gwp = g1W + t;
        #pragma unroll 4
        for (int i4 = 0; i4 < 128; ++i4) {
            float4 cq = ((const float4*)cat)[i4];
            const float* gw4 = gwp + (size_t)i4 * 4 * 256;
            acc = fmaf(cq.x, gw4[0], acc);
            acc = fmaf(cq.y, gw4[256], acc);
            acc = fmaf(cq.z, gw4[512], acc);
            acc = fmaf(cq.w, gw4[768], acc);
        }
        g1s[t] = gv + acc;
    }
    // ---- phase 2: layer-2 GCN aggregation for the 13 host rows only ----
    for (int h = wave; h < NH; h += 4) {
        int hv = host_idx[b * NH + h];
        float acc = xw2[(size_t)hv * 64 + lane];  // self (pre-scaled row)
        int e0 = offs[hv], e1 = offs[hv + 1];
        for (int e = e0; e < e1; e += 8) {
            int u[8];
            #pragma unroll
            for (int i = 0; i < 8; ++i) u[i] = csr[(e + i < e1) ? (e + i) : (e1 - 1)];
            float m[8];
            #pragma unroll
            for (int i = 0; i < 8; ++i) m[i] = xw2[(size_t)u[i] * 64 + lane];
            #pragma unroll
            for (int i = 0; i < 8; ++i)
                if (e + i < e1) acc = fmaxf(acc, m[i]);
        }
        x2l[h * 64 + lane] = fmaxf(fmaf(acc, dinv[hv], b2[lane]), 0.f);
    }
    __syncthreads();
    // ---- phase 3: layer-2 attention (H=64) over x2l ----
    const int col = lane;
    const int grp = wave;
    float accA[4], accF[4];
    {
        float abv = a2b[col], fbv = f2b[col];
        #pragma unroll
        for (int jj = 0; jj < 4; ++jj) { accA[jj] = abv; accF[jj] = fbv; }
    }
    #pragma unroll 4
    for (int k = 0; k < 64; ++k) {
        float wa = a2W[k * 64 + col];
        float wf = f2W[k * 64 + col];
        #pragma unroll
        for (int jj = 0; jj < 4; ++jj) {
            int j = grp * 4 + jj;
            if (j >= NH) j = 0;
            float xv = x2l[j * 64 + k];
            accA[jj] = fmaf(xv, wa, accA[jj]);
            accF[jj] = fmaf(xv, wf, accF[jj]);
        }
    }
    #pragma unroll
    for (int jj = 0; jj < 4; ++jj) {
        int j = grp * 4 + jj;
        if (j < NH) At[j][col] = accA[jj];
    }
    __syncthreads();
    for (int j = grp; j < NH; j += 4) {
        float m = At[j][lane];
        #pragma unroll
        for (int off = 32; off; off >>= 1) m = fmaxf(m, __shfl_xor(m, off));
        if (lane == 0) red_m[j] = m;
    }
    __syncthreads();
    #pragma unroll
    for (int jj = 0; jj < 4; ++jj) {
        int j = grp * 4 + jj;
        if (j < NH) At[j][col] = expf(accA[jj] - red_m[j]);
    }
    __syncthreads();
    for (int j = grp; j < NH; j += 4) {
        float s = At[j][lane];
        #pragma unroll
        for (int off = 32; off; off >>= 1) s += __shfl_xor(s, off);
        if (lane == 0) red_s[j] = s;
    }
    __syncthreads();
    float outc = 0.f;
    #pragma unroll
    for (int jj = 0; jj < 4; ++jj) {
        int j = grp * 4 + jj;
        if (j < NH) outc += At[j][col] / red_s[j] * accF[jj];
    }
    outp[t] = outc;
    cat[64 + t] = g1s[t];
    __syncthreads();
    if (t < 64) cat[t] = outp[t] + outp[64 + t] + outp[128 + t] + outp[192 + t];
    __syncthreads();
    // g2 residual update
    float acc2 = g2b[t];
    const float* gwp = g2W + t;
    #pragma unroll 4
    for (int i4 = 0; i4 < (64 + 256) / 4; ++i4) {
        float4 cq = ((const float4*)cat)[i4];
        const float* gw4 = gwp + (size_t)i4 * 4 * 256;
        acc2 = fmaf(cq.x, gw4[0], acc2);
        acc2 = fmaf(cq.y, gw4[256], acc2);
        acc2 = fmaf(cq.z, gw4[512], acc2);
        acc2 = fmaf(cq.w, gw4[768], acc2);
    }
    grow[t] = cat[64 + t] + acc2;
    __syncthreads();
    // head: out[b] = relu(grow@o1W+o1b)@o2W + o2b
    {
        float hp = 0.f;
        #pragma unroll 8
        for (int k = 0; k < 64; ++k) {
            int kk = grp * 64 + k;
            hp = fmaf(grow[kk], o1W[(size_t)kk * 64 + col], hp);
        }
        part[grp][col] = hp;
    }
    __syncthreads();
    if (t < 64) {
        float h = part[0][t] + part[1][t] + part[2][t] + part[3][t] + o1b[t];
        h = fmaxf(h, 0.f);
        float sres = h * o2W[t];
        #pragma unroll
        for (int off = 32; off; off >>= 1) sres += __shfl_xor(sres, off);
        if (t == 0) out[b] = sres + o2b[0];
    }
}

extern "C" void kernel_launch(void* const* d_in, const int* in_sizes, int n_in,
                              void* d_out, int out_size, void* d_ws, size_t ws_size,
                              hipStream_t stream) {
    (void)in_sizes; (void)n_in; (void)out_size;
    const float* x    = (const float*)d_in[0];
    const int* ei32   = (const int*)d_in[1];
    const long long* ei64 = (const long long*)d_in[1];
    const int* hidx   = (const int*)d_in[2];
    const float* W1 = (const float*)d_in[3],  *b1 = (const float*)d_in[4];
    const float* W2 = (const float*)d_in[5],  *b2 = (const float*)d_in[6];
    const float* a0W = (const float*)d_in[7],  *a0b = (const float*)d_in[8];
    const float* f0W = (const float*)d_in[9],  *f0b = (const float*)d_in[10];
    const float* g0W = (const float*)d_in[11], *g0b = (const float*)d_in[12];
    const float* a1W = (const float*)d_in[13], *a1b = (const float*)d_in[14];
    const float* f1W = (const float*)d_in[15], *f1b = (const float*)d_in[16];
    const float* g1W = (const float*)d_in[17], *g1b = (const float*)d_in[18];
    const float* a2W = (const float*)d_in[19], *a2b = (const float*)d_in[20];
    const float* f2W = (const float*)d_in[21], *f2b = (const float*)d_in[22];
    const float* g2W = (const float*)d_in[23], *g2b = (const float*)d_in[24];
    const float* o1W = (const float*)d_in[25], *o1b = (const float*)d_in[26];
    const float* o2W = (const float*)d_in[27], *o2b = (const float*)d_in[28];
    float* outp = (float*)d_out;

    char* p = (char*)d_ws;
    auto alloc = [&](size_t bytes) {
        char* r = p;
        p += (bytes + 255) & ~(size_t)255;
        return r;
    };
    float* dinv = (float*)alloc((size_t)N_NODES * 4);
    int* degc   = (int*)alloc((size_t)N_NODES * 4);
    int* offs   = (int*)alloc((size_t)(N_NODES + 1) * 4);
    int* csr    = (int*)alloc((size_t)N_EDGES * 4);
    int* bsums  = (int*)alloc(256 * 4);
    float* g    = (float*)alloc((size_t)B_GRAPH * 256 * 4);
    float* AF   = (float*)alloc((size_t)B_GRAPH * NH * 512 * 4);
    float* xw1  = (float*)alloc((size_t)N_NODES * 256 * 4);
    float* x1   = (float*)alloc((size_t)N_NODES * 256 * 4);
    // xw1 dead after fused_agg256 -> reuse region for xw2
    float* xw2  = xw1;

    size_t need = (size_t)(p - (char*)d_ws);
    if (need > ws_size) {
        fprintf(stderr, "kernel_launch: ws too small (%zu needed, %zu have)\n", need, ws_size);
        return;
    }

    hipMemsetAsync(degc, 0, (size_t)N_NODES * 4, stream);
    count_deg<<<1600, 256, 0, stream>>>(ei32, ei64, degc);
    scan_block_sums<<<200, 256, 0, stream>>>(degc, bsums);
    scan_finalize<<<200, 256, 0, stream>>>(degc, offs, dinv, bsums);

    // af0 | fill_csr | gemm1 (x@W1, dinv-prescaled)
    fused_gemm<64, 256, 416, 1600><<<416 + 1600 + 3200, 256, 0, stream>>>(
        x, W1, xw1, dinv, ei32, ei64, degc, csr,
        x, hidx, a0W, a0b, f0W, f0b, AF);
    // attn reduce 0 | agg (layer 1)
    fused_agg256<<<256 + 12800, 256, 0, stream>>>(xw1, dinv, offs, csr, b1, x1,
                                                  AF, g0W, g0b, nullptr, g);
    // af1 | gemm2 (x1@W2, dinv-prescaled)
    fused_gemm<256, 64, 416, 0><<<416 + 800, 256, 0, stream>>>(
        x1, W2, xw2, dinv, ei32, ei64, degc, csr,
        x1, hidx, a1W, a1b, f1W, f1b, AF);
    // per-graph: reduce1 + host-only agg64 + attn2 + g2 update + head
    attn_graph_head<<<256, 256, 0, stream>>>(
        AF, g1W, g1b, g, xw2, dinv, offs, csr, b2, hidx,
        a2W, a2b, f2W, f2b, g2W, g2b, o1W, o1b, o2W, o2b, outp);
}

// Round 9
// 323.988 us; speedup vs baseline: 1.8144x; 1.0404x over previous
//
#include <hip/hip_runtime.h>
#include <math.h>
#include <stdio.h>

#define N_NODES 51200
#define N_EDGES 409600
#define B_GRAPH 256
#define NH 13

typedef float v4f __attribute__((ext_vector_type(4)));
__device__ __forceinline__ void nt_store_f4(float* p, float4 v) {
    v4f w; w.x = v.x; w.y = v.y; w.z = v.z; w.w = v.w;
    __builtin_nontemporal_store(w, (v4f*)p);
}

// bf16 pack (RNE) / unpack helpers: payload-only compression for the gather.
__device__ __forceinline__ unsigned pack_bf2(float a, float b) {
    unsigned ua = __float_as_uint(a);
    ua = (ua + 0x7fffu + ((ua >> 16) & 1u)) >> 16;
    unsigned ub = __float_as_uint(b);
    ub = (ub + 0x7fffu + ((ub >> 16) & 1u)) & 0xffff0000u;
    return ua | ub;
}
__device__ __forceinline__ float bf_lo(unsigned u) { return __uint_as_float(u << 16); }
__device__ __forceinline__ float bf_hi(unsigned u) { return __uint_as_float(u & 0xffff0000u); }

// ei dtype probe, inlined: int64 ei has zero high words (uniform scalar loads).
__device__ __forceinline__ bool ei_is_64(const int* __restrict__ ei32) {
    int z = 1;
    #pragma unroll
    for (int k = 1; k < 16; k += 2) z &= (ei32[k] == 0);
    return z != 0;
}

// degc pre-zeroed by hipMemsetAsync; self-loop handled as deg = count+1.
__global__ void count_deg(const int* __restrict__ ei32, const long long* __restrict__ ei64,
                          int* __restrict__ degc) {
    int e = blockIdx.x * 256 + threadIdx.x;
    if (e >= N_EDGES) return;
    int v = ei_is_64(ei32) ? (int)ei64[N_EDGES + e] : ei32[N_EDGES + e];
    atomicAdd(&degc[v], 1);
}

__global__ void scan_block_sums(const int* __restrict__ degc, int* __restrict__ bsums) {
    __shared__ int sdata[256];
    int i = blockIdx.x * 256 + threadIdx.x;
    sdata[threadIdx.x] = degc[i];
    __syncthreads();
    for (int s = 128; s > 0; s >>= 1) {
        if (threadIdx.x < s) sdata[threadIdx.x] += sdata[threadIdx.x + s];
        __syncthreads();
    }
    if (threadIdx.x == 0) bsums[blockIdx.x] = sdata[0];
}

// finalize with inline scan of the 200 block sums
__global__ void scan_finalize(int* __restrict__ degc, int* __restrict__ offs,
                              float* __restrict__ dinv, const int* __restrict__ bsums) {
    __shared__ int bs[256];
    __shared__ int s[256];
    const int t = threadIdx.x;
    bs[t] = (t < 200) ? bsums[t] : 0;
    __syncthreads();
    for (int off = 1; off < 256; off <<= 1) {
        int u = (t >= off) ? bs[t - off] : 0;
        __syncthreads();
        bs[t] += u;
        __syncthreads();
    }
    int i = blockIdx.x * 256 + t;
    int cnt = degc[i];
    s[t] = cnt;
    __syncthreads();
    for (int off = 1; off < 256; off <<= 1) {
        int u = (t >= off) ? s[t - off] : 0;
        __syncthreads();
        s[t] += u;
        __syncthreads();
    }
    int base = (blockIdx.x == 0) ? 0 : bs[blockIdx.x - 1];
    int excl = base + s[t] - cnt;
    offs[i] = excl;
    dinv[i] = rsqrtf((float)(cnt + 1));
    degc[i] = excl;  // fill cursor
    if (i == N_NODES - 1) offs[N_NODES] = N_EDGES;
}

// ---- shared GEMM tile body: 64x64 out, BK=32, thread tile 4x4 ----
// BF16OUT: Y is a bf16 buffer (element stride YS); caller pre-offsets Y by
// col-block in bf16 elements (cb*64 bf16 = cb*32 floats).
template <int K, int WS, int YS, bool GATHER, bool SCALE, bool BIAS, bool BF16OUT>
__device__ __forceinline__ void gemm_body(const float* __restrict__ X,
        const float* __restrict__ W, const float* __restrict__ bias,
        const float* __restrict__ dinv, float* __restrict__ Y,
        int row0, const int* __restrict__ rows,
        float* __restrict__ xs, float* __restrict__ ws) {
    constexpr int BK = 32;
    constexpr int XS = BK + 4;  // 36
    const int t = threadIdx.x;
    const int ct = t & 15;
    const int rt = t >> 4;
    float acc[4][4] = {{0.f}};
    for (int kc = 0; kc < K; kc += BK) {
        __syncthreads();
        #pragma unroll
        for (int i = 0; i < 2; ++i) {
            int idx = t + i * 256;
            int q = idx & 7, r = idx >> 3;
            int xr = GATHER ? rows[r] : (row0 + r);
            float4 v = *(const float4*)(X + (size_t)xr * K + kc + q * 4);
            *(float4*)&xs[r * XS + q * 4] = v;
        }
        #pragma unroll
        for (int i = 0; i < 2; ++i) {
            int idx = t + i * 256;
            int q = idx & 15, k = idx >> 4;
            float4 v = *(const float4*)(W + (size_t)(kc + k) * WS + q * 4);
            *(float4*)&ws[k * 64 + q * 4] = v;
        }
        __syncthreads();
        #pragma unroll
        for (int kb = 0; kb < BK; kb += 4) {
            float4 wv[4];
            #pragma unroll
            for (int kk = 0; kk < 4; ++kk)
                wv[kk] = *(const float4*)&ws[(kb + kk) * 64 + ct * 4];
            #pragma unroll
            for (int r = 0; r < 4; ++r) {
                float4 xv = *(const float4*)&xs[(rt * 4 + r) * XS + kb];
                acc[r][0] = fmaf(xv.x, wv[0].x, acc[r][0]);
                acc[r][1] = fmaf(xv.x, wv[0].y, acc[r][1]);
                acc[r][2] = fmaf(xv.x, wv[0].z, acc[r][2]);
                acc[r][3] = fmaf(xv.x, wv[0].w, acc[r][3]);
                acc[r][0] = fmaf(xv.y, wv[1].x, acc[r][0]);
                acc[r][1] = fmaf(xv.y, wv[1].y, acc[r][1]);
                acc[r][2] = fmaf(xv.y, wv[1].z, acc[r][2]);
                acc[r][3] = fmaf(xv.y, wv[1].w, acc[r][3]);
                acc[r][0] = fmaf(xv.z, wv[2].x, acc[r][0]);
                acc[r][1] = fmaf(xv.z, wv[2].y, acc[r][1]);
                acc[r][2] = fmaf(xv.z, wv[2].z, acc[r][2]);
                acc[r][3] = fmaf(xv.z, wv[2].w, acc[r][3]);
                acc[r][0] = fmaf(xv.w, wv[3].x, acc[r][0]);
                acc[r][1] = fmaf(xv.w, wv[3].y, acc[r][1]);
                acc[r][2] = fmaf(xv.w, wv[3].z, acc[r][2]);
                acc[r][3] = fmaf(xv.w, wv[3].w, acc[r][3]);
            }
        }
    }
    #pragma unroll
    for (int r = 0; r < 4; ++r) {
        int row = row0 + rt * 4 + r;
        float4 o = make_float4(acc[r][0], acc[r][1], acc[r][2], acc[r][3]);
        if (BIAS) {
            o.x += bias[ct * 4 + 0];
            o.y += bias[ct * 4 + 1];
            o.z += bias[ct * 4 + 2];
            o.w += bias[ct * 4 + 3];
        }
        if (SCALE) {
            float sc = dinv[row];
            o.x *= sc; o.y *= sc; o.z *= sc; o.w *= sc;
        }
        if (BF16OUT) {
            unsigned short* yb = (unsigned short*)Y + (size_t)row * YS;
            uint2 pk;
            pk.x = pack_bf2(o.x, o.y);
            pk.y = pack_bf2(o.z, o.w);
            ((uint2*)yb)[ct] = pk;
        } else {
            *(float4*)&Y[(size_t)row * YS + ct * 4] = o;
        }
    }
}

// ---- fused launch: [0,NA) gemm_af (A|F, H=256), [NA,NA+NF) fill_csr,
//      [NA+NF,...) gemm X@W -> Y (dinv-prescaled, optionally bf16-packed).
//      Small segments FIRST so their latency hides under the big gemm.
template <int K, int NTOT, int NA_BLK, int NF_BLK, bool BF16Y>
__global__ __launch_bounds__(256) void fused_gemm(const float* __restrict__ X,
        const float* __restrict__ W, float* __restrict__ Y,
        const float* __restrict__ dinv,
        const int* __restrict__ ei32, const long long* __restrict__ ei64,
        int* __restrict__ cursor, int* __restrict__ csr,
        const float* __restrict__ XA, const int* __restrict__ host_idx,
        const float* __restrict__ aW, const float* __restrict__ ab,
        const float* __restrict__ fW, const float* __restrict__ fb,
        float* __restrict__ AF) {
    __shared__ float xs[64 * 36];
    __shared__ float ws[32 * 64];
    __shared__ int rows[64];
    const int bid = blockIdx.x;
    const int t = threadIdx.x;
    if (bid < NA_BLK) {
        const int rb = bid >> 3;        // 8 col-blocks (2*256/64)
        const int cb = bid & 7;
        const int c0 = cb * 64;
        const float* Wp = (c0 < 256) ? (aW + c0) : (fW + (c0 - 256));
        const float* bp = (c0 < 256) ? (ab + c0) : (fb + (c0 - 256));
        if (t < 64) rows[t] = host_idx[rb * 64 + t];
        gemm_body<K, 256, 512, true, false, true, false>(
            XA, Wp, bp, nullptr, AF + c0, rb * 64, rows, xs, ws);
    } else if (bid < NA_BLK + NF_BLK) {
        int e = (bid - NA_BLK) * 256 + t;
        if (e < N_EDGES) {
            int u, v;
            if (ei_is_64(ei32)) { u = (int)ei64[e]; v = (int)ei64[N_EDGES + e]; }
            else                { u = ei32[e];      v = ei32[N_EDGES + e]; }
            int pos = atomicAdd(&cursor[v], 1);
            csr[pos] = u;
        }
    } else {
        const int gbid = bid - NA_BLK - NF_BLK;
        constexpr int nColBlk = NTOT / 64;
        const int rb = gbid / nColBlk;
        const int cb = gbid - rb * nColBlk;
        // bf16 Y: col offset cb*64 bf16 elements = cb*32 floats
        float* Yp = BF16Y ? (Y + cb * 32) : (Y + cb * 64);
        gemm_body<K, NTOT, NTOT, false, true, false, BF16Y>(
            X, W + cb * 64, nullptr, dinv, Yp, rb * 64, nullptr, xs, ws);
    }
}

// ---- attn reduce body (H=256): softmax over feats + weighted sum + g update ----
__device__ __forceinline__ void attn_red256(const float* __restrict__ AF,
        const float* __restrict__ gW, const float* __restrict__ gb,
        const float* __restrict__ g_in, float* __restrict__ g_out, int b,
        float (*At)[256], float* red_m, float* red_s, float* cat) {
    const int t = threadIdx.x;
    const int wave = t >> 6, lane = t & 63;
    float accA[NH], accF[NH];
    #pragma unroll
    for (int j = 0; j < NH; ++j) {
        const float* r = AF + (size_t)(b * NH + j) * 512;
        accA[j] = r[t];
        accF[j] = r[256 + t];
        At[j][t] = accA[j];
    }
    __syncthreads();
    for (int j = wave; j < NH; j += 4) {
        float m = -3.402823466e38f;
        #pragma unroll
        for (int q = 0; q < 4; ++q) m = fmaxf(m, At[j][q * 64 + lane]);
        #pragma unroll
        for (int off = 32; off; off >>= 1) m = fmaxf(m, __shfl_xor(m, off));
        if (lane == 0) red_m[j] = m;
    }
    __syncthreads();
    #pragma unroll
    for (int j = 0; j < NH; ++j) At[j][t] = expf(accA[j] - red_m[j]);
    __syncthreads();
    for (int j = wave; j < NH; j += 4) {
        float s = 0.f;
        #pragma unroll
        for (int q = 0; q < 4; ++q) s += At[j][q * 64 + lane];
        #pragma unroll
        for (int off = 32; off; off >>= 1) s += __shfl_xor(s, off);
        if (lane == 0) red_s[j] = s;
    }
    __syncthreads();
    float outc = 0.f;
    #pragma unroll
    for (int j = 0; j < NH; ++j) outc += At[j][t] / red_s[j] * accF[j];
    cat[t] = outc;
    float gv = g_in ? g_in[b * 256 + t] : 0.f;
    cat[256 + t] = gv;
    __syncthreads();
    float acc = gb[t];
    const float* gwp = gW + t;
    #pragma unroll 4
    for (int i4 = 0; i4 < 128; ++i4) {
        float4 cq = ((const float4*)cat)[i4];
        const float* gw4 = gwp + (size_t)i4 * 4 * 256;
        acc = fmaf(cq.x, gw4[0], acc);
        acc = fmaf(cq.y, gw4[256], acc);
        acc = fmaf(cq.z, gw4[512], acc);
        acc = fmaf(cq.w, gw4[768], acc);
    }
    g_out[b * 256 + t] = gv + acc;
}

// ---- fused: [0,256) attn reduce 0 (first: hides under the agg wall),
//      [256,13056) agg_max over bf16-packed rows (out=relu(dinv_v*max+b), fp32) ----
__global__ __launch_bounds__(256) void fused_agg256(const uint2* __restrict__ xwb,
        const float* __restrict__ dinv, const int* __restrict__ offs,
        const int* __restrict__ csr, const float* __restrict__ bias,
        float* __restrict__ out,
        const float* __restrict__ AF, const float* __restrict__ gW,
        const float* __restrict__ gb, const float* __restrict__ g_in,
        float* __restrict__ g_out) {
    __shared__ float At[NH][256];
    __shared__ float red_m[NH];
    __shared__ float red_s[NH];
    __shared__ float cat[512];
    const int bid = blockIdx.x;
    if (bid < 256) {
        attn_red256(AF, gW, gb, g_in, g_out, bid, At, red_m, red_s, cat);
        return;
    }
    int gid = (bid - 256) * 256 + threadIdx.x;
    int v = gid >> 6;
    int lane = gid & 63;
    uint2 sw = xwb[(size_t)v * 64 + lane];  // self (pre-scaled bf16 row)
    float4 acc = make_float4(bf_lo(sw.x), bf_hi(sw.x), bf_lo(sw.y), bf_hi(sw.y));
    int e0 = offs[v];
    int e1 = offs[v + 1];
    int em = e0 + ((e1 - e0) & ~7);
    for (int e = e0; e < em; e += 8) {
        int u[8];
        #pragma unroll
        for (int i = 0; i < 8; ++i) u[i] = csr[e + i];
        uint2 m[8];
        #pragma unroll
        for (int i = 0; i < 8; ++i) m[i] = xwb[(size_t)u[i] * 64 + lane];
        #pragma unroll
        for (int i = 0; i < 8; ++i) {
            acc.x = fmaxf(acc.x, bf_lo(m[i].x));
            acc.y = fmaxf(acc.y, bf_hi(m[i].x));
            acc.z = fmaxf(acc.z, bf_lo(m[i].y));
            acc.w = fmaxf(acc.w, bf_hi(m[i].y));
        }
    }
    if (em < e1) {
        int u[8];
        #pragma unroll
        for (int i = 0; i < 8; ++i) u[i] = csr[(em + i < e1) ? (em + i) : (e1 - 1)];
        uint2 m[8];
        #pragma unroll
        for (int i = 0; i < 8; ++i) m[i] = xwb[(size_t)u[i] * 64 + lane];
        #pragma unroll
        for (int i = 0; i < 8; ++i) {
            if (em + i < e1) {
                acc.x = fmaxf(acc.x, bf_lo(m[i].x));
                acc.y = fmaxf(acc.y, bf_hi(m[i].x));
                acc.z = fmaxf(acc.z, bf_lo(m[i].y));
                acc.w = fmaxf(acc.w, bf_hi(m[i].y));
            }
        }
    }
    float dv = dinv[v];
    float4 b4 = ((const float4*)bias)[lane];
    float4 o;
    o.x = fmaxf(fmaf(acc.x, dv, b4.x), 0.f);
    o.y = fmaxf(fmaf(acc.y, dv, b4.y), 0.f);
    o.z = fmaxf(fmaf(acc.z, dv, b4.z), 0.f);
    o.w = fmaxf(fmaf(acc.w, dv, b4.w), 0.f);
    nt_store_f4(out + (size_t)v * 256 + lane * 4, o);
}

// ---- per-graph mega-kernel: layer-1 attn reduce + host-only layer-2 GCN agg
//      + layer-2 attention + g2 update + head. One block per graph. ----
__global__ __launch_bounds__(256) void attn_graph_head(
        const float* __restrict__ AF,   // layer-1 A|F (3328 x 512)
        const float* __restrict__ g1W, const float* __restrict__ g1b,
        const float* __restrict__ g_in, // g after reduce0
        const float* __restrict__ xw2,  // prescaled x1@W2 (51200 x 64, fp32)
        const float* __restrict__ dinv, const int* __restrict__ offs,
        const int* __restrict__ csr, const float* __restrict__ b2,
        const int* __restrict__ host_idx,
        const float* __restrict__ a2W, const float* __restrict__ a2b,
        const float* __restrict__ f2W, const float* __restrict__ f2b,
        const float* __restrict__ g2W, const float* __restrict__ g2b,
        const float* __restrict__ o1W, const float* __restrict__ o1b,
        const float* __restrict__ o2W, const float* __restrict__ o2b,
        float* __restrict__ out) {
    __shared__ float At[NH][256];
    __shared__ float red_m[NH];
    __shared__ float red_s[NH];
    __shared__ float cat[512];
    __shared__ float g1s[256];
    __shared__ float x2l[NH * 64];
    __shared__ float outp[256];
    __shared__ float part[4][64];
    __shared__ float grow[256];
    const int b = blockIdx.x;
    const int t = threadIdx.x;
    const int wave = t >> 6, lane = t & 63;

    // ---- phase 1: layer-1 attn reduce (H=256), result to g1s (LDS) ----
    {
        float accA[NH], accF[NH];
        #pragma unroll
        for (int j = 0; j < NH; ++j) {
            const float* r = AF + (size_t)(b * NH + j) * 512;
            accA[j] = r[t];
            accF[j] = r[256 + t];
            At[j][t] = accA[j];
        }
        __syncthreads();
        for (int j = wave; j < NH; j += 4) {
            float m = -3.402823466e38f;
            #pragma unroll
            for (int q = 0; q < 4; ++q) m = fmaxf(m, At[j][q * 64 + lane]);
            #pragma unroll
            for (int off = 32; off; off >>= 1) m = fmaxf(m, __shfl_xor(m, off));
            if (lane == 0) red_m[j] = m;
        }
        __syncthreads();
        #pragma unroll
        for (int j = 0; j < NH; ++j) At[j][t] = expf(accA[j] - red_m[j]);
        __syncthreads();
        for (int j = wave; j < NH; j += 4) {
            float s = 0.f;
            #pragma unroll
            for (int q = 0; q < 4; ++q) s += At[j][q * 64 + lane];
            #pragma unroll
            for (int off = 32; off; off >>= 1) s += __shfl_xor(s, off);
            if (lane == 0) red_s[j] = s;
        }
        __syncthreads();
        float outc = 0.f;
        #pragma unroll
        for (int j = 0; j < NH; ++j) outc += At[j][t] / red_s[j] * accF[j];
        cat[t] = outc;
        float gv = g_in[b * 256 + t];
        cat[256 + t] = gv;
        __syncthreads();
        float acc = g1b[t];
        const float* gwp = g1W + t;
        #pragma unroll 4
        for (int i4 = 0; i4 < 128; ++i4) {
            float4 cq = ((const float4*)cat)[i4];
            const float* gw4 = gwp + (size_t)i4 * 4 * 256;
            acc = fmaf(cq.x, gw4[0], acc);
            acc = fmaf(cq.y, gw4[256], acc);
            acc = fmaf(cq.z, gw4[512], acc);
            acc = fmaf(cq.w, gw4[768], acc);
        }
        g1s[t] = gv + acc;
    }
    // ---- phase 2: layer-2 GCN aggregation for the 13 host rows only ----
    for (int h = wave; h < NH; h += 4) {
        int hv = host_idx[b * NH + h];
        float acc = xw2[(size_t)hv * 64 + lane];  // self (pre-scaled row)
        int e0 = offs[hv], e1 = offs[hv + 1];
        for (int e = e0; e < e1; e += 8) {
            int u[8];
            #pragma unroll
            for (int i = 0; i < 8; ++i) u[i] = csr[(e + i < e1) ? (e + i) : (e1 - 1)];
            float m[8];
            #pragma unroll
            for (int i = 0; i < 8; ++i) m[i] = xw2[(size_t)u[i] * 64 + lane];
            #pragma unroll
            for (int i = 0; i < 8; ++i)
                if (e + i < e1) acc = fmaxf(acc, m[i]);
        }
        x2l[h * 64 + lane] = fmaxf(fmaf(acc, dinv[hv], b2[lane]), 0.f);
    }
    __syncthreads();
    // ---- phase 3: layer-2 attention (H=64) over x2l ----
    const int col = lane;
    const int grp = wave;
    float accA[4], accF[4];
    {
        float abv = a2b[col], fbv = f2b[col];
        #pragma unroll
        for (int jj = 0; jj < 4; ++jj) { accA[jj] = abv; accF[jj] = fbv; }
    }
    #pragma unroll 4
    for (int k = 0; k < 64; ++k) {
        float wa = a2W[k * 64 + col];
        float wf = f2W[k * 64 + col];
        #pragma unroll
        for (int jj = 0; jj < 4; ++jj) {
            int j = grp * 4 + jj;
            if (j >= NH) j = 0;
            float xv = x2l[j * 64 + k];
            accA[jj] = fmaf(xv, wa, accA[jj]);
            accF[jj] = fmaf(xv, wf, accF[jj]);
        }
    }
    #pragma unroll
    for (int jj = 0; jj < 4; ++jj) {
        int j = grp * 4 + jj;
        if (j < NH) At[j][col] = accA[jj];
    }
    __syncthreads();
    for (int j = grp; j < NH; j += 4) {
        float m = At[j][lane];
        #pragma unroll
        for (int off = 32; off; off >>= 1) m = fmaxf(m, __shfl_xor(m, off));
        if (lane == 0) red_m[j] = m;
    }
    __syncthreads();
    #pragma unroll
    for (int jj = 0; jj < 4; ++jj) {
        int j = grp * 4 + jj;
        if (j < NH) At[j][col] = expf(accA[jj] - red_m[j]);
    }
    __syncthreads();
    for (int j = grp; j < NH; j += 4) {
        float s = At[j][lane];
        #pragma unroll
        for (int off = 32; off; off >>= 1) s += __shfl_xor(s, off);
        if (lane == 0) red_s[j] = s;
    }
    __syncthreads();
    float outc = 0.f;
    #pragma unroll
    for (int jj = 0; jj < 4; ++jj) {
        int j = grp * 4 + jj;
        if (j < NH) outc += At[j][col] / red_s[j] * accF[jj];
    }
    outp[t] = outc;
    cat[64 + t] = g1s[t];
    __syncthreads();
    if (t < 64) cat[t] = outp[t] + outp[64 + t] + outp[128 + t] + outp[192 + t];
    __syncthreads();
    // g2 residual update
    float acc2 = g2b[t];
    const float* gwp = g2W + t;
    #pragma unroll 4
    for (int i4 = 0; i4 < (64 + 256) / 4; ++i4) {
        float4 cq = ((const float4*)cat)[i4];
        const float* gw4 = gwp + (size_t)i4 * 4 * 256;
        acc2 = fmaf(cq.x, gw4[0], acc2);
        acc2 = fmaf(cq.y, gw4[256], acc2);
        acc2 = fmaf(cq.z, gw4[512], acc2);
        acc2 = fmaf(cq.w, gw4[768], acc2);
    }
    grow[t] = cat[64 + t] + acc2;
    __syncthreads();
    // head: out[b] = relu(grow@o1W+o1b)@o2W + o2b
    {
        float hp = 0.f;
        #pragma unroll 8
        for (int k = 0; k < 64; ++k) {
            int kk = grp * 64 + k;
            hp = fmaf(grow[kk], o1W[(size_t)kk * 64 + col], hp);
        }
        part[grp][col] = hp;
    }
    __syncthreads();
    if (t < 64) {
        float h = part[0][t] + part[1][t] + part[2][t] + part[3][t] + o1b[t];
        h = fmaxf(h, 0.f);
        float sres = h * o2W[t];
        #pragma unroll
        for (int off = 32; off; off >>= 1) sres += __shfl_xor(sres, off);
        if (t == 0) out[b] = sres + o2b[0];
    }
}

extern "C" void kernel_launch(void* const* d_in, const int* in_sizes, int n_in,
                              void* d_out, int out_size, void* d_ws, size_t ws_size,
                              hipStream_t stream) {
    (void)in_sizes; (void)n_in; (void)out_size;
    const float* x    = (const float*)d_in[0];
    const int* ei32   = (const int*)d_in[1];
    const long long* ei64 = (const long long*)d_in[1];
    const int* hidx   = (const int*)d_in[2];
    const float* W1 = (const float*)d_in[3],  *b1 = (const float*)d_in[4];
    const float* W2 = (const float*)d_in[5],  *b2 = (const float*)d_in[6];
    const float* a0W = (const float*)d_in[7],  *a0b = (const float*)d_in[8];
    const float* f0W = (const float*)d_in[9],  *f0b = (const float*)d_in[10];
    const float* g0W = (const float*)d_in[11], *g0b = (const float*)d_in[12];
    const float* a1W = (const float*)d_in[13], *a1b = (const float*)d_in[14];
    const float* f1W = (const float*)d_in[15], *f1b = (const float*)d_in[16];
    const float* g1W = (const float*)d_in[17], *g1b = (const float*)d_in[18];
    const float* a2W = (const float*)d_in[19], *a2b = (const float*)d_in[20];
    const float* f2W = (const float*)d_in[21], *f2b = (const float*)d_in[22];
    const float* g2W = (const float*)d_in[23], *g2b = (const float*)d_in[24];
    const float* o1W = (const float*)d_in[25], *o1b = (const float*)d_in[26];
    const float* o2W = (const float*)d_in[27], *o2b = (const float*)d_in[28];
    float* outp = (float*)d_out;

    char* p = (char*)d_ws;
    auto alloc = [&](size_t bytes) {
        char* r = p;
        p += (bytes + 255) & ~(size_t)255;
        return r;
    };
    float* dinv = (float*)alloc((size_t)N_NODES * 4);
    int* degc   = (int*)alloc((size_t)N_NODES * 4);
    int* offs   = (int*)alloc((size_t)(N_NODES + 1) * 4);
    int* csr    = (int*)alloc((size_t)N_EDGES * 4);
    int* bsums  = (int*)alloc(256 * 4);
    float* g    = (float*)alloc((size_t)B_GRAPH * 256 * 4);
    float* AF   = (float*)alloc((size_t)B_GRAPH * NH * 512 * 4);
    unsigned short* xw1b = (unsigned short*)alloc((size_t)N_NODES * 256 * 2);  // bf16
    float* x1   = (float*)alloc((size_t)N_NODES * 256 * 4);
    float* xw2  = (float*)alloc((size_t)N_NODES * 64 * 4);

    size_t need = (size_t)(p - (char*)d_ws);
    if (need > ws_size) {
        fprintf(stderr, "kernel_launch: ws too small (%zu needed, %zu have)\n", need, ws_size);
        return;
    }

    hipMemsetAsync(degc, 0, (size_t)N_NODES * 4, stream);
    count_deg<<<1600, 256, 0, stream>>>(ei32, ei64, degc);
    scan_block_sums<<<200, 256, 0, stream>>>(degc, bsums);
    scan_finalize<<<200, 256, 0, stream>>>(degc, offs, dinv, bsums);

    // af0 | fill_csr | gemm1 (x@W1, dinv-prescaled, bf16-packed)
    fused_gemm<64, 256, 416, 1600, true><<<416 + 1600 + 3200, 256, 0, stream>>>(
        x, W1, (float*)xw1b, dinv, ei32, ei64, degc, csr,
        x, hidx, a0W, a0b, f0W, f0b, AF);
    // attn reduce 0 | agg (layer 1, bf16 gather)
    fused_agg256<<<256 + 12800, 256, 0, stream>>>((const uint2*)xw1b, dinv, offs, csr,
                                                  b1, x1, AF, g0W, g0b, nullptr, g);
    // af1 | gemm2 (x1@W2, dinv-prescaled, fp32)
    fused_gemm<256, 64, 416, 0, false><<<416 + 800, 256, 0, stream>>>(
        x1, W2, xw2, dinv, ei32, ei64, degc, csr,
        x1, hidx, a1W, a1b, f1W, f1b, AF);
    // per-graph: reduce1 + host-only agg64 + attn2 + g2 update + head
    attn_graph_head<<<256, 256, 0, stream>>>(
        AF, g1W, g1b, g, xw2, dinv, offs, csr, b2, hidx,
        a2W, a2b, f2W, f2b, g2W, g2b, o1W, o1b, o2W, o2b, outp);
}

// Round 13
// 301.180 us; speedup vs baseline: 1.9517x; 1.0757x over previous
//
#include <hip/hip_runtime.h>
#include <math.h>
#include <stdio.h>

#define N_NODES 51200
#define N_EDGES 409600
#define B_GRAPH 256
#define NH 13

typedef float v4f __attribute__((ext_vector_type(4)));
__device__ __forceinline__ void nt_store_f4(float* p, float4 v) {
    v4f w; w.x = v.x; w.y = v.y; w.z = v.z; w.w = v.w;
    __builtin_nontemporal_store(w, (v4f*)p);
}

// bf16 pack (RNE) / unpack helpers: payload-only compression for gathers.
__device__ __forceinline__ unsigned pack_bf2(float a, float b) {
    unsigned ua = __float_as_uint(a);
    ua = (ua + 0x7fffu + ((ua >> 16) & 1u)) >> 16;
    unsigned ub = __float_as_uint(b);
    ub = (ub + 0x7fffu + ((ub >> 16) & 1u)) & 0xffff0000u;
    return ua | ub;
}
__device__ __forceinline__ float bf_lo(unsigned u) { return __uint_as_float(u << 16); }
__device__ __forceinline__ float bf_hi(unsigned u) { return __uint_as_float(u & 0xffff0000u); }

// ei dtype probe, inlined: int64 ei has zero high words (uniform scalar loads).
__device__ __forceinline__ bool ei_is_64(const int* __restrict__ ei32) {
    int z = 1;
    #pragma unroll
    for (int k = 1; k < 16; k += 2) z &= (ei32[k] == 0);
    return z != 0;
}

// degc pre-zeroed by hipMemsetAsync; self-loop handled as deg = count+1.
__global__ void count_deg(const int* __restrict__ ei32, const long long* __restrict__ ei64,
                          int* __restrict__ degc) {
    int e = blockIdx.x * 256 + threadIdx.x;
    if (e >= N_EDGES) return;
    int v = ei_is_64(ei32) ? (int)ei64[N_EDGES + e] : ei32[N_EDGES + e];
    atomicAdd(&degc[v], 1);
}

__global__ void scan_block_sums(const int* __restrict__ degc, int* __restrict__ bsums) {
    __shared__ int sdata[256];
    int i = blockIdx.x * 256 + threadIdx.x;
    sdata[threadIdx.x] = degc[i];
    __syncthreads();
    for (int s = 128; s > 0; s >>= 1) {
        if (threadIdx.x < s) sdata[threadIdx.x] += sdata[threadIdx.x + s];
        __syncthreads();
    }
    if (threadIdx.x == 0) bsums[blockIdx.x] = sdata[0];
}

// finalize with inline scan of the 200 block sums
__global__ void scan_finalize(int* __restrict__ degc, int* __restrict__ offs,
                              float* __restrict__ dinv, const int* __restrict__ bsums) {
    __shared__ int bs[256];
    __shared__ int s[256];
    const int t = threadIdx.x;
    bs[t] = (t < 200) ? bsums[t] : 0;
    __syncthreads();
    for (int off = 1; off < 256; off <<= 1) {
        int u = (t >= off) ? bs[t - off] : 0;
        __syncthreads();
        bs[t] += u;
        __syncthreads();
    }
    int i = blockIdx.x * 256 + t;
    int cnt = degc[i];
    s[t] = cnt;
    __syncthreads();
    for (int off = 1; off < 256; off <<= 1) {
        int u = (t >= off) ? s[t - off] : 0;
        __syncthreads();
        s[t] += u;
        __syncthreads();
    }
    int base = (blockIdx.x == 0) ? 0 : bs[blockIdx.x - 1];
    int excl = base + s[t] - cnt;
    offs[i] = excl;
    dinv[i] = rsqrtf((float)(cnt + 1));
    degc[i] = excl;  // fill cursor
    if (i == N_NODES - 1) offs[N_NODES] = N_EDGES;
}

// ---- shared GEMM tile body: 64x64 out, BK=32, thread tile 4x4 ----
// BF16OUT: Y is a bf16 buffer (element stride YS); caller pre-offsets Y by
// col-block in bf16 elements.
template <int K, int WS, int YS, bool GATHER, bool SCALE, bool BIAS, bool BF16OUT>
__device__ __forceinline__ void gemm_body(const float* __restrict__ X,
        const float* __restrict__ W, const float* __restrict__ bias,
        const float* __restrict__ dinv, float* __restrict__ Y,
        int row0, const int* __restrict__ rows,
        float* __restrict__ xs, float* __restrict__ ws) {
    constexpr int BK = 32;
    constexpr int XS = BK + 4;  // 36
    const int t = threadIdx.x;
    const int ct = t & 15;
    const int rt = t >> 4;
    float acc[4][4] = {{0.f}};
    for (int kc = 0; kc < K; kc += BK) {
        __syncthreads();
        #pragma unroll
        for (int i = 0; i < 2; ++i) {
            int idx = t + i * 256;
            int q = idx & 7, r = idx >> 3;
            int xr = GATHER ? rows[r] : (row0 + r);
            float4 v = *(const float4*)(X + (size_t)xr * K + kc + q * 4);
            *(float4*)&xs[r * XS + q * 4] = v;
        }
        #pragma unroll
        for (int i = 0; i < 2; ++i) {
            int idx = t + i * 256;
            int q = idx & 15, k = idx >> 4;
            float4 v = *(const float4*)(W + (size_t)(kc + k) * WS + q * 4);
            *(float4*)&ws[k * 64 + q * 4] = v;
        }
        __syncthreads();
        #pragma unroll
        for (int kb = 0; kb < BK; kb += 4) {
            float4 wv[4];
            #pragma unroll
            for (int kk = 0; kk < 4; ++kk)
                wv[kk] = *(const float4*)&ws[(kb + kk) * 64 + ct * 4];
            #pragma unroll
            for (int r = 0; r < 4; ++r) {
                float4 xv = *(const float4*)&xs[(rt * 4 + r) * XS + kb];
                acc[r][0] = fmaf(xv.x, wv[0].x, acc[r][0]);
                acc[r][1] = fmaf(xv.x, wv[0].y, acc[r][1]);
                acc[r][2] = fmaf(xv.x, wv[0].z, acc[r][2]);
                acc[r][3] = fmaf(xv.x, wv[0].w, acc[r][3]);
                acc[r][0] = fmaf(xv.y, wv[1].x, acc[r][0]);
                acc[r][1] = fmaf(xv.y, wv[1].y, acc[r][1]);
                acc[r][2] = fmaf(xv.y, wv[1].z, acc[r][2]);
                acc[r][3] = fmaf(xv.y, wv[1].w, acc[r][3]);
                acc[r][0] = fmaf(xv.z, wv[2].x, acc[r][0]);
                acc[r][1] = fmaf(xv.z, wv[2].y, acc[r][1]);
                acc[r][2] = fmaf(xv.z, wv[2].z, acc[r][2]);
                acc[r][3] = fmaf(xv.z, wv[2].w, acc[r][3]);
                acc[r][0] = fmaf(xv.w, wv[3].x, acc[r][0]);
                acc[r][1] = fmaf(xv.w, wv[3].y, acc[r][1]);
                acc[r][2] = fmaf(xv.w, wv[3].z, acc[r][2]);
                acc[r][3] = fmaf(xv.w, wv[3].w, acc[r][3]);
            }
        }
    }
    #pragma unroll
    for (int r = 0; r < 4; ++r) {
        int row = row0 + rt * 4 + r;
        float4 o = make_float4(acc[r][0], acc[r][1], acc[r][2], acc[r][3]);
        if (BIAS) {
            o.x += bias[ct * 4 + 0];
            o.y += bias[ct * 4 + 1];
            o.z += bias[ct * 4 + 2];
            o.w += bias[ct * 4 + 3];
        }
        if (SCALE) {
            float sc = dinv[row];
            o.x *= sc; o.y *= sc; o.z *= sc; o.w *= sc;
        }
        if (BF16OUT) {
            unsigned short* yb = (unsigned short*)Y + (size_t)row * YS;
            uint2 pk;
            pk.x = pack_bf2(o.x, o.y);
            pk.y = pack_bf2(o.z, o.w);
            ((uint2*)yb)[ct] = pk;
        } else {
            *(float4*)&Y[(size_t)row * YS + ct * 4] = o;
        }
    }
}

// ---- fused launch: [0,NA) gemm_af (A|F, H=256), [NA,NA+NF) fill_csr,
//      [NA+NF,...) gemm X@W -> Y (dinv-prescaled). Small segments FIRST. ----
template <int K, int NTOT, int NA_BLK, int NF_BLK, bool BF16Y>
__global__ __launch_bounds__(256) void fused_gemm(const float* __restrict__ X,
        const float* __restrict__ W, float* __restrict__ Y,
        const float* __restrict__ dinv,
        const int* __restrict__ ei32, const long long* __restrict__ ei64,
        int* __restrict__ cursor, int* __restrict__ csr,
        const float* __restrict__ XA, const int* __restrict__ host_idx,
        const float* __restrict__ aW, const float* __restrict__ ab,
        const float* __restrict__ fW, const float* __restrict__ fb,
        float* __restrict__ AF) {
    __shared__ float xs[64 * 36];
    __shared__ float ws[32 * 64];
    __shared__ int rows[64];
    const int bid = blockIdx.x;
    const int t = threadIdx.x;
    if (bid < NA_BLK) {
        const int rb = bid >> 3;        // 8 col-blocks (2*256/64)
        const int cb = bid & 7;
        const int c0 = cb * 64;
        const float* Wp = (c0 < 256) ? (aW + c0) : (fW + (c0 - 256));
        const float* bp = (c0 < 256) ? (ab + c0) : (fb + (c0 - 256));
        if (t < 64) rows[t] = host_idx[rb * 64 + t];
        gemm_body<K, 256, 512, true, false, true, false>(
            XA, Wp, bp, nullptr, AF + c0, rb * 64, rows, xs, ws);
    } else if (bid < NA_BLK + NF_BLK) {
        int e = (bid - NA_BLK) * 256 + t;
        if (e < N_EDGES) {
            int u, v;
            if (ei_is_64(ei32)) { u = (int)ei64[e]; v = (int)ei64[N_EDGES + e]; }
            else                { u = ei32[e];      v = ei32[N_EDGES + e]; }
            int pos = atomicAdd(&cursor[v], 1);
            csr[pos] = u;
        }
    } else {
        const int gbid = bid - NA_BLK - NF_BLK;
        constexpr int nColBlk = NTOT / 64;
        const int rb = gbid / nColBlk;
        const int cb = gbid - rb * nColBlk;
        float* Yp = BF16Y ? (Y + cb * 32) : (Y + cb * 64);
        gemm_body<K, NTOT, NTOT, false, true, false, BF16Y>(
            X, W + cb * 64, nullptr, dinv, Yp, rb * 64, nullptr, xs, ws);
    }
}

// ---- attn reduce body (H=256): softmax over feats + weighted sum + g update ----
__device__ __forceinline__ void attn_red256(const float* __restrict__ AF,
        const float* __restrict__ gW, const float* __restrict__ gb,
        const float* __restrict__ g_in, float* __restrict__ g_out, int b,
        float (*At)[256], float* red_m, float* red_s, float* cat) {
    const int t = threadIdx.x;
    const int wave = t >> 6, lane = t & 63;
    float accA[NH], accF[NH];
    #pragma unroll
    for (int j = 0; j < NH; ++j) {
        const float* r = AF + (size_t)(b * NH + j) * 512;
        accA[j] = r[t];
        accF[j] = r[256 + t];
        At[j][t] = accA[j];
    }
    __syncthreads();
    for (int j = wave; j < NH; j += 4) {
        float m = -3.402823466e38f;
        #pragma unroll
        for (int q = 0; q < 4; ++q) m = fmaxf(m, At[j][q * 64 + lane]);
        #pragma unroll
        for (int off = 32; off; off >>= 1) m = fmaxf(m, __shfl_xor(m, off));
        if (lane == 0) red_m[j] = m;
    }
    __syncthreads();
    #pragma unroll
    for (int j = 0; j < NH; ++j) At[j][t] = expf(accA[j] - red_m[j]);
    __syncthreads();
    for (int j = wave; j < NH; j += 4) {
        float s = 0.f;
        #pragma unroll
        for (int q = 0; q < 4; ++q) s += At[j][q * 64 + lane];
        #pragma unroll
        for (int off = 32; off; off >>= 1) s += __shfl_xor(s, off);
        if (lane == 0) red_s[j] = s;
    }
    __syncthreads();
    float outc = 0.f;
    #pragma unroll
    for (int j = 0; j < NH; ++j) outc += At[j][t] / red_s[j] * accF[j];
    cat[t] = outc;
    float gv = g_in ? g_in[b * 256 + t] : 0.f;
    cat[256 + t] = gv;
    __syncthreads();
    float acc = gb[t];
    const float* gwp = gW + t;
    #pragma unroll 4
    for (int i4 = 0; i4 < 128; ++i4) {
        float4 cq = ((const float4*)cat)[i4];
        const float* gw4 = gwp + (size_t)i4 * 4 * 256;
        acc = fmaf(cq.x, gw4[0], acc);
        acc = fmaf(cq.y, gw4[256], acc);
        acc = fmaf(cq.z, gw4[512], acc);
        acc = fmaf(cq.w, gw4[768], acc);
    }
    g_out[b * 256 + t] = gv + acc;
}

// ---- fused: [0,256) attn reduce 0 (first: hides under the agg wall),
//      [256,13056) agg_max over bf16 rows, OUTPUT fp32 x1 ----
__global__ __launch_bounds__(256) void fused_agg256(const uint2* __restrict__ xwb,
        const float* __restrict__ dinv, const int* __restrict__ offs,
        const int* __restrict__ csr, const float* __restrict__ bias,
        float* __restrict__ out,
        const float* __restrict__ AF, const float* __restrict__ gW,
        const float* __restrict__ gb, const float* __restrict__ g_in,
        float* __restrict__ g_out) {
    __shared__ float At[NH][256];
    __shared__ float red_m[NH];
    __shared__ float red_s[NH];
    __shared__ float cat[512];
    const int bid = blockIdx.x;
    if (bid < 256) {
        attn_red256(AF, gW, gb, g_in, g_out, bid, At, red_m, red_s, cat);
        return;
    }
    int gid = (bid - 256) * 256 + threadIdx.x;
    int v = gid >> 6;
    int lane = gid & 63;
    uint2 sw = xwb[(size_t)v * 64 + lane];  // self (pre-scaled bf16 row)
    float4 acc = make_float4(bf_lo(sw.x), bf_hi(sw.x), bf_lo(sw.y), bf_hi(sw.y));
    int e0 = offs[v];
    int e1 = offs[v + 1];
    int em = e0 + ((e1 - e0) & ~7);
    for (int e = e0; e < em; e += 8) {
        int u[8];
        #pragma unroll
        for (int i = 0; i < 8; ++i) u[i] = csr[e + i];
        uint2 m[8];
        #pragma unroll
        for (int i = 0; i < 8; ++i) m[i] = xwb[(size_t)u[i] * 64 + lane];
        #pragma unroll
        for (int i = 0; i < 8; ++i) {
            acc.x = fmaxf(acc.x, bf_lo(m[i].x));
            acc.y = fmaxf(acc.y, bf_hi(m[i].x));
            acc.z = fmaxf(acc.z, bf_lo(m[i].y));
            acc.w = fmaxf(acc.w, bf_hi(m[i].y));
        }
    }
    if (em < e1) {
        int u[8];
        #pragma unroll
        for (int i = 0; i < 8; ++i) u[i] = csr[(em + i < e1) ? (em + i) : (e1 - 1)];
        uint2 m[8];
        #pragma unroll
        for (int i = 0; i < 8; ++i) m[i] = xwb[(size_t)u[i] * 64 + lane];
        #pragma unroll
        for (int i = 0; i < 8; ++i) {
            if (em + i < e1) {
                acc.x = fmaxf(acc.x, bf_lo(m[i].x));
                acc.y = fmaxf(acc.y, bf_hi(m[i].x));
                acc.z = fmaxf(acc.z, bf_lo(m[i].y));
                acc.w = fmaxf(acc.w, bf_hi(m[i].y));
            }
        }
    }
    float dv = dinv[v];
    float4 b4 = ((const float4*)bias)[lane];
    float4 o;
    o.x = fmaxf(fmaf(acc.x, dv, b4.x), 0.f);
    o.y = fmaxf(fmaf(acc.y, dv, b4.y), 0.f);
    o.z = fmaxf(fmaf(acc.z, dv, b4.z), 0.f);
    o.w = fmaxf(fmaf(acc.w, dv, b4.w), 0.f);
    nt_store_f4(out + (size_t)v * 256 + lane * 4, o);
}

// ---- per-graph mega-kernel, 1024 threads (16 waves): layer-1 attn reduce +
//      host-only layer-2 GCN agg + layer-2 attention + g2 update + head. ----
__global__ __launch_bounds__(1024) void attn_graph_head(
        const float* __restrict__ AF,   // layer-1 A|F (3328 x 512)
        const float* __restrict__ g1W, const float* __restrict__ g1b,
        const float* __restrict__ g_in, // g after reduce0
        const float* __restrict__ xw2,  // prescaled x1@W2 (51200 x 64, fp32)
        const float* __restrict__ dinv, const int* __restrict__ offs,
        const int* __restrict__ csr, const float* __restrict__ b2,
        const int* __restrict__ host_idx,
        const float* __restrict__ a2W, const float* __restrict__ a2b,
        const float* __restrict__ f2W, const float* __restrict__ f2b,
        const float* __restrict__ g2W, const float* __restrict__ g2b,
        const float* __restrict__ o1W, const float* __restrict__ o1b,
        const float* __restrict__ o2W, const float* __restrict__ o2b,
        float* __restrict__ out) {
    __shared__ float At[NH][256];
    __shared__ float Ft[NH][256];
    __shared__ float red_m[NH];
    __shared__ float red_s[NH];
    __shared__ float cat[512];      // [0,256)=attn1 out, [256,512)=g_in
    __shared__ float catB[320];     // [0,64)=attn2 out, [64,320)=g1s
    __shared__ float g1s[256];
    __shared__ float x2l[NH][64];
    __shared__ float part4[4][256];
    __shared__ float part16[16][64];
    __shared__ float grow[256];
    const int b = blockIdx.x;
    const int t = threadIdx.x;       // 0..1023
    const int wave = t >> 6;         // 0..15
    const int lane = t & 63;
    const int c = t & 255;
    const int quad = t >> 8;         // 0..3

    // ---- phase 2 FIRST (waves 0..12; no barrier): long-latency host gathers
    //      issue early and drain while other phases compute ----
    if (wave < NH) {
        int hv = host_idx[b * NH + wave];
        float acc = xw2[(size_t)hv * 64 + lane];  // self (pre-scaled row)
        int e0 = offs[hv], e1 = offs[hv + 1];
        for (int e = e0; e < e1; e += 8) {
            int u[8];
            #pragma unroll
            for (int i = 0; i < 8; ++i) u[i] = csr[(e + i < e1) ? (e + i) : (e1 - 1)];
            float m[8];
            #pragma unroll
            for (int i = 0; i < 8; ++i) m[i] = xw2[(size_t)u[i] * 64 + lane];
            #pragma unroll
            for (int i = 0; i < 8; ++i)
                if (e + i < e1) acc = fmaxf(acc, m[i]);
        }
        x2l[wave][lane] = fmaxf(fmaf(acc, dinv[hv], b2[lane]), 0.f);
    }
    // ---- phase 1a: cooperative AF load into At/Ft ----
    for (int idx = t; idx < NH * 128; idx += 1024) {
        int j = idx >> 7, q = idx & 127;
        float4 v = ((const float4*)(AF + (size_t)(b * NH + j) * 512))[q];
        if (q < 64) *(float4*)&At[j][q * 4] = v;
        else        *(float4*)&Ft[j][(q - 64) * 4] = v;
    }
    __syncthreads();
    // ---- phase 1b: row max (wave j reduces row j) ----
    if (wave < NH) {
        float m = -3.402823466e38f;
        #pragma unroll
        for (int q = 0; q < 4; ++q) m = fmaxf(m, At[wave][q * 64 + lane]);
        #pragma unroll
        for (int off = 32; off; off >>= 1) m = fmaxf(m, __shfl_xor(m, off));
        if (lane == 0) red_m[wave] = m;
    }
    __syncthreads();
    // ---- phase 1c: exp in place (all 1024 threads) ----
    for (int idx = t; idx < NH * 256; idx += 1024) {
        int j = idx >> 8, cc = idx & 255;
        At[j][cc] = expf(At[j][cc] - red_m[j]);
    }
    __syncthreads();
    // ---- phase 1d: row sum ----
    if (wave < NH) {
        float s = 0.f;
        #pragma unroll
        for (int q = 0; q < 4; ++q) s += At[wave][q * 64 + lane];
        #pragma unroll
        for (int off = 32; off; off >>= 1) s += __shfl_xor(s, off);
        if (lane == 0) red_s[wave] = s;
    }
    __syncthreads();
    // ---- phase 1e: weighted sum + g_in into cat ----
    if (quad == 0) {
        float outc = 0.f;
        #pragma unroll
        for (int j = 0; j < NH; ++j) outc += At[j][c] / red_s[j] * Ft[j][c];
        cat[c] = outc;
        cat[256 + c] = g_in[b * 256 + c];
    }
    __syncthreads();
    // ---- phase 1f: g1W update, k-split over quads (512 floats = 128 float4,
    //      32 float4 per quad — round-12 bug was 20/quad, dropping k in [320,512)) ----
    {
        float acc = 0.f;
        const float* gwp = g1W + c;
        #pragma unroll 4
        for (int i4 = quad * 32; i4 < quad * 32 + 32; ++i4) {
            float4 cq = ((const float4*)cat)[i4];
            const float* gw4 = gwp + (size_t)i4 * 1024;
            acc = fmaf(cq.x, gw4[0], acc);
            acc = fmaf(cq.y, gw4[256], acc);
            acc = fmaf(cq.z, gw4[512], acc);
            acc = fmaf(cq.w, gw4[768], acc);
        }
        part4[quad][c] = acc;
    }
    __syncthreads();
    if (quad == 0)
        g1s[c] = cat[256 + c] + g1b[c] +
                 part4[0][c] + part4[1][c] + part4[2][c] + part4[3][c];
    __syncthreads();
    // ---- phase 3a: layer-2 attention matmul + row softmax (wave j = row j) ----
    if (wave < NH) {
        float aA = a2b[lane], aF = f2b[lane];
        #pragma unroll 8
        for (int k = 0; k < 64; ++k) {
            float xv = x2l[wave][k];
            aA = fmaf(xv, a2W[k * 64 + lane], aA);
            aF = fmaf(xv, f2W[k * 64 + lane], aF);
        }
        float m = aA;
        #pragma unroll
        for (int off = 32; off; off >>= 1) m = fmaxf(m, __shfl_xor(m, off));
        float pexp = expf(aA - m);
        float s = pexp;
        #pragma unroll
        for (int off = 32; off; off >>= 1) s += __shfl_xor(s, off);
        At[wave][lane] = pexp / s * aF;  // per-row contribution
    }
    __syncthreads();
    // ---- phase 3b: catB = [sum_j contrib | g1s] ----
    if (t < 64) {
        float o = 0.f;
        #pragma unroll
        for (int j = 0; j < NH; ++j) o += At[j][t];
        catB[t] = o;
    }
    if (quad == 0) catB[64 + c] = g1s[c];
    __syncthreads();
    // ---- phase 4: g2W update, k-split over quads (320 floats = 80 float4) ----
    {
        float acc = 0.f;
        const float* gwp = g2W + c;
        #pragma unroll 4
        for (int i4 = quad * 20; i4 < quad * 20 + 20; ++i4) {
            float4 cq = ((const float4*)catB)[i4];
            const float* gw4 = gwp + (size_t)i4 * 1024;
            acc = fmaf(cq.x, gw4[0], acc);
            acc = fmaf(cq.y, gw4[256], acc);
            acc = fmaf(cq.z, gw4[512], acc);
            acc = fmaf(cq.w, gw4[768], acc);
        }
        part4[quad][c] = acc;
    }
    __syncthreads();
    if (quad == 0)
        grow[c] = g1s[c] + g2b[c] +
                  part4[0][c] + part4[1][c] + part4[2][c] + part4[3][c];
    __syncthreads();
    // ---- phase 5: head, o1 k-split over 16 waves (16 k each) ----
    {
        float hp = 0.f;
        #pragma unroll
        for (int k = wave * 16; k < wave * 16 + 16; ++k)
            hp = fmaf(grow[k], o1W[(size_t)k * 64 + lane], hp);
        part16[wave][lane] = hp;
    }
    __syncthreads();
    if (wave == 0) {
        float h = o1b[lane];
        #pragma unroll
        for (int w = 0; w < 16; ++w) h += part16[w][lane];
        h = fmaxf(h, 0.f);
        float sres = h * o2W[lane];
        #pragma unroll
        for (int off = 32; off; off >>= 1) sres += __shfl_xor(sres, off);
        if (lane == 0) out[b] = sres + o2b[0];
    }
}

extern "C" void kernel_launch(void* const* d_in, const int* in_sizes, int n_in,
                              void* d_out, int out_size, void* d_ws, size_t ws_size,
                              hipStream_t stream) {
    (void)in_sizes; (void)n_in; (void)out_size;
    const float* x    = (const float*)d_in[0];
    const int* ei32   = (const int*)d_in[1];
    const long long* ei64 = (const long long*)d_in[1];
    const int* hidx   = (const int*)d_in[2];
    const float* W1 = (const float*)d_in[3],  *b1 = (const float*)d_in[4];
    const float* W2 = (const float*)d_in[5],  *b2 = (const float*)d_in[6];
    const float* a0W = (const float*)d_in[7],  *a0b = (const float*)d_in[8];
    const float* f0W = (const float*)d_in[9],  *f0b = (const float*)d_in[10];
    const float* g0W = (const float*)d_in[11], *g0b = (const float*)d_in[12];
    const float* a1W = (const float*)d_in[13], *a1b = (const float*)d_in[14];
    const float* f1W = (const float*)d_in[15], *f1b = (const float*)d_in[16];
    const float* g1W = (const float*)d_in[17], *g1b = (const float*)d_in[18];
    const float* a2W = (const float*)d_in[19], *a2b = (const float*)d_in[20];
    const float* f2W = (const float*)d_in[21], *f2b = (const float*)d_in[22];
    const float* g2W = (const float*)d_in[23], *g2b = (const float*)d_in[24];
    const float* o1W = (const float*)d_in[25], *o1b = (const float*)d_in[26];
    const float* o2W = (const float*)d_in[27], *o2b = (const float*)d_in[28];
    float* outp = (float*)d_out;

    char* p = (char*)d_ws;
    auto alloc = [&](size_t bytes) {
        char* r = p;
        p += (bytes + 255) & ~(size_t)255;
        return r;
    };
    float* dinv = (float*)alloc((size_t)N_NODES * 4);
    int* degc   = (int*)alloc((size_t)N_NODES * 4);
    int* offs   = (int*)alloc((size_t)(N_NODES + 1) * 4);
    int* csr    = (int*)alloc((size_t)N_EDGES * 4);
    int* bsums  = (int*)alloc(256 * 4);
    float* g    = (float*)alloc((size_t)B_GRAPH * 256 * 4);
    float* AF   = (float*)alloc((size_t)B_GRAPH * NH * 512 * 4);
    unsigned short* xw1b = (unsigned short*)alloc((size_t)N_NODES * 256 * 2);  // bf16
    float* x1   = (float*)alloc((size_t)N_NODES * 256 * 4);
    float* xw2  = (float*)alloc((size_t)N_NODES * 64 * 4);

    size_t need = (size_t)(p - (char*)d_ws);
    if (need > ws_size) {
        fprintf(stderr, "kernel_launch: ws too small (%zu needed, %zu have)\n", need, ws_size);
        return;
    }

    (void)hipMemsetAsync(degc, 0, (size_t)N_NODES * 4, stream);
    count_deg<<<1600, 256, 0, stream>>>(ei32, ei64, degc);
    scan_block_sums<<<200, 256, 0, stream>>>(degc, bsums);
    scan_finalize<<<200, 256, 0, stream>>>(degc, offs, dinv, bsums);

    // af0 | fill_csr | gemm1 (x@W1, dinv-prescaled, bf16-packed)
    fused_gemm<64, 256, 416, 1600, true><<<416 + 1600 + 3200, 256, 0, stream>>>(
        x, W1, (float*)xw1b, dinv, ei32, ei64, degc, csr,
        x, hidx, a0W, a0b, f0W, f0b, AF);
    // attn reduce 0 | agg (layer 1, bf16 gather, fp32 output)
    fused_agg256<<<256 + 12800, 256, 0, stream>>>((const uint2*)xw1b, dinv, offs, csr,
                                                  b1, x1, AF, g0W, g0b, nullptr, g);
    // af1 | gemm2 (x1@W2, fp32 input, dinv-prescaled fp32 output)
    fused_gemm<256, 64, 416, 0, false><<<416 + 800, 256, 0, stream>>>(
        x1, W2, xw2, dinv, ei32, ei64, degc, csr,
        x1, hidx, a1W, a1b, f1W, f1b, AF);
    // per-graph (1024 thr): reduce1 + host-only agg + attn2 + g2 update + head
    attn_graph_head<<<256, 1024, 0, stream>>>(
        AF, g1W, g1b, g, xw2, dinv, offs, csr, b2, hidx,
        a2W, a2b, f2W, f2b, g2W, g2b, o1W, o1b, o2W, o2b, outp);
}

// Round 14
// 297.279 us; speedup vs baseline: 1.9774x; 1.0131x over previous
//
#include <hip/hip_runtime.h>
#include <math.h>
#include <stdio.h>

#define N_NODES 51200
#define N_EDGES 409600
#define B_GRAPH 256
#define NH 13

typedef float v4f __attribute__((ext_vector_type(4)));
typedef unsigned v2u __attribute__((ext_vector_type(2)));
__device__ __forceinline__ void nt_store_u2(uint2* p, uint2 v) {
    v2u w; w.x = v.x; w.y = v.y;
    __builtin_nontemporal_store(w, (v2u*)p);
}

// bf16 pack (RNE) / unpack helpers: payload-only compression for gathers.
__device__ __forceinline__ unsigned pack_bf2(float a, float b) {
    unsigned ua = __float_as_uint(a);
    ua = (ua + 0x7fffu + ((ua >> 16) & 1u)) >> 16;
    unsigned ub = __float_as_uint(b);
    ub = (ub + 0x7fffu + ((ub >> 16) & 1u)) & 0xffff0000u;
    return ua | ub;
}
__device__ __forceinline__ float bf_lo(unsigned u) { return __uint_as_float(u << 16); }
__device__ __forceinline__ float bf_hi(unsigned u) { return __uint_as_float(u & 0xffff0000u); }

// ei dtype probe, inlined: int64 ei has zero high words (uniform scalar loads).
__device__ __forceinline__ bool ei_is_64(const int* __restrict__ ei32) {
    int z = 1;
    #pragma unroll
    for (int k = 1; k < 16; k += 2) z &= (ei32[k] == 0);
    return z != 0;
}

__global__ void count_deg(const int* __restrict__ ei32, const long long* __restrict__ ei64,
                          int* __restrict__ degc) {
    int e = blockIdx.x * 256 + threadIdx.x;
    if (e >= N_EDGES) return;
    int v = ei_is_64(ei32) ? (int)ei64[N_EDGES + e] : ei32[N_EDGES + e];
    atomicAdd(&degc[v], 1);
}

__global__ void scan_block_sums(const int* __restrict__ degc, int* __restrict__ bsums) {
    __shared__ int sdata[256];
    int i = blockIdx.x * 256 + threadIdx.x;
    sdata[threadIdx.x] = degc[i];
    __syncthreads();
    for (int s = 128; s > 0; s >>= 1) {
        if (threadIdx.x < s) sdata[threadIdx.x] += sdata[threadIdx.x + s];
        __syncthreads();
    }
    if (threadIdx.x == 0) bsums[blockIdx.x] = sdata[0];
}

__global__ void scan_finalize(int* __restrict__ degc, int* __restrict__ offs,
                              float* __restrict__ dinv, const int* __restrict__ bsums) {
    __shared__ int bs[256];
    __shared__ int s[256];
    const int t = threadIdx.x;
    bs[t] = (t < 200) ? bsums[t] : 0;
    __syncthreads();
    for (int off = 1; off < 256; off <<= 1) {
        int u = (t >= off) ? bs[t - off] : 0;
        __syncthreads();
        bs[t] += u;
        __syncthreads();
    }
    int i = blockIdx.x * 256 + t;
    int cnt = degc[i];
    s[t] = cnt;
    __syncthreads();
    for (int off = 1; off < 256; off <<= 1) {
        int u = (t >= off) ? s[t - off] : 0;
        __syncthreads();
        s[t] += u;
        __syncthreads();
    }
    int base = (blockIdx.x == 0) ? 0 : bs[blockIdx.x - 1];
    int excl = base + s[t] - cnt;
    offs[i] = excl;
    dinv[i] = rsqrtf((float)(cnt + 1));
    degc[i] = excl;  // fill cursor
    if (i == N_NODES - 1) offs[N_NODES] = N_EDGES;
}

// ---- 64x64 tile body (af path): gather + bias, fp32 out, 4x4/thread ----
template <int K, int WS, bool BF16IN>
__device__ __forceinline__ void gemm_body64(const float* __restrict__ X,
        const float* __restrict__ W, const float* __restrict__ bias,
        float* __restrict__ Y, int row0, const int* __restrict__ rows,
        float* __restrict__ xs, float* __restrict__ ws) {
    constexpr int BK = 32;
    constexpr int XS = BK + 4;
    const int t = threadIdx.x;
    const int ct = t & 15;
    const int rt = t >> 4;
    float acc[4][4] = {{0.f}};
    for (int kc = 0; kc < K; kc += BK) {
        __syncthreads();
        #pragma unroll
        for (int i = 0; i < 2; ++i) {
            int idx = t + i * 256;
            int q = idx & 7, r = idx >> 3;
            int xr = rows[r];
            float4 v;
            if (BF16IN) {
                uint2 pv = ((const uint2*)X)[(size_t)xr * (K / 4) + kc / 4 + q];
                v = make_float4(bf_lo(pv.x), bf_hi(pv.x), bf_lo(pv.y), bf_hi(pv.y));
            } else {
                v = *(const float4*)(X + (size_t)xr * K + kc + q * 4);
            }
            *(float4*)&xs[r * XS + q * 4] = v;
        }
        #pragma unroll
        for (int i = 0; i < 2; ++i) {
            int idx = t + i * 256;
            int q = idx & 15, k = idx >> 4;
            float4 v = *(const float4*)(W + (size_t)(kc + k) * WS + q * 4);
            *(float4*)&ws[k * 64 + q * 4] = v;
        }
        __syncthreads();
        #pragma unroll
        for (int kb = 0; kb < BK; kb += 4) {
            float4 wv[4];
            #pragma unroll
            for (int kk = 0; kk < 4; ++kk)
                wv[kk] = *(const float4*)&ws[(kb + kk) * 64 + ct * 4];
            #pragma unroll
            for (int r = 0; r < 4; ++r) {
                float4 xv = *(const float4*)&xs[(rt * 4 + r) * XS + kb];
                float xk[4] = {xv.x, xv.y, xv.z, xv.w};
                #pragma unroll
                for (int kk = 0; kk < 4; ++kk) {
                    acc[r][0] = fmaf(xk[kk], wv[kk].x, acc[r][0]);
                    acc[r][1] = fmaf(xk[kk], wv[kk].y, acc[r][1]);
                    acc[r][2] = fmaf(xk[kk], wv[kk].z, acc[r][2]);
                    acc[r][3] = fmaf(xk[kk], wv[kk].w, acc[r][3]);
                }
            }
        }
    }
    #pragma unroll
    for (int r = 0; r < 4; ++r) {
        int row = row0 + rt * 4 + r;
        float4 o = make_float4(acc[r][0] + bias[ct * 4 + 0],
                               acc[r][1] + bias[ct * 4 + 1],
                               acc[r][2] + bias[ct * 4 + 2],
                               acc[r][3] + bias[ct * 4 + 3]);
        *(float4*)&Y[(size_t)row * 512 + ct * 4] = o;
    }
}

// ---- main GEMM body: 128-row block, CPT cols/thread (8 rows/thread),
//      dinv prescale, optional bf16 in/out. LDS bytes/fma: 8x8 -> 1.0,
//      8x4 -> 1.5 (vs 2.0 for 4x4 — round-13 LDS-BW analysis). ----
template <int K, int WS, int YS, int NCOLB, int CPT, bool BF16IN, bool BF16OUT>
__device__ __forceinline__ void gemm_main(const float* __restrict__ X,
        const float* __restrict__ W, const float* __restrict__ dinv,
        float* __restrict__ Y, int row0,
        float* __restrict__ xs, float* __restrict__ ws) {
    constexpr int BK = 32;
    constexpr int XS = BK + 4;
    constexpr int CQ = CPT / 4;
    const int t = threadIdx.x;
    const int ct = t & 15;          // col group (CPT cols)
    const int rt = t >> 4;          // row group (8 rows)
    float acc[8][CPT];
    #pragma unroll
    for (int r = 0; r < 8; ++r)
        #pragma unroll
        for (int c = 0; c < CPT; ++c) acc[r][c] = 0.f;
    for (int kc = 0; kc < K; kc += BK) {
        __syncthreads();
        // stage x: 128 rows x 32 k = 1024 (float4|uint2), 4/thread
        #pragma unroll
        for (int i = 0; i < 4; ++i) {
            int idx = t + i * 256;
            int q = idx & 7, r = idx >> 3;
            float4 v;
            if (BF16IN) {
                uint2 pv = ((const uint2*)X)[(size_t)(row0 + r) * (K / 4) + kc / 4 + q];
                v = make_float4(bf_lo(pv.x), bf_hi(pv.x), bf_lo(pv.y), bf_hi(pv.y));
            } else {
                v = *(const float4*)(X + (size_t)(row0 + r) * K + kc + q * 4);
            }
            *(float4*)&xs[r * XS + q * 4] = v;
        }
        // stage w: 32 k x NCOLB floats, NCOLB/32 float4 per thread
        #pragma unroll
        for (int i = 0; i < NCOLB / 32; ++i) {
            int idx = t + i * 256;
            int q = idx & (NCOLB / 4 - 1), k = idx / (NCOLB / 4);
            float4 v = *(const float4*)(W + (size_t)(kc + k) * WS + q * 4);
            *(float4*)&ws[k * NCOLB + q * 4] = v;
        }
        __syncthreads();
        #pragma unroll
        for (int kb = 0; kb < BK; kb += 4) {
            float4 wv[4][CQ];
            #pragma unroll
            for (int kk = 0; kk < 4; ++kk)
                #pragma unroll
                for (int cq = 0; cq < CQ; ++cq)
                    wv[kk][cq] = *(const float4*)&ws[(kb + kk) * NCOLB + ct * CPT + cq * 4];
            #pragma unroll
            for (int r = 0; r < 8; ++r) {
                float4 xv = *(const float4*)&xs[(rt * 8 + r) * XS + kb];
                float xk[4] = {xv.x, xv.y, xv.z, xv.w};
                #pragma unroll
                for (int kk = 0; kk < 4; ++kk)
                    #pragma unroll
                    for (int cq = 0; cq < CQ; ++cq) {
                        acc[r][cq * 4 + 0] = fmaf(xk[kk], wv[kk][cq].x, acc[r][cq * 4 + 0]);
                        acc[r][cq * 4 + 1] = fmaf(xk[kk], wv[kk][cq].y, acc[r][cq * 4 + 1]);
                        acc[r][cq * 4 + 2] = fmaf(xk[kk], wv[kk][cq].z, acc[r][cq * 4 + 2]);
                        acc[r][cq * 4 + 3] = fmaf(xk[kk], wv[kk][cq].w, acc[r][cq * 4 + 3]);
                    }
            }
        }
    }
    #pragma unroll
    for (int r = 0; r < 8; ++r) {
        int row = row0 + rt * 8 + r;
        float sc = dinv[row];
        #pragma unroll
        for (int cq = 0; cq < CQ; ++cq) {
            float4 o = make_float4(acc[r][cq * 4 + 0] * sc, acc[r][cq * 4 + 1] * sc,
                                   acc[r][cq * 4 + 2] * sc, acc[r][cq * 4 + 3] * sc);
            if (BF16OUT) {
                unsigned short* yb = (unsigned short*)Y + (size_t)row * YS;
                uint2 pk;
                pk.x = pack_bf2(o.x, o.y);
                pk.y = pack_bf2(o.z, o.w);
                ((uint2*)yb)[ct * CQ + cq] = pk;
            } else {
                *(float4*)&Y[(size_t)row * YS + ct * CPT + cq * 4] = o;
            }
        }
    }
}

// ---- fused 1: [0,416) af0 | [416,2016) fill_csr | [2016,2816) gemm1
//      (x@W1 -> bf16 xw1b, 128x128 tile, 8x8/thread) ----
__global__ __launch_bounds__(256) void fused_gemm1(const float* __restrict__ x,
        const float* __restrict__ W1, float* __restrict__ xw1b,
        const float* __restrict__ dinv,
        const int* __restrict__ ei32, const long long* __restrict__ ei64,
        int* __restrict__ cursor, int* __restrict__ csr,
        const int* __restrict__ host_idx,
        const float* __restrict__ a0W, const float* __restrict__ a0b,
        const float* __restrict__ f0W, const float* __restrict__ f0b,
        float* __restrict__ AF) {
    __shared__ float xs[128 * 36];
    __shared__ float ws[32 * 128];
    __shared__ int rows[64];
    const int bid = blockIdx.x;
    const int t = threadIdx.x;
    if (bid < 416) {
        const int rb = bid >> 3;
        const int cb = bid & 7;
        const int c0 = cb * 64;
        const float* Wp = (c0 < 256) ? (a0W + c0) : (f0W + (c0 - 256));
        const float* bp = (c0 < 256) ? (a0b + c0) : (f0b + (c0 - 256));
        if (t < 64) rows[t] = host_idx[rb * 64 + t];
        __syncthreads();
        gemm_body64<64, 256, false>(x, Wp, bp, AF + c0, rb * 64, rows, xs, ws);
    } else if (bid < 2016) {
        int e = (bid - 416) * 256 + t;
        if (e < N_EDGES) {
            int u, v;
            if (ei_is_64(ei32)) { u = (int)ei64[e]; v = (int)ei64[N_EDGES + e]; }
            else                { u = ei32[e];      v = ei32[N_EDGES + e]; }
            int pos = atomicAdd(&cursor[v], 1);
            csr[pos] = u;
        }
    } else {
        const int gbid = bid - 2016;
        const int rb = gbid >> 1;
        const int cb = gbid & 1;
        // bf16 Y: col-block 128 bf16 elements = 64 floats
        gemm_main<64, 256, 256, 128, 8, false, true>(
            x, W1 + cb * 128, dinv, xw1b + cb * 64, rb * 128, xs, ws);
    }
}

// ---- fused 2: [0,416) af1 (bf16 x1 in) | [416,816) gemm2
//      (x1b@W2 -> fp32 xw2, 128x64 tile, 8x4/thread) ----
__global__ __launch_bounds__(256) void fused_gemm2(const float* __restrict__ x1b,
        const float* __restrict__ W2, float* __restrict__ xw2,
        const float* __restrict__ dinv,
        const int* __restrict__ host_idx,
        const float* __restrict__ a1W, const float* __restrict__ a1b,
        const float* __restrict__ f1W, const float* __restrict__ f1b,
        float* __restrict__ AF) {
    __shared__ float xs[128 * 36];
    __shared__ float ws[32 * 64];
    __shared__ int rows[64];
    const int bid = blockIdx.x;
    const int t = threadIdx.x;
    if (bid < 416) {
        const int rb = bid >> 3;
        const int cb = bid & 7;
        const int c0 = cb * 64;
        const float* Wp = (c0 < 256) ? (a1W + c0) : (f1W + (c0 - 256));
        const float* bp = (c0 < 256) ? (a1b + c0) : (f1b + (c0 - 256));
        if (t < 64) rows[t] = host_idx[rb * 64 + t];
        __syncthreads();
        gemm_body64<256, 256, true>(x1b, Wp, bp, AF + c0, rb * 64, rows, xs, ws);
    } else {
        const int gbid = bid - 416;
        gemm_main<256, 64, 64, 64, 4, true, false>(
            x1b, W2, dinv, xw2, gbid * 128, xs, ws);
    }
}

// ---- attn reduce body (H=256): softmax over feats + weighted sum + g update ----
__device__ __forceinline__ void attn_red256(const float* __restrict__ AF,
        const float* __restrict__ gW, const float* __restrict__ gb,
        const float* __restrict__ g_in, float* __restrict__ g_out, int b,
        float (*At)[256], float* red_m, float* red_s, float* cat) {
    const int t = threadIdx.x;
    const int wave = t >> 6, lane = t & 63;
    float accA[NH], accF[NH];
    #pragma unroll
    for (int j = 0; j < NH; ++j) {
        const float* r = AF + (size_t)(b * NH + j) * 512;
        accA[j] = r[t];
        accF[j] = r[256 + t];
        At[j][t] = accA[j];
    }
    __syncthreads();
    for (int j = wave; j < NH; j += 4) {
        float m = -3.402823466e38f;
        #pragma unroll
        for (int q = 0; q < 4; ++q) m = fmaxf(m, At[j][q * 64 + lane]);
        #pragma unroll
        for (int off = 32; off; off >>= 1) m = fmaxf(m, __shfl_xor(m, off));
        if (lane == 0) red_m[j] = m;
    }
    __syncthreads();
    #pragma unroll
    for (int j = 0; j < NH; ++j) At[j][t] = expf(accA[j] - red_m[j]);
    __syncthreads();
    for (int j = wave; j < NH; j += 4) {
        float s = 0.f;
        #pragma unroll
        for (int q = 0; q < 4; ++q) s += At[j][q * 64 + lane];
        #pragma unroll
        for (int off = 32; off; off >>= 1) s += __shfl_xor(s, off);
        if (lane == 0) red_s[j] = s;
    }
    __syncthreads();
    float outc = 0.f;
    #pragma unroll
    for (int j = 0; j < NH; ++j) outc += At[j][t] / red_s[j] * accF[j];
    cat[t] = outc;
    float gv = g_in ? g_in[b * 256 + t] : 0.f;
    cat[256 + t] = gv;
    __syncthreads();
    float acc = gb[t];
    const float* gwp = gW + t;
    #pragma unroll 4
    for (int i4 = 0; i4 < 128; ++i4) {
        float4 cq = ((const float4*)cat)[i4];
        const float* gw4 = gwp + (size_t)i4 * 4 * 256;
        acc = fmaf(cq.x, gw4[0], acc);
        acc = fmaf(cq.y, gw4[256], acc);
        acc = fmaf(cq.z, gw4[512], acc);
        acc = fmaf(cq.w, gw4[768], acc);
    }
    g_out[b * 256 + t] = gv + acc;
}

// ---- fused: [0,256) attn reduce 0 (first), [256,13056) agg_max over bf16
//      rows, OUTPUT bf16 x1b (round-13 evidence: x1-bf16 adds no error) ----
__global__ __launch_bounds__(256) void fused_agg256(const uint2* __restrict__ xwb,
        const float* __restrict__ dinv, const int* __restrict__ offs,
        const int* __restrict__ csr, const float* __restrict__ bias,
        uint2* __restrict__ outb,
        const float* __restrict__ AF, const float* __restrict__ gW,
        const float* __restrict__ gb, const float* __restrict__ g_in,
        float* __restrict__ g_out) {
    __shared__ float At[NH][256];
    __shared__ float red_m[NH];
    __shared__ float red_s[NH];
    __shared__ float cat[512];
    const int bid = blockIdx.x;
    if (bid < 256) {
        attn_red256(AF, gW, gb, g_in, g_out, bid, At, red_m, red_s, cat);
        return;
    }
    int gid = (bid - 256) * 256 + threadIdx.x;
    int v = gid >> 6;
    int lane = gid & 63;
    uint2 sw = xwb[(size_t)v * 64 + lane];  // self (pre-scaled bf16 row)
    float4 acc = make_float4(bf_lo(sw.x), bf_hi(sw.x), bf_lo(sw.y), bf_hi(sw.y));
    int e0 = offs[v];
    int e1 = offs[v + 1];
    int em = e0 + ((e1 - e0) & ~7);
    for (int e = e0; e < em; e += 8) {
        int u[8];
        #pragma unroll
        for (int i = 0; i < 8; ++i) u[i] = csr[e + i];
        uint2 m[8];
        #pragma unroll
        for (int i = 0; i < 8; ++i) m[i] = xwb[(size_t)u[i] * 64 + lane];
        #pragma unroll
        for (int i = 0; i < 8; ++i) {
            acc.x = fmaxf(acc.x, bf_lo(m[i].x));
            acc.y = fmaxf(acc.y, bf_hi(m[i].x));
            acc.z = fmaxf(acc.z, bf_lo(m[i].y));
            acc.w = fmaxf(acc.w, bf_hi(m[i].y));
        }
    }
    if (em < e1) {
        int u[8];
        #pragma unroll
        for (int i = 0; i < 8; ++i) u[i] = csr[(em + i < e1) ? (em + i) : (e1 - 1)];
        uint2 m[8];
        #pragma unroll
        for (int i = 0; i < 8; ++i) m[i] = xwb[(size_t)u[i] * 64 + lane];
        #pragma unroll
        for (int i = 0; i < 8; ++i) {
            if (em + i < e1) {
                acc.x = fmaxf(acc.x, bf_lo(m[i].x));
                acc.y = fmaxf(acc.y, bf_hi(m[i].x));
                acc.z = fmaxf(acc.z, bf_lo(m[i].y));
                acc.w = fmaxf(acc.w, bf_hi(m[i].y));
            }
        }
    }
    float dv = dinv[v];
    float4 b4 = ((const float4*)bias)[lane];
    float4 o;
    o.x = fmaxf(fmaf(acc.x, dv, b4.x), 0.f);
    o.y = fmaxf(fmaf(acc.y, dv, b4.y), 0.f);
    o.z = fmaxf(fmaf(acc.z, dv, b4.z), 0.f);
    o.w = fmaxf(fmaf(acc.w, dv, b4.w), 0.f);
    uint2 pk;
    pk.x = pack_bf2(o.x, o.y);
    pk.y = pack_bf2(o.z, o.w);
    nt_store_u2(outb + (size_t)v * 64 + lane, pk);
}

// ---- per-graph mega-kernel, 1024 threads (verified round 13) ----
__global__ __launch_bounds__(1024) void attn_graph_head(
        const float* __restrict__ AF,
        const float* __restrict__ g1W, const float* __restrict__ g1b,
        const float* __restrict__ g_in,
        const float* __restrict__ xw2,
        const float* __restrict__ dinv, const int* __restrict__ offs,
        const int* __restrict__ csr, const float* __restrict__ b2,
        const int* __restrict__ host_idx,
        const float* __restrict__ a2W, const float* __restrict__ a2b,
        const float* __restrict__ f2W, const float* __restrict__ f2b,
        const float* __restrict__ g2W, const float* __restrict__ g2b,
        const float* __restrict__ o1W, const float* __restrict__ o1b,
        const float* __restrict__ o2W, const float* __restrict__ o2b,
        float* __restrict__ out) {
    __shared__ float At[NH][256];
    __shared__ float Ft[NH][256];
    __shared__ float red_m[NH];
    __shared__ float red_s[NH];
    __shared__ float cat[512];
    __shared__ float catB[320];
    __shared__ float g1s[256];
    __shared__ float x2l[NH][64];
    __shared__ float part4[4][256];
    __shared__ float part16[16][64];
    __shared__ float grow[256];
    const int b = blockIdx.x;
    const int t = threadIdx.x;
    const int wave = t >> 6;
    const int lane = t & 63;
    const int c = t & 255;
    const int quad = t >> 8;

    if (wave < NH) {
        int hv = host_idx[b * NH + wave];
        float acc = xw2[(size_t)hv * 64 + lane];
        int e0 = offs[hv], e1 = offs[hv + 1];
        for (int e = e0; e < e1; e += 8) {
            int u[8];
            #pragma unroll
            for (int i = 0; i < 8; ++i) u[i] = csr[(e + i < e1) ? (e + i) : (e1 - 1)];
            float m[8];
            #pragma unroll
            for (int i = 0; i < 8; ++i) m[i] = xw2[(size_t)u[i] * 64 + lane];
            #pragma unroll
            for (int i = 0; i < 8; ++i)
                if (e + i < e1) acc = fmaxf(acc, m[i]);
        }
        x2l[wave][lane] = fmaxf(fmaf(acc, dinv[hv], b2[lane]), 0.f);
    }
    for (int idx = t; idx < NH * 128; idx += 1024) {
        int j = idx >> 7, q = idx & 127;
        float4 v = ((const float4*)(AF + (size_t)(b * NH + j) * 512))[q];
        if (q < 64) *(float4*)&At[j][q * 4] = v;
        else        *(float4*)&Ft[j][(q - 64) * 4] = v;
    }
    __syncthreads();
    if (wave < NH) {
        float m = -3.402823466e38f;
        #pragma unroll
        for (int q = 0; q < 4; ++q) m = fmaxf(m, At[wave][q * 64 + lane]);
        #pragma unroll
        for (int off = 32; off; off >>= 1) m = fmaxf(m, __shfl_xor(m, off));
        if (lane == 0) red_m[wave] = m;
    }
    __syncthreads();
    for (int idx = t; idx < NH * 256; idx += 1024) {
        int j = idx >> 8, cc = idx & 255;
        At[j][cc] = expf(At[j][cc] - red_m[j]);
    }
    __syncthreads();
    if (wave < NH) {
        float s = 0.f;
        #pragma unroll
        for (int q = 0; q < 4; ++q) s += At[wave][q * 64 + lane];
        #pragma unroll
        for (int off = 32; off; off >>= 1) s += __shfl_xor(s, off);
        if (lane == 0) red_s[wave] = s;
    }
    __syncthreads();
    if (quad == 0) {
        float outc = 0.f;
        #pragma unroll
        for (int j = 0; j < NH; ++j) outc += At[j][c] / red_s[j] * Ft[j][c];
        cat[c] = outc;
        cat[256 + c] = g_in[b * 256 + c];
    }
    __syncthreads();
    // g1W update: 512 floats = 128 float4, 32 per quad (full coverage!)
    {
        float acc = 0.f;
        const float* gwp = g1W + c;
        #pragma unroll 4
        for (int i4 = quad * 32; i4 < quad * 32 + 32; ++i4) {
            float4 cq = ((const float4*)cat)[i4];
            const float* gw4 = gwp + (size_t)i4 * 1024;
            acc = fmaf(cq.x, gw4[0], acc);
            acc = fmaf(cq.y, gw4[256], acc);
            acc = fmaf(cq.z, gw4[512], acc);
            acc = fmaf(cq.w, gw4[768], acc);
        }
        part4[quad][c] = acc;
    }
    __syncthreads();
    if (quad == 0)
        g1s[c] = cat[256 + c] + g1b[c] +
                 part4[0][c] + part4[1][c] + part4[2][c] + part4[3][c];
    __syncthreads();
    if (wave < NH) {
        float aA = a2b[lane], aF = f2b[lane];
        #pragma unroll 8
        for (int k = 0; k < 64; ++k) {
            float xv = x2l[wave][k];
            aA = fmaf(xv, a2W[k * 64 + lane], aA);
            aF = fmaf(xv, f2W[k * 64 + lane], aF);
        }
        float m = aA;
        #pragma unroll
        for (int off = 32; off; off >>= 1) m = fmaxf(m, __shfl_xor(m, off));
        float pexp = expf(aA - m);
        float s = pexp;
        #pragma unroll
        for (int off = 32; off; off >>= 1) s += __shfl_xor(s, off);
        At[wave][lane] = pexp / s * aF;
    }
    __syncthreads();
    if (t < 64) {
        float o = 0.f;
        #pragma unroll
        for (int j = 0; j < NH; ++j) o += At[j][t];
        catB[t] = o;
    }
    if (quad == 0) catB[64 + c] = g1s[c];
    __syncthreads();
    // g2W update: 320 floats = 80 float4, 20 per quad
    {
        float acc = 0.f;
        const float* gwp = g2W + c;
        #pragma unroll 4
        for (int i4 = quad * 20; i4 < quad * 20 + 20; ++i4) {
            float4 cq = ((const float4*)catB)[i4];
            const float* gw4 = gwp + (size_t)i4 * 1024;
            acc = fmaf(cq.x, gw4[0], acc);
            acc = fmaf(cq.y, gw4[256], acc);
            acc = fmaf(cq.z, gw4[512], acc);
            acc = fmaf(cq.w, gw4[768], acc);
        }
        part4[quad][c] = acc;
    }
    __syncthreads();
    if (quad == 0)
        grow[c] = g1s[c] + g2b[c] +
                  part4[0][c] + part4[1][c] + part4[2][c] + part4[3][c];
    __syncthreads();
    {
        float hp = 0.f;
        #pragma unroll
        for (int k = wave * 16; k < wave * 16 + 16; ++k)
            hp = fmaf(grow[k], o1W[(size_t)k * 64 + lane], hp);
        part16[wave][lane] = hp;
    }
    __syncthreads();
    if (wave == 0) {
        float h = o1b[lane];
        #pragma unroll
        for (int w = 0; w < 16; ++w) h += part16[w][lane];
        h = fmaxf(h, 0.f);
        float sres = h * o2W[lane];
        #pragma unroll
        for (int off = 32; off; off >>= 1) sres += __shfl_xor(sres, off);
        if (lane == 0) out[b] = sres + o2b[0];
    }
}

extern "C" void kernel_launch(void* const* d_in, const int* in_sizes, int n_in,
                              void* d_out, int out_size, void* d_ws, size_t ws_size,
                              hipStream_t stream) {
    (void)in_sizes; (void)n_in; (void)out_size;
    const float* x    = (const float*)d_in[0];
    const int* ei32   = (const int*)d_in[1];
    const long long* ei64 = (const long long*)d_in[1];
    const int* hidx   = (const int*)d_in[2];
    const float* W1 = (const float*)d_in[3],  *b1 = (const float*)d_in[4];
    const float* W2 = (const float*)d_in[5],  *b2 = (const float*)d_in[6];
    const float* a0W = (const float*)d_in[7],  *a0b = (const float*)d_in[8];
    const float* f0W = (const float*)d_in[9],  *f0b = (const float*)d_in[10];
    const float* g0W = (const float*)d_in[11], *g0b = (const float*)d_in[12];
    const float* a1W = (const float*)d_in[13], *a1b = (const float*)d_in[14];
    const float* f1W = (const float*)d_in[15], *f1b = (const float*)d_in[16];
    const float* g1W = (const float*)d_in[17], *g1b = (const float*)d_in[18];
    const float* a2W = (const float*)d_in[19], *a2b = (const float*)d_in[20];
    const float* f2W = (const float*)d_in[21], *f2b = (const float*)d_in[22];
    const float* g2W = (const float*)d_in[23], *g2b = (const float*)d_in[24];
    const float* o1W = (const float*)d_in[25], *o1b = (const float*)d_in[26];
    const float* o2W = (const float*)d_in[27], *o2b = (const float*)d_in[28];
    float* outp = (float*)d_out;

    char* p = (char*)d_ws;
    auto alloc = [&](size_t bytes) {
        char* r = p;
        p += (bytes + 255) & ~(size_t)255;
        return r;
    };
    float* dinv = (float*)alloc((size_t)N_NODES * 4);
    int* degc   = (int*)alloc((size_t)N_NODES * 4);
    int* offs   = (int*)alloc((size_t)(N_NODES + 1) * 4);
    int* csr    = (int*)alloc((size_t)N_EDGES * 4);
    int* bsums  = (int*)alloc(256 * 4);
    float* g    = (float*)alloc((size_t)B_GRAPH * 256 * 4);
    float* AF   = (float*)alloc((size_t)B_GRAPH * NH * 512 * 4);
    unsigned short* xw1b = (unsigned short*)alloc((size_t)N_NODES * 256 * 2);  // bf16
    unsigned short* x1b  = (unsigned short*)alloc((size_t)N_NODES * 256 * 2);  // bf16
    float* xw2  = (float*)alloc((size_t)N_NODES * 64 * 4);

    size_t need = (size_t)(p - (char*)d_ws);
    if (need > ws_size) {
        fprintf(stderr, "kernel_launch: ws too small (%zu needed, %zu have)\n", need, ws_size);
        return;
    }

    (void)hipMemsetAsync(degc, 0, (size_t)N_NODES * 4, stream);
    count_deg<<<1600, 256, 0, stream>>>(ei32, ei64, degc);
    scan_block_sums<<<200, 256, 0, stream>>>(degc, bsums);
    scan_finalize<<<200, 256, 0, stream>>>(degc, offs, dinv, bsums);

    // af0 | fill_csr | gemm1 (128x128, bf16 out)
    fused_gemm1<<<2816, 256, 0, stream>>>(
        x, W1, (float*)xw1b, dinv, ei32, ei64, degc, csr,
        hidx, a0W, a0b, f0W, f0b, AF);
    // attn reduce 0 | agg (bf16 gather, bf16 out)
    fused_agg256<<<256 + 12800, 256, 0, stream>>>((const uint2*)xw1b, dinv, offs, csr,
                                                  b1, (uint2*)x1b, AF, g0W, g0b,
                                                  nullptr, g);
    // af1 (bf16 in) | gemm2 (128x64, bf16 in, fp32 out)
    fused_gemm2<<<816, 256, 0, stream>>>(
        (const float*)x1b, W2, xw2, dinv, hidx, a1W, a1b, f1W, f1b, AF);
    // per-graph (1024 thr): reduce1 + host-only agg + attn2 + g2 update + head
    attn_graph_head<<<256, 1024, 0, stream>>>(
        AF, g1W, g1b, g, xw2, dinv, offs, csr, b2, hidx,
        a2W, a2b, f2W, f2b, g2W, g2b, o1W, o1b, o2W, o2b, outp);
}